// Round 8
// baseline (444.031 us; speedup 1.0000x reference)
//
#include <hip/hip_runtime.h>

typedef __attribute__((ext_vector_type(8))) short short8;
typedef __attribute__((ext_vector_type(8))) unsigned short ushort8;
typedef __attribute__((ext_vector_type(4))) float f32x4;

__device__ __forceinline__ unsigned short f2bf(float f){
  unsigned int u = __builtin_bit_cast(unsigned int, f);
  u += 0x7fffu + ((u >> 16) & 1u);           // round-to-nearest-even
  return (unsigned short)(u >> 16);
}
__device__ __forceinline__ float bf2f(unsigned short h){
  unsigned int u = ((unsigned int)h) << 16;
  return __builtin_bit_cast(float, u);
}
__device__ __forceinline__ float leaky(float x){ return x > 0.f ? x : 0.3f * x; }

// ---------------- BN statistics: stage 1 (per-block partial sums) ----------------
__global__ __launch_bounds__(256) void ca_stats_partial(const float* __restrict__ state,
    const int* __restrict__ agp, float* __restrict__ part, int B){
  int d = threadIdx.x;
  int ag = agp[0];
  int bPer = (B + 255) >> 8;
  int b0 = blockIdx.x * bPer;
  float sC = 0.f, ssC = 0.f, sO = 0.f, ssO = 0.f;
  for (int b = 0; b < bPer; b++){
    int bb = b0 + b;
    if (bb >= B) break;
    const float* row = state + ((size_t)bb << 12);   // *16*256
    #pragma unroll
    for (int a = 0; a < 16; a++){
      float v = row[a*256 + d];
      bool isC = (a == ag);
      sC  += isC ? v   : 0.f;
      ssC += isC ? v*v : 0.f;
      sO  += isC ? 0.f : v;
      ssO += isC ? 0.f : v*v;
    }
  }
  float* p = part + (size_t)blockIdx.x * 1024;
  p[d] = sC; p[d+256] = ssC; p[d+512] = sO; p[d+768] = ssO;
}

// ---------------- BN statistics: stage 2 (finalize rs, mean*rs), 1024 threads ----------------
__global__ __launch_bounds__(1024) void ca_stats_final(const float* __restrict__ part,
    float* __restrict__ stats, int nblk, int B){
  int d = threadIdx.x & 255, sl = threadIdx.x >> 8;
  float sC = 0.f, ssC = 0.f, sO = 0.f, ssO = 0.f;
  for (int g = sl; g < nblk; g += 4){
    const float* p = part + (size_t)g * 1024;
    sC += p[d]; ssC += p[d+256]; sO += p[d+512]; ssO += p[d+768];
  }
  __shared__ float red[4][4][256];
  red[sl][0][d] = sC; red[sl][1][d] = ssC; red[sl][2][d] = sO; red[sl][3][d] = ssO;
  __syncthreads();
  if (sl == 0){
    sC  = red[0][0][d] + red[1][0][d] + red[2][0][d] + red[3][0][d];
    ssC = red[0][1][d] + red[1][1][d] + red[2][1][d] + red[3][1][d];
    sO  = red[0][2][d] + red[1][2][d] + red[2][2][d] + red[3][2][d];
    ssO = red[0][3][d] + red[1][3][d] + red[2][3][d] + red[3][3][d];
    float nC = (float)B, nO = (float)B * 15.f;
    float mC = sC / nC, vC = ssC / nC - mC * mC;
    float mO = sO / nO, vO = ssO / nO - mO * mO;
    float rC = rsqrtf(vC + 1e-3f), rO = rsqrtf(vO + 1e-3f);
    stats[d] = rC; stats[d+256] = mC * rC; stats[d+512] = rO; stats[d+768] = mO * rO;
  }
}

// ---------------- weight prep: WsT/WcT (bf16, transposed, rs-folded) + biases ----------------
__global__ __launch_bounds__(256) void ca_prep_sc(const float* __restrict__ Ws,
    const float* __restrict__ bs, const float* __restrict__ Wc, const float* __restrict__ bc,
    const float* __restrict__ stats, unsigned short* __restrict__ WsT,
    unsigned short* __restrict__ WcT, float* __restrict__ bsp, float* __restrict__ bcp){
  int n = blockIdx.x, d = threadIdx.x;
  float rC = stats[d], mrC = stats[d+256], rO = stats[d+512], mrO = stats[d+768];
  float ws = Ws[(size_t)d*512 + n], wc = Wc[(size_t)d*512 + n];
  WsT[(size_t)n*256 + d] = f2bf(ws * rC);
  WcT[(size_t)n*256 + d] = f2bf(wc * rO);
  __shared__ float red[256];
  red[d] = mrC * ws;
  __syncthreads();
  for (int s = 128; s > 0; s >>= 1){ if (d < s) red[d] += red[d+s]; __syncthreads(); }
  if (d == 0) bsp[n] = bs[n] - red[0];
  __syncthreads();
  red[d] = mrO * wc;
  __syncthreads();
  for (int s = 128; s > 0; s >>= 1){ if (d < s) red[d] += red[d+s]; __syncthreads(); }
  if (d == 0) bcp[n] = bc[n] - red[0];
}

// ---------------- weight prep: WkT/WvT/WqT (bf16, [h*64+d][n], 1/8 folded into q) ----------------
__global__ __launch_bounds__(512) void ca_prep_kvq(const float* __restrict__ Wk,
    const float* __restrict__ Wv, const float* __restrict__ Wq,
    unsigned short* __restrict__ WkT, unsigned short* __restrict__ WvT,
    unsigned short* __restrict__ WqT){
  int c = blockIdx.x & 511, m = blockIdx.x >> 9;
  int n = threadIdx.x;
  int h = c >> 6, dd = c & 63;
  const float* W = (m == 0) ? Wk : (m == 1) ? Wv : Wq;
  unsigned short* O = (m == 0) ? WkT : (m == 1) ? WvT : WqT;
  float scale = (m == 2) ? 0.125f : 1.f;
  O[(size_t)c*512 + n] = f2bf(W[((size_t)h*512 + n)*64 + dd] * scale);
}

// ---------------- Q kernel: q = (leaky(norm(cur)@Ws + bs)) @ Wq  (32 b-rows / block) ----------------
__global__ __launch_bounds__(512) void ca_q_kernel(const float* __restrict__ state,
    const int* __restrict__ agp,
    const unsigned short* __restrict__ WsT, const float* __restrict__ bsp,
    const unsigned short* __restrict__ WqT, unsigned short* __restrict__ Qws){
  __shared__ unsigned short U[32*512];      // 32KB union: Alds (first 16KB) then SE
  __shared__ float bias_s[512];
  unsigned short* Alds = U;                 // 32 rows x 256 cols, swizzled
  unsigned short* SE = U;                   // 32 rows x 512 cols, swizzled
  int tid = threadIdx.x, lane = tid & 63, w = tid >> 6;
  int j = lane & 15, hi = lane >> 4;
  int b0 = blockIdx.x * 32;
  int ag = agp[0];

  for (int s = tid; s < 32*32; s += 512){
    int row = s >> 5, kg = s & 31;
    const float* p = state + (((size_t)(b0 + row) * 16 + ag) << 8) + kg * 8;
    f32x4 v0 = *(const f32x4*)p, v1 = *(const f32x4*)(p + 4);
    ushort8 hv;
    hv[0]=f2bf(v0[0]); hv[1]=f2bf(v0[1]); hv[2]=f2bf(v0[2]); hv[3]=f2bf(v0[3]);
    hv[4]=f2bf(v1[0]); hv[5]=f2bf(v1[1]); hv[6]=f2bf(v1[2]); hv[7]=f2bf(v1[3]);
    *(ushort8*)&Alds[row*256 + ((kg ^ (row & 7)) << 3)] = hv;
  }
  bias_s[tid & 511] = bsp[tid & 511];
  __syncthreads();

  int cb = w * 64;
  f32x4 zero4 = {0.f, 0.f, 0.f, 0.f};
  f32x4 acc[2][4];
  #pragma unroll
  for (int a1 = 0; a1 < 2; a1++)
    #pragma unroll
    for (int a2 = 0; a2 < 4; a2++) acc[a1][a2] = zero4;

  #pragma unroll
  for (int kk = 0; kk < 8; kk++){
    short8 bfr[4];
    #pragma unroll
    for (int nt = 0; nt < 4; nt++)
      bfr[nt] = *(const short8*)&WsT[(size_t)(cb + nt*16 + j)*256 + kk*32 + hi*8];
    #pragma unroll
    for (int mt = 0; mt < 2; mt++){
      int row = mt*16 + j;
      short8 afr = *(const short8*)&Alds[row*256 + ((((kk << 2) | hi) ^ (row & 7)) << 3)];
      #pragma unroll
      for (int nt = 0; nt < 4; nt++)
        acc[mt][nt] = __builtin_amdgcn_mfma_f32_16x16x32_bf16(afr, bfr[nt], acc[mt][nt], 0, 0, 0);
    }
  }
  __syncthreads();   // Alds dead; SE overlays it
  #pragma unroll
  for (int mt = 0; mt < 2; mt++)
    #pragma unroll
    for (int nt = 0; nt < 4; nt++)
      #pragma unroll
      for (int i = 0; i < 4; i++){
        int row = mt*16 + hi*4 + i, col = cb + nt*16 + j;
        float x = leaky(acc[mt][nt][i] + bias_s[col]);
        SE[row*512 + ((((col >> 3) ^ (row & 7)) << 3) | (col & 7))] = f2bf(x);
      }
  __syncthreads();

  f32x4 qa[2][4];
  #pragma unroll
  for (int a1 = 0; a1 < 2; a1++)
    #pragma unroll
    for (int a2 = 0; a2 < 4; a2++) qa[a1][a2] = zero4;
  #pragma unroll
  for (int kk = 0; kk < 16; kk++){
    short8 bfr[4];
    #pragma unroll
    for (int nt = 0; nt < 4; nt++)
      bfr[nt] = *(const short8*)&WqT[(size_t)(cb + nt*16 + j)*512 + kk*32 + hi*8];
    #pragma unroll
    for (int mt = 0; mt < 2; mt++){
      int row = mt*16 + j;
      short8 afr = *(const short8*)&SE[row*512 + ((((kk << 2) | hi) ^ (row & 7)) << 3)];
      #pragma unroll
      for (int nt = 0; nt < 4; nt++)
        qa[mt][nt] = __builtin_amdgcn_mfma_f32_16x16x32_bf16(afr, bfr[nt], qa[mt][nt], 0, 0, 0);
    }
  }
  #pragma unroll
  for (int mt = 0; mt < 2; mt++)
    #pragma unroll
    for (int nt = 0; nt < 4; nt++)
      #pragma unroll
      for (int i = 0; i < 4; i++)
        Qws[(size_t)(b0 + mt*16 + hi*4 + i)*512 + cb + nt*16 + j] = f2bf(qa[mt][nt][i]);
}

// ---------------- main fused kernel: sa_enc -> K -> softmax -> V -> att ----------------
// 512 threads = 8 waves, wave w = head w, 64 M-rows, 4 batches/block.
// EXPLICIT DEPTH-1 PREFETCH of B-fragments (bcur/bnxt) in all three GEMM k-loops:
// next-kk L2 loads are issued before the current 16-MFMA run (~310 SIMD-cyc)
// so the ~300cyc L2 latency is covered at the fixed 2 waves/SIMD.
// Staging phase batches all 8 HBM loads before convert+LDS-write.
__global__ __launch_bounds__(512) void ca_main_kernel(const float* __restrict__ state,
    const int* __restrict__ agp,
    const unsigned short* __restrict__ WcT, const float* __restrict__ bcp,
    const unsigned short* __restrict__ WkT, const unsigned short* __restrict__ WvT,
    const unsigned short* __restrict__ Qws, float* __restrict__ out){
  __shared__ unsigned short U[64*512];      // 64KB union: Alds (first 32KB), then SA
  __shared__ float bias_s[512];
  unsigned short* Alds = U;                 // 64 rows x 256 cols bf16 swizzled (ai=15 pad)
  unsigned short* SA = U;                   // 64 rows x 512 cols bf16 swizzled
  int tid = threadIdx.x, lane = tid & 63, w = tid >> 6;
  int j = lane & 15, hi = lane >> 4;
  int b0 = blockIdx.x * 4;
  int ag = agp[0];
  f32x4 zero4 = {0.f, 0.f, 0.f, 0.f};

  // ---- staging: issue all 8 HBM loads first, then convert+write (no serial stalls)
  {
    f32x4 st0[4], st1[4];
    #pragma unroll
    for (int it = 0; it < 4; it++){
      int s = tid + 512*it;
      int row = s >> 5, kg = s & 31;
      int bl = row >> 4, ai = row & 15;
      if (ai < 15){
        int a = ai + (ai >= ag ? 1 : 0);
        const float* p = state + (((size_t)(b0 + bl) * 16 + a) << 8) + kg * 8;
        st0[it] = *(const f32x4*)p;
        st1[it] = *(const f32x4*)(p + 4);
      } else { st0[it] = zero4; st1[it] = zero4; }
    }
    #pragma unroll
    for (int it = 0; it < 4; it++){
      int s = tid + 512*it;
      int row = s >> 5, kg = s & 31;
      ushort8 hv;
      hv[0]=f2bf(st0[it][0]); hv[1]=f2bf(st0[it][1]); hv[2]=f2bf(st0[it][2]); hv[3]=f2bf(st0[it][3]);
      hv[4]=f2bf(st1[it][0]); hv[5]=f2bf(st1[it][1]); hv[6]=f2bf(st1[it][2]); hv[7]=f2bf(st1[it][3]);
      *(ushort8*)&Alds[row*256 + ((kg ^ (row & 7)) << 3)] = hv;
    }
  }
  bias_s[tid & 511] = bcp[tid & 511];
  __syncthreads();

  int cb = w * 64;

  // ---- GEMM1: sa_enc[:, cb:cb+64] (acc in registers), B prefetch depth 1
  f32x4 acc[4][4];
  #pragma unroll
  for (int a1 = 0; a1 < 4; a1++)
    #pragma unroll
    for (int a2 = 0; a2 < 4; a2++) acc[a1][a2] = zero4;
  {
    short8 bcur[4], bnxt[4];
    #pragma unroll
    for (int nt = 0; nt < 4; nt++)
      bcur[nt] = *(const short8*)&WcT[(size_t)(cb + nt*16 + j)*256 + hi*8];
    #pragma unroll
    for (int kk = 0; kk < 8; kk++){
      if (kk < 7){
        #pragma unroll
        for (int nt = 0; nt < 4; nt++)
          bnxt[nt] = *(const short8*)&WcT[(size_t)(cb + nt*16 + j)*256 + (kk+1)*32 + hi*8];
      }
      #pragma unroll
      for (int mt = 0; mt < 4; mt++){
        int row = mt*16 + j;
        short8 afr = *(const short8*)&Alds[row*256 + ((((kk << 2) | hi) ^ (row & 7)) << 3)];
        #pragma unroll
        for (int nt = 0; nt < 4; nt++)
          acc[mt][nt] = __builtin_amdgcn_mfma_f32_16x16x32_bf16(afr, bcur[nt], acc[mt][nt], 0, 0, 0);
      }
      if (kk < 7){
        #pragma unroll
        for (int nt = 0; nt < 4; nt++) bcur[nt] = bnxt[nt];
      }
    }
  }
  __syncthreads();   // Alds dead from here; SA overlays it
  #pragma unroll
  for (int mt = 0; mt < 4; mt++)
    #pragma unroll
    for (int nt = 0; nt < 4; nt++)
      #pragma unroll
      for (int i = 0; i < 4; i++){
        int row = mt*16 + hi*4 + i, col = cb + nt*16 + j;
        float x = leaky(acc[mt][nt][i] + bias_s[col]);
        SA[row*512 + ((((col >> 3) ^ (row & 7)) << 3) | (col & 7))] = f2bf(x);
      }
  __syncthreads();

  // ---- GEMM2-K: K_head_w = sa_enc @ WkT[cb..cb+64], B prefetch depth 1
  f32x4 ka[4][4];
  #pragma unroll
  for (int a1 = 0; a1 < 4; a1++)
    #pragma unroll
    for (int a2 = 0; a2 < 4; a2++) ka[a1][a2] = zero4;
  {
    short8 bcur[4], bnxt[4];
    #pragma unroll
    for (int nt = 0; nt < 4; nt++)
      bcur[nt] = *(const short8*)&WkT[(size_t)(cb + nt*16 + j)*512 + hi*8];
    #pragma unroll
    for (int kk = 0; kk < 16; kk++){
      if (kk < 15){
        #pragma unroll
        for (int nt = 0; nt < 4; nt++)
          bnxt[nt] = *(const short8*)&WkT[(size_t)(cb + nt*16 + j)*512 + (kk+1)*32 + hi*8];
      }
      #pragma unroll
      for (int mt = 0; mt < 4; mt++){
        int row = mt*16 + j;
        short8 afr = *(const short8*)&SA[row*512 + ((((kk << 2) | hi) ^ (row & 7)) << 3)];
        #pragma unroll
        for (int nt = 0; nt < 4; nt++)
          ka[mt][nt] = __builtin_amdgcn_mfma_f32_16x16x32_bf16(afr, bcur[nt], ka[mt][nt], 0, 0, 0);
      }
      if (kk < 15){
        #pragma unroll
        for (int nt = 0; nt < 4; nt++) bcur[nt] = bnxt[nt];
      }
    }
  }

  // ---- q fragments (only needed for softmax)
  float qv[4][4];
  #pragma unroll
  for (int mt = 0; mt < 4; mt++)
    #pragma unroll
    for (int nt = 0; nt < 4; nt++)
      qv[mt][nt] = bf2f(Qws[(size_t)(b0 + mt)*512 + cb + nt*16 + j]);

  // ---- scores + softmax (fully in-register; mt == local batch index)
  float wgt[4][4];
  #pragma unroll
  for (int mt = 0; mt < 4; mt++){
    float sv[4];
    #pragma unroll
    for (int i = 0; i < 4; i++){
      float t = qv[mt][0]*ka[mt][0][i] + qv[mt][1]*ka[mt][1][i]
              + qv[mt][2]*ka[mt][2][i] + qv[mt][3]*ka[mt][3][i];
      t += __shfl_xor(t, 1); t += __shfl_xor(t, 2);
      t += __shfl_xor(t, 4); t += __shfl_xor(t, 8);
      sv[i] = t;
    }
    sv[3] = (hi == 3) ? -1e30f : sv[3];   // mask pad row a=15
    float m = fmaxf(fmaxf(sv[0], sv[1]), fmaxf(sv[2], sv[3]));
    m = fmaxf(m, __shfl_xor(m, 16)); m = fmaxf(m, __shfl_xor(m, 32));
    float e0 = __expf(sv[0]-m), e1 = __expf(sv[1]-m), e2 = __expf(sv[2]-m), e3 = __expf(sv[3]-m);
    float sum = e0 + e1 + e2 + e3;
    sum += __shfl_xor(sum, 16); sum += __shfl_xor(sum, 32);
    float inv = 1.f / sum;
    wgt[mt][0] = e0*inv; wgt[mt][1] = e1*inv; wgt[mt][2] = e2*inv; wgt[mt][3] = e3*inv;
  }

  // ---- GEMM2-V: B prefetch depth 1
  f32x4 va[4][4];
  #pragma unroll
  for (int a1 = 0; a1 < 4; a1++)
    #pragma unroll
    for (int a2 = 0; a2 < 4; a2++) va[a1][a2] = zero4;
  {
    short8 bcur[4], bnxt[4];
    #pragma unroll
    for (int nt = 0; nt < 4; nt++)
      bcur[nt] = *(const short8*)&WvT[(size_t)(cb + nt*16 + j)*512 + hi*8];
    #pragma unroll
    for (int kk = 0; kk < 16; kk++){
      if (kk < 15){
        #pragma unroll
        for (int nt = 0; nt < 4; nt++)
          bnxt[nt] = *(const short8*)&WvT[(size_t)(cb + nt*16 + j)*512 + (kk+1)*32 + hi*8];
      }
      #pragma unroll
      for (int mt = 0; mt < 4; mt++){
        int row = mt*16 + j;
        short8 afr = *(const short8*)&SA[row*512 + ((((kk << 2) | hi) ^ (row & 7)) << 3)];
        #pragma unroll
        for (int nt = 0; nt < 4; nt++)
          va[mt][nt] = __builtin_amdgcn_mfma_f32_16x16x32_bf16(afr, bcur[nt], va[mt][nt], 0, 0, 0);
      }
      if (kk < 15){
        #pragma unroll
        for (int nt = 0; nt < 4; nt++) bcur[nt] = bnxt[nt];
      }
    }
  }

  // ---- att = sum_a w * leaky(V); butterfly over hi groups; coalesced store
  #pragma unroll
  for (int mt = 0; mt < 4; mt++){
    float ap0 = 0.f, ap1 = 0.f, ap2 = 0.f, ap3 = 0.f;
    #pragma unroll
    for (int i = 0; i < 4; i++){
      float wv = wgt[mt][i];
      ap0 += wv * leaky(va[mt][0][i]);
      ap1 += wv * leaky(va[mt][1][i]);
      ap2 += wv * leaky(va[mt][2][i]);
      ap3 += wv * leaky(va[mt][3][i]);
    }
    ap0 += __shfl_xor(ap0, 16); ap0 += __shfl_xor(ap0, 32);
    ap1 += __shfl_xor(ap1, 16); ap1 += __shfl_xor(ap1, 32);
    ap2 += __shfl_xor(ap2, 16); ap2 += __shfl_xor(ap2, 32);
    ap3 += __shfl_xor(ap3, 16); ap3 += __shfl_xor(ap3, 32);
    float val = (hi == 0) ? ap0 : (hi == 1) ? ap1 : (hi == 2) ? ap2 : ap3;
    out[(size_t)(b0 + mt)*512 + cb + lane] = val;
  }
}

extern "C" void kernel_launch(void* const* d_in, const int* in_sizes, int n_in,
                              void* d_out, int out_size, void* d_ws, size_t ws_size,
                              hipStream_t stream) {
  const float* state = (const float*)d_in[0];
  const int*   agp   = (const int*)d_in[1];
  const float* Ws    = (const float*)d_in[2];
  const float* bs    = (const float*)d_in[3];
  const float* Wc    = (const float*)d_in[4];
  const float* bc    = (const float*)d_in[5];
  const float* Wk    = (const float*)d_in[6];
  const float* Wq    = (const float*)d_in[7];
  const float* Wv    = (const float*)d_in[8];
  float* out = (float*)d_out;
  int B = in_sizes[0] / 4096;   // state is (B,16,256)

  char* wsb = (char*)d_ws;
  float* part  = (float*)wsb;                                   // 256*1024*4 = 1 MB
  float* stats = (float*)(wsb + (1 << 20));                     // 4 KB
  float* bsp   = (float*)(wsb + (1 << 20) + 4096);              // 2 KB
  float* bcp   = (float*)(wsb + (1 << 20) + 6144);              // 2 KB
  unsigned short* WsT = (unsigned short*)(wsb + (1 << 20) + 8192);
  unsigned short* WcT = WsT + 512*256;
  unsigned short* WkT = WcT + 512*256;
  unsigned short* WvT = WkT + 512*512;
  unsigned short* WqT = WvT + 512*512;
  unsigned short* Qws = WqT + 512*512;   // B*512 bf16 = 8 MB; total ws ~11.1 MB

  hipLaunchKernelGGL(ca_stats_partial, dim3(256), dim3(256), 0, stream, state, agp, part, B);
  hipLaunchKernelGGL(ca_stats_final,   dim3(1),   dim3(1024), 0, stream, part, stats, 256, B);
  hipLaunchKernelGGL(ca_prep_sc,       dim3(512), dim3(256), 0, stream, Ws, bs, Wc, bc, stats, WsT, WcT, bsp, bcp);
  hipLaunchKernelGGL(ca_prep_kvq,      dim3(1536),dim3(512), 0, stream, Wk, Wv, Wq, WkT, WvT, WqT);
  hipLaunchKernelGGL(ca_q_kernel,      dim3(B/32),dim3(512), 0, stream, state, agp, WsT, bsp, WqT, Qws);
  hipLaunchKernelGGL(ca_main_kernel,   dim3(B/4), dim3(512), 0, stream, state, agp, WcT, bcp, WkT, WvT, Qws, out);
}

// Round 9
// 299.193 us; speedup vs baseline: 1.4841x; 1.4841x over previous
//
#include <hip/hip_runtime.h>

typedef __attribute__((ext_vector_type(8))) short short8;
typedef __attribute__((ext_vector_type(8))) unsigned short ushort8;
typedef __attribute__((ext_vector_type(4))) float f32x4;

__device__ __forceinline__ unsigned short f2bf(float f){
  unsigned int u = __builtin_bit_cast(unsigned int, f);
  u += 0x7fffu + ((u >> 16) & 1u);           // round-to-nearest-even
  return (unsigned short)(u >> 16);
}
__device__ __forceinline__ float bf2f(unsigned short h){
  unsigned int u = ((unsigned int)h) << 16;
  return __builtin_bit_cast(float, u);
}
__device__ __forceinline__ float leaky(float x){ return x > 0.f ? x : 0.3f * x; }

// ---------------- BN statistics: stage 1 (per-block partial sums) ----------------
__global__ __launch_bounds__(256) void ca_stats_partial(const float* __restrict__ state,
    const int* __restrict__ agp, float* __restrict__ part, int B){
  int d = threadIdx.x;
  int ag = agp[0];
  int bPer = (B + 255) >> 8;
  int b0 = blockIdx.x * bPer;
  float sC = 0.f, ssC = 0.f, sO = 0.f, ssO = 0.f;
  for (int b = 0; b < bPer; b++){
    int bb = b0 + b;
    if (bb >= B) break;
    const float* row = state + ((size_t)bb << 12);   // *16*256
    #pragma unroll
    for (int a = 0; a < 16; a++){
      float v = row[a*256 + d];
      bool isC = (a == ag);
      sC  += isC ? v   : 0.f;
      ssC += isC ? v*v : 0.f;
      sO  += isC ? 0.f : v;
      ssO += isC ? 0.f : v*v;
    }
  }
  float* p = part + (size_t)blockIdx.x * 1024;
  p[d] = sC; p[d+256] = ssC; p[d+512] = sO; p[d+768] = ssO;
}

// ---------------- BN statistics: stage 2 (finalize rs, mean*rs), 1024 threads ----------------
__global__ __launch_bounds__(1024) void ca_stats_final(const float* __restrict__ part,
    float* __restrict__ stats, int nblk, int B){
  int d = threadIdx.x & 255, sl = threadIdx.x >> 8;
  float sC = 0.f, ssC = 0.f, sO = 0.f, ssO = 0.f;
  for (int g = sl; g < nblk; g += 4){
    const float* p = part + (size_t)g * 1024;
    sC += p[d]; ssC += p[d+256]; sO += p[d+512]; ssO += p[d+768];
  }
  __shared__ float red[4][4][256];
  red[sl][0][d] = sC; red[sl][1][d] = ssC; red[sl][2][d] = sO; red[sl][3][d] = ssO;
  __syncthreads();
  if (sl == 0){
    sC  = red[0][0][d] + red[1][0][d] + red[2][0][d] + red[3][0][d];
    ssC = red[0][1][d] + red[1][1][d] + red[2][1][d] + red[3][1][d];
    sO  = red[0][2][d] + red[1][2][d] + red[2][2][d] + red[3][2][d];
    ssO = red[0][3][d] + red[1][3][d] + red[2][3][d] + red[3][3][d];
    float nC = (float)B, nO = (float)B * 15.f;
    float mC = sC / nC, vC = ssC / nC - mC * mC;
    float mO = sO / nO, vO = ssO / nO - mO * mO;
    float rC = rsqrtf(vC + 1e-3f), rO = rsqrtf(vO + 1e-3f);
    stats[d] = rC; stats[d+256] = mC * rC; stats[d+512] = rO; stats[d+768] = mO * rO;
  }
}

// ---------------- weight prep: WsT/WcT (bf16, transposed, rs-folded) + biases ----------------
__global__ __launch_bounds__(256) void ca_prep_sc(const float* __restrict__ Ws,
    const float* __restrict__ bs, const float* __restrict__ Wc, const float* __restrict__ bc,
    const float* __restrict__ stats, unsigned short* __restrict__ WsT,
    unsigned short* __restrict__ WcT, float* __restrict__ bsp, float* __restrict__ bcp){
  int n = blockIdx.x, d = threadIdx.x;
  float rC = stats[d], mrC = stats[d+256], rO = stats[d+512], mrO = stats[d+768];
  float ws = Ws[(size_t)d*512 + n], wc = Wc[(size_t)d*512 + n];
  WsT[(size_t)n*256 + d] = f2bf(ws * rC);
  WcT[(size_t)n*256 + d] = f2bf(wc * rO);
  __shared__ float red[256];
  red[d] = mrC * ws;
  __syncthreads();
  for (int s = 128; s > 0; s >>= 1){ if (d < s) red[d] += red[d+s]; __syncthreads(); }
  if (d == 0) bsp[n] = bs[n] - red[0];
  __syncthreads();
  red[d] = mrO * wc;
  __syncthreads();
  for (int s = 128; s > 0; s >>= 1){ if (d < s) red[d] += red[d+s]; __syncthreads(); }
  if (d == 0) bcp[n] = bc[n] - red[0];
}

// ---------------- weight prep: WkT/WvT/WqT (bf16, [h*64+d][n], 1/8 folded into q) ----------------
__global__ __launch_bounds__(512) void ca_prep_kvq(const float* __restrict__ Wk,
    const float* __restrict__ Wv, const float* __restrict__ Wq,
    unsigned short* __restrict__ WkT, unsigned short* __restrict__ WvT,
    unsigned short* __restrict__ WqT){
  int c = blockIdx.x & 511, m = blockIdx.x >> 9;
  int n = threadIdx.x;
  int h = c >> 6, dd = c & 63;
  const float* W = (m == 0) ? Wk : (m == 1) ? Wv : Wq;
  unsigned short* O = (m == 0) ? WkT : (m == 1) ? WvT : WqT;
  float scale = (m == 2) ? 0.125f : 1.f;
  O[(size_t)c*512 + n] = f2bf(W[((size_t)h*512 + n)*64 + dd] * scale);
}

// ---------------- Q kernel: q = (leaky(norm(cur)@Ws + bs)) @ Wq  (32 b-rows / block) ----------------
__global__ __launch_bounds__(512) void ca_q_kernel(const float* __restrict__ state,
    const int* __restrict__ agp,
    const unsigned short* __restrict__ WsT, const float* __restrict__ bsp,
    const unsigned short* __restrict__ WqT, unsigned short* __restrict__ Qws){
  __shared__ unsigned short U[32*512];      // 32KB union: Alds (first 16KB) then SE
  __shared__ float bias_s[512];
  unsigned short* Alds = U;                 // 32 rows x 256 cols, swizzled
  unsigned short* SE = U;                   // 32 rows x 512 cols, swizzled
  int tid = threadIdx.x, lane = tid & 63, w = tid >> 6;
  int j = lane & 15, hi = lane >> 4;
  int b0 = blockIdx.x * 32;
  int ag = agp[0];

  for (int s = tid; s < 32*32; s += 512){
    int row = s >> 5, kg = s & 31;
    const float* p = state + (((size_t)(b0 + row) * 16 + ag) << 8) + kg * 8;
    f32x4 v0 = *(const f32x4*)p, v1 = *(const f32x4*)(p + 4);
    ushort8 hv;
    hv[0]=f2bf(v0[0]); hv[1]=f2bf(v0[1]); hv[2]=f2bf(v0[2]); hv[3]=f2bf(v0[3]);
    hv[4]=f2bf(v1[0]); hv[5]=f2bf(v1[1]); hv[6]=f2bf(v1[2]); hv[7]=f2bf(v1[3]);
    *(ushort8*)&Alds[row*256 + ((kg ^ (row & 7)) << 3)] = hv;
  }
  bias_s[tid & 511] = bsp[tid & 511];
  __syncthreads();

  int cb = w * 64;
  f32x4 zero4 = {0.f, 0.f, 0.f, 0.f};
  f32x4 acc[2][4];
  #pragma unroll
  for (int a1 = 0; a1 < 2; a1++)
    #pragma unroll
    for (int a2 = 0; a2 < 4; a2++) acc[a1][a2] = zero4;

  #pragma unroll
  for (int kk = 0; kk < 8; kk++){
    short8 bfr[4];
    #pragma unroll
    for (int nt = 0; nt < 4; nt++)
      bfr[nt] = *(const short8*)&WsT[(size_t)(cb + nt*16 + j)*256 + kk*32 + hi*8];
    #pragma unroll
    for (int mt = 0; mt < 2; mt++){
      int row = mt*16 + j;
      short8 afr = *(const short8*)&Alds[row*256 + ((((kk << 2) | hi) ^ (row & 7)) << 3)];
      #pragma unroll
      for (int nt = 0; nt < 4; nt++)
        acc[mt][nt] = __builtin_amdgcn_mfma_f32_16x16x32_bf16(afr, bfr[nt], acc[mt][nt], 0, 0, 0);
    }
  }
  __syncthreads();   // Alds dead; SE overlays it
  #pragma unroll
  for (int mt = 0; mt < 2; mt++)
    #pragma unroll
    for (int nt = 0; nt < 4; nt++)
      #pragma unroll
      for (int i = 0; i < 4; i++){
        int row = mt*16 + hi*4 + i, col = cb + nt*16 + j;
        float x = leaky(acc[mt][nt][i] + bias_s[col]);
        SE[row*512 + ((((col >> 3) ^ (row & 7)) << 3) | (col & 7))] = f2bf(x);
      }
  __syncthreads();

  f32x4 qa[2][4];
  #pragma unroll
  for (int a1 = 0; a1 < 2; a1++)
    #pragma unroll
    for (int a2 = 0; a2 < 4; a2++) qa[a1][a2] = zero4;
  #pragma unroll
  for (int kk = 0; kk < 16; kk++){
    short8 bfr[4];
    #pragma unroll
    for (int nt = 0; nt < 4; nt++)
      bfr[nt] = *(const short8*)&WqT[(size_t)(cb + nt*16 + j)*512 + kk*32 + hi*8];
    #pragma unroll
    for (int mt = 0; mt < 2; mt++){
      int row = mt*16 + j;
      short8 afr = *(const short8*)&SE[row*512 + ((((kk << 2) | hi) ^ (row & 7)) << 3)];
      #pragma unroll
      for (int nt = 0; nt < 4; nt++)
        qa[mt][nt] = __builtin_amdgcn_mfma_f32_16x16x32_bf16(afr, bfr[nt], qa[mt][nt], 0, 0, 0);
    }
  }
  #pragma unroll
  for (int mt = 0; mt < 2; mt++)
    #pragma unroll
    for (int nt = 0; nt < 4; nt++)
      #pragma unroll
      for (int i = 0; i < 4; i++)
        Qws[(size_t)(b0 + mt*16 + hi*4 + i)*512 + cb + nt*16 + j] = f2bf(qa[mt][nt][i]);
}

// ---------------- main fused kernel: sa_enc -> K -> softmax -> V -> att ----------------
// 8 batches (128 M-rows) per block, 512 threads = 8 waves, wave w = head w.
// Each B-fragment load now feeds 8 MFMAs (vs 4): total vector-mem instructions
// halve chip-wide (1024 blocks). kk loops are `#pragma unroll 1` to bound register
// liveness (R5's full-unroll at mt=8 spilled); one 128-reg accumulator live per phase.
__global__ __launch_bounds__(512) void ca_main_kernel(const float* __restrict__ state,
    const int* __restrict__ agp,
    const unsigned short* __restrict__ WcT, const float* __restrict__ bcp,
    const unsigned short* __restrict__ WkT, const unsigned short* __restrict__ WvT,
    const unsigned short* __restrict__ Qws, float* __restrict__ out){
  __shared__ unsigned short U[128*512];     // 128KB union: Alds (first 64KB), then SA
  __shared__ unsigned short Qs[8*512];      // 8KB staged q rows (bf16)
  __shared__ float bias_s[512];
  unsigned short* Alds = U;                 // 128 rows x 256 cols bf16 swizzled (ai=15 pad)
  unsigned short* SA = U;                   // 128 rows x 512 cols bf16 swizzled
  int tid = threadIdx.x, lane = tid & 63, w = tid >> 6;
  int j = lane & 15, hi = lane >> 4;
  int b0 = blockIdx.x * 8;
  int ag = agp[0];
  f32x4 zero4 = {0.f, 0.f, 0.f, 0.f};

  // ---- staging: 128 rows x 256, batched loads (2 groups of 4x32B per thread)
  #pragma unroll
  for (int g = 0; g < 2; g++){
    f32x4 st0[4], st1[4];
    #pragma unroll
    for (int it = 0; it < 4; it++){
      int s = tid + 512*(g*4 + it);
      int row = s >> 5, kg = s & 31;
      int bl = row >> 4, ai = row & 15;
      if (ai < 15){
        int a = ai + (ai >= ag ? 1 : 0);
        const float* p = state + (((size_t)(b0 + bl) * 16 + a) << 8) + kg * 8;
        st0[it] = *(const f32x4*)p;
        st1[it] = *(const f32x4*)(p + 4);
      } else { st0[it] = zero4; st1[it] = zero4; }
    }
    #pragma unroll
    for (int it = 0; it < 4; it++){
      int s = tid + 512*(g*4 + it);
      int row = s >> 5, kg = s & 31;
      ushort8 hv;
      hv[0]=f2bf(st0[it][0]); hv[1]=f2bf(st0[it][1]); hv[2]=f2bf(st0[it][2]); hv[3]=f2bf(st0[it][3]);
      hv[4]=f2bf(st1[it][0]); hv[5]=f2bf(st1[it][1]); hv[6]=f2bf(st1[it][2]); hv[7]=f2bf(st1[it][3]);
      *(ushort8*)&Alds[row*256 + ((kg ^ (row & 7)) << 3)] = hv;
    }
  }
  // ---- stage q rows (8 batches x 512 cols bf16 = 8KB, one ushort8 per thread)
  *(ushort8*)&Qs[tid*8] = *(const ushort8*)&Qws[(size_t)b0*512 + tid*8];
  bias_s[tid] = bcp[tid];
  __syncthreads();

  int cb = w * 64;

  // ---- GEMM1: sa_enc rows [0,128) x cols [cb,cb+64)
  f32x4 acc[8][4];
  #pragma unroll
  for (int a1 = 0; a1 < 8; a1++)
    #pragma unroll
    for (int a2 = 0; a2 < 4; a2++) acc[a1][a2] = zero4;
  {
    short8 bcur[4], bnxt[4];
    #pragma unroll
    for (int nt = 0; nt < 4; nt++)
      bcur[nt] = *(const short8*)&WcT[(size_t)(cb + nt*16 + j)*256 + hi*8];
    #pragma unroll 1
    for (int kk = 0; kk < 8; kk++){
      if (kk < 7){
        #pragma unroll
        for (int nt = 0; nt < 4; nt++)
          bnxt[nt] = *(const short8*)&WcT[(size_t)(cb + nt*16 + j)*256 + (kk+1)*32 + hi*8];
      }
      #pragma unroll
      for (int mt = 0; mt < 8; mt++){
        int row = mt*16 + j;
        short8 afr = *(const short8*)&Alds[row*256 + ((((kk << 2) | hi) ^ (row & 7)) << 3)];
        #pragma unroll
        for (int nt = 0; nt < 4; nt++)
          acc[mt][nt] = __builtin_amdgcn_mfma_f32_16x16x32_bf16(afr, bcur[nt], acc[mt][nt], 0, 0, 0);
      }
      #pragma unroll
      for (int nt = 0; nt < 4; nt++) bcur[nt] = bnxt[nt];
    }
  }
  __syncthreads();   // Alds dead from here; SA overlays it
  #pragma unroll
  for (int mt = 0; mt < 8; mt++)
    #pragma unroll
    for (int nt = 0; nt < 4; nt++)
      #pragma unroll
      for (int i = 0; i < 4; i++){
        int row = mt*16 + hi*4 + i, col = cb + nt*16 + j;
        float x = leaky(acc[mt][nt][i] + bias_s[col]);
        SA[row*512 + ((((col >> 3) ^ (row & 7)) << 3) | (col & 7))] = f2bf(x);
      }
  __syncthreads();

  // ---- GEMM2-K: K rows [0,128) for head w
  f32x4 ka[8][4];
  #pragma unroll
  for (int a1 = 0; a1 < 8; a1++)
    #pragma unroll
    for (int a2 = 0; a2 < 4; a2++) ka[a1][a2] = zero4;
  {
    short8 bcur[4], bnxt[4];
    #pragma unroll
    for (int nt = 0; nt < 4; nt++)
      bcur[nt] = *(const short8*)&WkT[(size_t)(cb + nt*16 + j)*512 + hi*8];
    #pragma unroll 1
    for (int kk = 0; kk < 16; kk++){
      if (kk < 15){
        #pragma unroll
        for (int nt = 0; nt < 4; nt++)
          bnxt[nt] = *(const short8*)&WkT[(size_t)(cb + nt*16 + j)*512 + (kk+1)*32 + hi*8];
      }
      #pragma unroll
      for (int mt = 0; mt < 8; mt++){
        int row = mt*16 + j;
        short8 afr = *(const short8*)&SA[row*512 + ((((kk << 2) | hi) ^ (row & 7)) << 3)];
        #pragma unroll
        for (int nt = 0; nt < 4; nt++)
          ka[mt][nt] = __builtin_amdgcn_mfma_f32_16x16x32_bf16(afr, bcur[nt], ka[mt][nt], 0, 0, 0);
      }
      #pragma unroll
      for (int nt = 0; nt < 4; nt++) bcur[nt] = bnxt[nt];
    }
  }

  // ---- scores + softmax (in-register; mt == local batch index, q from LDS)
  float wgt[8][4];
  #pragma unroll
  for (int mt = 0; mt < 8; mt++){
    float sv[4];
    #pragma unroll
    for (int i = 0; i < 4; i++){
      float t = 0.f;
      #pragma unroll
      for (int nt = 0; nt < 4; nt++)
        t += bf2f(Qs[mt*512 + cb + nt*16 + j]) * ka[mt][nt][i];
      t += __shfl_xor(t, 1); t += __shfl_xor(t, 2);
      t += __shfl_xor(t, 4); t += __shfl_xor(t, 8);
      sv[i] = t;
    }
    sv[3] = (hi == 3) ? -1e30f : sv[3];   // mask pad row a=15
    float m = fmaxf(fmaxf(sv[0], sv[1]), fmaxf(sv[2], sv[3]));
    m = fmaxf(m, __shfl_xor(m, 16)); m = fmaxf(m, __shfl_xor(m, 32));
    float e0 = __expf(sv[0]-m), e1 = __expf(sv[1]-m), e2 = __expf(sv[2]-m), e3 = __expf(sv[3]-m);
    float sum = e0 + e1 + e2 + e3;
    sum += __shfl_xor(sum, 16); sum += __shfl_xor(sum, 32);
    float inv = 1.f / sum;
    wgt[mt][0] = e0*inv; wgt[mt][1] = e1*inv; wgt[mt][2] = e2*inv; wgt[mt][3] = e3*inv;
  }

  // ---- GEMM2-V (ka dead; va is the only live accumulator set)
  f32x4 va[8][4];
  #pragma unroll
  for (int a1 = 0; a1 < 8; a1++)
    #pragma unroll
    for (int a2 = 0; a2 < 4; a2++) va[a1][a2] = zero4;
  {
    short8 bcur[4], bnxt[4];
    #pragma unroll
    for (int nt = 0; nt < 4; nt++)
      bcur[nt] = *(const short8*)&WvT[(size_t)(cb + nt*16 + j)*512 + hi*8];
    #pragma unroll 1
    for (int kk = 0; kk < 16; kk++){
      if (kk < 15){
        #pragma unroll
        for (int nt = 0; nt < 4; nt++)
          bnxt[nt] = *(const short8*)&WvT[(size_t)(cb + nt*16 + j)*512 + (kk+1)*32 + hi*8];
      }
      #pragma unroll
      for (int mt = 0; mt < 8; mt++){
        int row = mt*16 + j;
        short8 afr = *(const short8*)&SA[row*512 + ((((kk << 2) | hi) ^ (row & 7)) << 3)];
        #pragma unroll
        for (int nt = 0; nt < 4; nt++)
          va[mt][nt] = __builtin_amdgcn_mfma_f32_16x16x32_bf16(afr, bcur[nt], va[mt][nt], 0, 0, 0);
      }
      #pragma unroll
      for (int nt = 0; nt < 4; nt++) bcur[nt] = bnxt[nt];
    }
  }

  // ---- att = sum_a w * leaky(V); butterfly over hi groups; coalesced store
  #pragma unroll
  for (int mt = 0; mt < 8; mt++){
    float ap0 = 0.f, ap1 = 0.f, ap2 = 0.f, ap3 = 0.f;
    #pragma unroll
    for (int i = 0; i < 4; i++){
      float wv = wgt[mt][i];
      ap0 += wv * leaky(va[mt][0][i]);
      ap1 += wv * leaky(va[mt][1][i]);
      ap2 += wv * leaky(va[mt][2][i]);
      ap3 += wv * leaky(va[mt][3][i]);
    }
    ap0 += __shfl_xor(ap0, 16); ap0 += __shfl_xor(ap0, 32);
    ap1 += __shfl_xor(ap1, 16); ap1 += __shfl_xor(ap1, 32);
    ap2 += __shfl_xor(ap2, 16); ap2 += __shfl_xor(ap2, 32);
    ap3 += __shfl_xor(ap3, 16); ap3 += __shfl_xor(ap3, 32);
    float val = (hi == 0) ? ap0 : (hi == 1) ? ap1 : (hi == 2) ? ap2 : ap3;
    out[(size_t)(b0 + mt)*512 + cb + lane] = val;
  }
}

extern "C" void kernel_launch(void* const* d_in, const int* in_sizes, int n_in,
                              void* d_out, int out_size, void* d_ws, size_t ws_size,
                              hipStream_t stream) {
  const float* state = (const float*)d_in[0];
  const int*   agp   = (const int*)d_in[1];
  const float* Ws    = (const float*)d_in[2];
  const float* bs    = (const float*)d_in[3];
  const float* Wc    = (const float*)d_in[4];
  const float* bc    = (const float*)d_in[5];
  const float* Wk    = (const float*)d_in[6];
  const float* Wq    = (const float*)d_in[7];
  const float* Wv    = (const float*)d_in[8];
  float* out = (float*)d_out;
  int B = in_sizes[0] / 4096;   // state is (B,16,256)

  char* wsb = (char*)d_ws;
  float* part  = (float*)wsb;                                   // 256*1024*4 = 1 MB
  float* stats = (float*)(wsb + (1 << 20));                     // 4 KB
  float* bsp   = (float*)(wsb + (1 << 20) + 4096);              // 2 KB
  float* bcp   = (float*)(wsb + (1 << 20) + 6144);              // 2 KB
  unsigned short* WsT = (unsigned short*)(wsb + (1 << 20) + 8192);
  unsigned short* WcT = WsT + 512*256;
  unsigned short* WkT = WcT + 512*256;
  unsigned short* WvT = WkT + 512*512;
  unsigned short* WqT = WvT + 512*512;
  unsigned short* Qws = WqT + 512*512;   // B*512 bf16 = 8 MB; total ws ~11.1 MB

  hipLaunchKernelGGL(ca_stats_partial, dim3(256), dim3(256), 0, stream, state, agp, part, B);
  hipLaunchKernelGGL(ca_stats_final,   dim3(1),   dim3(1024), 0, stream, part, stats, 256, B);
  hipLaunchKernelGGL(ca_prep_sc,       dim3(512), dim3(256), 0, stream, Ws, bs, Wc, bc, stats, WsT, WcT, bsp, bcp);
  hipLaunchKernelGGL(ca_prep_kvq,      dim3(1536),dim3(512), 0, stream, Wk, Wv, Wq, WkT, WvT, WqT);
  hipLaunchKernelGGL(ca_q_kernel,      dim3(B/32),dim3(512), 0, stream, state, agp, WsT, bsp, WqT, Qws);
  hipLaunchKernelGGL(ca_main_kernel,   dim3(B/8), dim3(512), 0, stream, state, agp, WcT, bcp, WkT, WvT, Qws, out);
}

// Round 10
// 271.115 us; speedup vs baseline: 1.6378x; 1.1036x over previous
//
#include <hip/hip_runtime.h>

typedef __attribute__((ext_vector_type(8))) short short8;
typedef __attribute__((ext_vector_type(8))) unsigned short ushort8;
typedef __attribute__((ext_vector_type(4))) float f32x4;

__device__ __forceinline__ unsigned short f2bf(float f){
  unsigned int u = __builtin_bit_cast(unsigned int, f);
  u += 0x7fffu + ((u >> 16) & 1u);           // round-to-nearest-even
  return (unsigned short)(u >> 16);
}
__device__ __forceinline__ float bf2f(unsigned short h){
  unsigned int u = ((unsigned int)h) << 16;
  return __builtin_bit_cast(float, u);
}
__device__ __forceinline__ float leaky(float x){ return x > 0.f ? x : 0.3f * x; }

// ---------------- BN statistics: stage 1 (per-block partial sums) ----------------
__global__ __launch_bounds__(256) void ca_stats_partial(const float* __restrict__ state,
    const int* __restrict__ agp, float* __restrict__ part, int B){
  int d = threadIdx.x;
  int ag = agp[0];
  int bPer = (B + 255) >> 8;
  int b0 = blockIdx.x * bPer;
  float sC = 0.f, ssC = 0.f, sO = 0.f, ssO = 0.f;
  for (int b = 0; b < bPer; b++){
    int bb = b0 + b;
    if (bb >= B) break;
    const float* row = state + ((size_t)bb << 12);   // *16*256
    #pragma unroll
    for (int a = 0; a < 16; a++){
      float v = row[a*256 + d];
      bool isC = (a == ag);
      sC  += isC ? v   : 0.f;
      ssC += isC ? v*v : 0.f;
      sO  += isC ? 0.f : v;
      ssO += isC ? 0.f : v*v;
    }
  }
  float* p = part + (size_t)blockIdx.x * 1024;
  p[d] = sC; p[d+256] = ssC; p[d+512] = sO; p[d+768] = ssO;
}

// ---------------- BN statistics: stage 2 (finalize rs, mean*rs), 1024 threads ----------------
__global__ __launch_bounds__(1024) void ca_stats_final(const float* __restrict__ part,
    float* __restrict__ stats, int nblk, int B){
  int d = threadIdx.x & 255, sl = threadIdx.x >> 8;
  float sC = 0.f, ssC = 0.f, sO = 0.f, ssO = 0.f;
  for (int g = sl; g < nblk; g += 4){
    const float* p = part + (size_t)g * 1024;
    sC += p[d]; ssC += p[d+256]; sO += p[d+512]; ssO += p[d+768];
  }
  __shared__ float red[4][4][256];
  red[sl][0][d] = sC; red[sl][1][d] = ssC; red[sl][2][d] = sO; red[sl][3][d] = ssO;
  __syncthreads();
  if (sl == 0){
    sC  = red[0][0][d] + red[1][0][d] + red[2][0][d] + red[3][0][d];
    ssC = red[0][1][d] + red[1][1][d] + red[2][1][d] + red[3][1][d];
    sO  = red[0][2][d] + red[1][2][d] + red[2][2][d] + red[3][2][d];
    ssO = red[0][3][d] + red[1][3][d] + red[2][3][d] + red[3][3][d];
    float nC = (float)B, nO = (float)B * 15.f;
    float mC = sC / nC, vC = ssC / nC - mC * mC;
    float mO = sO / nO, vO = ssO / nO - mO * mO;
    float rC = rsqrtf(vC + 1e-3f), rO = rsqrtf(vO + 1e-3f);
    stats[d] = rC; stats[d+256] = mC * rC; stats[d+512] = rO; stats[d+768] = mO * rO;
  }
}

// ---------------- weight prep: WsT/WcT (bf16, transposed, rs-folded) + biases ----------------
__global__ __launch_bounds__(256) void ca_prep_sc(const float* __restrict__ Ws,
    const float* __restrict__ bs, const float* __restrict__ Wc, const float* __restrict__ bc,
    const float* __restrict__ stats, unsigned short* __restrict__ WsT,
    unsigned short* __restrict__ WcT, float* __restrict__ bsp, float* __restrict__ bcp){
  int n = blockIdx.x, d = threadIdx.x;
  float rC = stats[d], mrC = stats[d+256], rO = stats[d+512], mrO = stats[d+768];
  float ws = Ws[(size_t)d*512 + n], wc = Wc[(size_t)d*512 + n];
  WsT[(size_t)n*256 + d] = f2bf(ws * rC);
  WcT[(size_t)n*256 + d] = f2bf(wc * rO);
  __shared__ float red[256];
  red[d] = mrC * ws;
  __syncthreads();
  for (int s = 128; s > 0; s >>= 1){ if (d < s) red[d] += red[d+s]; __syncthreads(); }
  if (d == 0) bsp[n] = bs[n] - red[0];
  __syncthreads();
  red[d] = mrO * wc;
  __syncthreads();
  for (int s = 128; s > 0; s >>= 1){ if (d < s) red[d] += red[d+s]; __syncthreads(); }
  if (d == 0) bcp[n] = bc[n] - red[0];
}

// ---------------- weight prep: WkT/WvT/WqT (transposed) + Wkbf (flat cast) ----------------
__global__ __launch_bounds__(512) void ca_prep_kvq(const float* __restrict__ Wk,
    const float* __restrict__ Wv, const float* __restrict__ Wq,
    unsigned short* __restrict__ WkT, unsigned short* __restrict__ WvT,
    unsigned short* __restrict__ WqT, unsigned short* __restrict__ Wkbf){
  int c = blockIdx.x & 511, m = blockIdx.x >> 9;
  int n = threadIdx.x;
  if (m == 3){   // flat bf16 cast of Wk[h][n][d] (layout already d-contiguous)
    size_t idx = (size_t)c*512 + n;
    Wkbf[idx] = f2bf(Wk[idx]);
    return;
  }
  int h = c >> 6, dd = c & 63;
  const float* W = (m == 0) ? Wk : (m == 1) ? Wv : Wq;
  unsigned short* O = (m == 0) ? WkT : (m == 1) ? WvT : WqT;
  float scale = (m == 2) ? 0.125f : 1.f;
  O[(size_t)c*512 + n] = f2bf(W[((size_t)h*512 + n)*64 + dd] * scale);
}

// ---------------- Q kernel (fallback path): s_enc -> q -> Qws  (32 b-rows / block) ----------------
__global__ __launch_bounds__(512) void ca_q_kernel(const float* __restrict__ state,
    const int* __restrict__ agp,
    const unsigned short* __restrict__ WsT, const float* __restrict__ bsp,
    const unsigned short* __restrict__ WqT, unsigned short* __restrict__ Qws){
  __shared__ unsigned short U[32*512];
  __shared__ float bias_s[512];
  unsigned short* Alds = U;
  unsigned short* SE = U;
  int tid = threadIdx.x, lane = tid & 63, w = tid >> 6;
  int j = lane & 15, hi = lane >> 4;
  int b0 = blockIdx.x * 32;
  int ag = agp[0];

  for (int s = tid; s < 32*32; s += 512){
    int row = s >> 5, kg = s & 31;
    const float* p = state + (((size_t)(b0 + row) * 16 + ag) << 8) + kg * 8;
    f32x4 v0 = *(const f32x4*)p, v1 = *(const f32x4*)(p + 4);
    ushort8 hv;
    hv[0]=f2bf(v0[0]); hv[1]=f2bf(v0[1]); hv[2]=f2bf(v0[2]); hv[3]=f2bf(v0[3]);
    hv[4]=f2bf(v1[0]); hv[5]=f2bf(v1[1]); hv[6]=f2bf(v1[2]); hv[7]=f2bf(v1[3]);
    *(ushort8*)&Alds[row*256 + ((kg ^ (row & 7)) << 3)] = hv;
  }
  bias_s[tid & 511] = bsp[tid & 511];
  __syncthreads();

  int cb = w * 64;
  f32x4 zero4 = {0.f, 0.f, 0.f, 0.f};
  f32x4 acc[2][4];
  #pragma unroll
  for (int a1 = 0; a1 < 2; a1++)
    #pragma unroll
    for (int a2 = 0; a2 < 4; a2++) acc[a1][a2] = zero4;

  #pragma unroll
  for (int kk = 0; kk < 8; kk++){
    short8 bfr[4];
    #pragma unroll
    for (int nt = 0; nt < 4; nt++)
      bfr[nt] = *(const short8*)&WsT[(size_t)(cb + nt*16 + j)*256 + kk*32 + hi*8];
    #pragma unroll
    for (int mt = 0; mt < 2; mt++){
      int row = mt*16 + j;
      short8 afr = *(const short8*)&Alds[row*256 + ((((kk << 2) | hi) ^ (row & 7)) << 3)];
      #pragma unroll
      for (int nt = 0; nt < 4; nt++)
        acc[mt][nt] = __builtin_amdgcn_mfma_f32_16x16x32_bf16(afr, bfr[nt], acc[mt][nt], 0, 0, 0);
    }
  }
  __syncthreads();
  #pragma unroll
  for (int mt = 0; mt < 2; mt++)
    #pragma unroll
    for (int nt = 0; nt < 4; nt++)
      #pragma unroll
      for (int i = 0; i < 4; i++){
        int row = mt*16 + hi*4 + i, col = cb + nt*16 + j;
        float x = leaky(acc[mt][nt][i] + bias_s[col]);
        SE[row*512 + ((((col >> 3) ^ (row & 7)) << 3) | (col & 7))] = f2bf(x);
      }
  __syncthreads();

  f32x4 qa[2][4];
  #pragma unroll
  for (int a1 = 0; a1 < 2; a1++)
    #pragma unroll
    for (int a2 = 0; a2 < 4; a2++) qa[a1][a2] = zero4;
  #pragma unroll
  for (int kk = 0; kk < 16; kk++){
    short8 bfr[4];
    #pragma unroll
    for (int nt = 0; nt < 4; nt++)
      bfr[nt] = *(const short8*)&WqT[(size_t)(cb + nt*16 + j)*512 + kk*32 + hi*8];
    #pragma unroll
    for (int mt = 0; mt < 2; mt++){
      int row = mt*16 + j;
      short8 afr = *(const short8*)&SE[row*512 + ((((kk << 2) | hi) ^ (row & 7)) << 3)];
      #pragma unroll
      for (int nt = 0; nt < 4; nt++)
        qa[mt][nt] = __builtin_amdgcn_mfma_f32_16x16x32_bf16(afr, bfr[nt], qa[mt][nt], 0, 0, 0);
    }
  }
  #pragma unroll
  for (int mt = 0; mt < 2; mt++)
    #pragma unroll
    for (int nt = 0; nt < 4; nt++)
      #pragma unroll
      for (int i = 0; i < 4; i++)
        Qws[(size_t)(b0 + mt*16 + hi*4 + i)*512 + cb + nt*16 + j] = f2bf(qa[mt][nt][i]);
}

// ---------------- Q kernel (qk path): s_enc -> q -> qk = q@Wk^T -> QKws[b][8][512] ----------------
__global__ __launch_bounds__(512) void ca_q_kernel_qk(const float* __restrict__ state,
    const int* __restrict__ agp,
    const unsigned short* __restrict__ WsT, const float* __restrict__ bsp,
    const unsigned short* __restrict__ WqT, const unsigned short* __restrict__ Wkbf,
    unsigned short* __restrict__ QKws){
  __shared__ unsigned short U[32*512];      // 32KB union: Alds / SE / Qlds
  __shared__ float bias_s[512];
  unsigned short* Alds = U;
  unsigned short* SE = U;
  unsigned short* Qlds = U;
  int tid = threadIdx.x, lane = tid & 63, w = tid >> 6;
  int j = lane & 15, hi = lane >> 4;
  int b0 = blockIdx.x * 32;
  int ag = agp[0];

  for (int s = tid; s < 32*32; s += 512){
    int row = s >> 5, kg = s & 31;
    const float* p = state + (((size_t)(b0 + row) * 16 + ag) << 8) + kg * 8;
    f32x4 v0 = *(const f32x4*)p, v1 = *(const f32x4*)(p + 4);
    ushort8 hv;
    hv[0]=f2bf(v0[0]); hv[1]=f2bf(v0[1]); hv[2]=f2bf(v0[2]); hv[3]=f2bf(v0[3]);
    hv[4]=f2bf(v1[0]); hv[5]=f2bf(v1[1]); hv[6]=f2bf(v1[2]); hv[7]=f2bf(v1[3]);
    *(ushort8*)&Alds[row*256 + ((kg ^ (row & 7)) << 3)] = hv;
  }
  bias_s[tid & 511] = bsp[tid & 511];
  __syncthreads();

  int cb = w * 64;
  f32x4 zero4 = {0.f, 0.f, 0.f, 0.f};
  f32x4 acc[2][4];
  #pragma unroll
  for (int a1 = 0; a1 < 2; a1++)
    #pragma unroll
    for (int a2 = 0; a2 < 4; a2++) acc[a1][a2] = zero4;

  #pragma unroll
  for (int kk = 0; kk < 8; kk++){
    short8 bfr[4];
    #pragma unroll
    for (int nt = 0; nt < 4; nt++)
      bfr[nt] = *(const short8*)&WsT[(size_t)(cb + nt*16 + j)*256 + kk*32 + hi*8];
    #pragma unroll
    for (int mt = 0; mt < 2; mt++){
      int row = mt*16 + j;
      short8 afr = *(const short8*)&Alds[row*256 + ((((kk << 2) | hi) ^ (row & 7)) << 3)];
      #pragma unroll
      for (int nt = 0; nt < 4; nt++)
        acc[mt][nt] = __builtin_amdgcn_mfma_f32_16x16x32_bf16(afr, bfr[nt], acc[mt][nt], 0, 0, 0);
    }
  }
  __syncthreads();   // Alds dead; SE overlays it
  #pragma unroll
  for (int mt = 0; mt < 2; mt++)
    #pragma unroll
    for (int nt = 0; nt < 4; nt++)
      #pragma unroll
      for (int i = 0; i < 4; i++){
        int row = mt*16 + hi*4 + i, col = cb + nt*16 + j;
        float x = leaky(acc[mt][nt][i] + bias_s[col]);
        SE[row*512 + ((((col >> 3) ^ (row & 7)) << 3) | (col & 7))] = f2bf(x);
      }
  __syncthreads();

  // q = s_enc @ WqT (1/8 folded), kept in registers
  f32x4 qa[2][4];
  #pragma unroll
  for (int a1 = 0; a1 < 2; a1++)
    #pragma unroll
    for (int a2 = 0; a2 < 4; a2++) qa[a1][a2] = zero4;
  #pragma unroll
  for (int kk = 0; kk < 16; kk++){
    short8 bfr[4];
    #pragma unroll
    for (int nt = 0; nt < 4; nt++)
      bfr[nt] = *(const short8*)&WqT[(size_t)(cb + nt*16 + j)*512 + kk*32 + hi*8];
    #pragma unroll
    for (int mt = 0; mt < 2; mt++){
      int row = mt*16 + j;
      short8 afr = *(const short8*)&SE[row*512 + ((((kk << 2) | hi) ^ (row & 7)) << 3)];
      #pragma unroll
      for (int nt = 0; nt < 4; nt++)
        qa[mt][nt] = __builtin_amdgcn_mfma_f32_16x16x32_bf16(afr, bfr[nt], qa[mt][nt], 0, 0, 0);
    }
  }
  __syncthreads();   // SE dead; Qlds overlays it
  #pragma unroll
  for (int mt = 0; mt < 2; mt++)
    #pragma unroll
    for (int nt = 0; nt < 4; nt++)
      #pragma unroll
      for (int i = 0; i < 4; i++){
        int row = mt*16 + hi*4 + i, col = cb + nt*16 + j;
        Qlds[row*512 + ((((col >> 3) ^ (row & 7)) << 3) | (col & 7))] = f2bf(qa[mt][nt][i]);
      }
  __syncthreads();

  // qk[b][h=w][n] = sum_d q[b][w*64+d] * Wk[w][n][d]  (M=32 batches, K=64, N=512)
  short8 aq[2][2];
  #pragma unroll
  for (int mt = 0; mt < 2; mt++)
    #pragma unroll
    for (int kq = 0; kq < 2; kq++){
      int row = mt*16 + j;
      int col = w*64 + kq*32 + hi*8;
      aq[mt][kq] = *(const short8*)&Qlds[row*512 + ((((col >> 3) ^ (row & 7)) << 3))];
    }
  for (int nt = 0; nt < 32; nt++){
    f32x4 q0 = zero4, q1 = zero4;
    #pragma unroll
    for (int kq = 0; kq < 2; kq++){
      short8 bf = *(const short8*)&Wkbf[(size_t)(w*512 + nt*16 + j)*64 + kq*32 + hi*8];
      q0 = __builtin_amdgcn_mfma_f32_16x16x32_bf16(aq[0][kq], bf, q0, 0, 0, 0);
      q1 = __builtin_amdgcn_mfma_f32_16x16x32_bf16(aq[1][kq], bf, q1, 0, 0, 0);
    }
    #pragma unroll
    for (int i = 0; i < 4; i++){
      QKws[((size_t)(b0 + hi*4 + i)*8 + w)*512 + nt*16 + j]      = f2bf(q0[i]);
      QKws[((size_t)(b0 + 16 + hi*4 + i)*8 + w)*512 + nt*16 + j] = f2bf(q1[i]);
    }
  }
}

// ---------------- main kernel (qk path): sa_enc -> scores(qk) -> softmax -> V -> att ----------------
// 8 batches (128 rows)/block, 8 waves. K-GEMM replaced by a 16-MFMA scores tile per
// wave (M=16 agents, N=16 heads(8 valid), K=512) fed from QKws; V-GEMM unchanged.
__global__ __launch_bounds__(512) void ca_main_kernel_qk(const float* __restrict__ state,
    const int* __restrict__ agp,
    const unsigned short* __restrict__ WcT, const float* __restrict__ bcp,
    const unsigned short* __restrict__ WvT, const unsigned short* __restrict__ QKws,
    float* __restrict__ out){
  __shared__ unsigned short U[128*512];     // 128KB union: Alds (first 64KB), then SA
  __shared__ float bias_s[512];
  __shared__ float Wl[8*16*8];              // wgt[b][a][h], 4KB
  unsigned short* Alds = U;
  unsigned short* SA = U;
  int tid = threadIdx.x, lane = tid & 63, w = tid >> 6;
  int j = lane & 15, hi = lane >> 4;
  int b0 = blockIdx.x * 8;
  int ag = agp[0];
  f32x4 zero4 = {0.f, 0.f, 0.f, 0.f};
  short8 zero8 = {0,0,0,0,0,0,0,0};

  #pragma unroll
  for (int g = 0; g < 2; g++){
    f32x4 st0[4], st1[4];
    #pragma unroll
    for (int it = 0; it < 4; it++){
      int s = tid + 512*(g*4 + it);
      int row = s >> 5, kg = s & 31;
      int bl = row >> 4, ai = row & 15;
      if (ai < 15){
        int a = ai + (ai >= ag ? 1 : 0);
        const float* p = state + (((size_t)(b0 + bl) * 16 + a) << 8) + kg * 8;
        st0[it] = *(const f32x4*)p;
        st1[it] = *(const f32x4*)(p + 4);
      } else { st0[it] = zero4; st1[it] = zero4; }
    }
    #pragma unroll
    for (int it = 0; it < 4; it++){
      int s = tid + 512*(g*4 + it);
      int row = s >> 5, kg = s & 31;
      ushort8 hv;
      hv[0]=f2bf(st0[it][0]); hv[1]=f2bf(st0[it][1]); hv[2]=f2bf(st0[it][2]); hv[3]=f2bf(st0[it][3]);
      hv[4]=f2bf(st1[it][0]); hv[5]=f2bf(st1[it][1]); hv[6]=f2bf(st1[it][2]); hv[7]=f2bf(st1[it][3]);
      *(ushort8*)&Alds[row*256 + ((kg ^ (row & 7)) << 3)] = hv;
    }
  }
  bias_s[tid] = bcp[tid];
  __syncthreads();

  int cb = w * 64;

  // ---- GEMM1: sa_enc rows [0,128) x cols [cb,cb+64)
  f32x4 acc[8][4];
  #pragma unroll
  for (int a1 = 0; a1 < 8; a1++)
    #pragma unroll
    for (int a2 = 0; a2 < 4; a2++) acc[a1][a2] = zero4;
  {
    short8 bcur[4], bnxt[4];
    #pragma unroll
    for (int nt = 0; nt < 4; nt++)
      bcur[nt] = *(const short8*)&WcT[(size_t)(cb + nt*16 + j)*256 + hi*8];
    #pragma unroll 1
    for (int kk = 0; kk < 8; kk++){
      if (kk < 7){
        #pragma unroll
        for (int nt = 0; nt < 4; nt++)
          bnxt[nt] = *(const short8*)&WcT[(size_t)(cb + nt*16 + j)*256 + (kk+1)*32 + hi*8];
      }
      #pragma unroll
      for (int mt = 0; mt < 8; mt++){
        int row = mt*16 + j;
        short8 afr = *(const short8*)&Alds[row*256 + ((((kk << 2) | hi) ^ (row & 7)) << 3)];
        #pragma unroll
        for (int nt = 0; nt < 4; nt++)
          acc[mt][nt] = __builtin_amdgcn_mfma_f32_16x16x32_bf16(afr, bcur[nt], acc[mt][nt], 0, 0, 0);
      }
      #pragma unroll
      for (int nt = 0; nt < 4; nt++) bcur[nt] = bnxt[nt];
    }
  }
  __syncthreads();
  #pragma unroll
  for (int mt = 0; mt < 8; mt++)
    #pragma unroll
    for (int nt = 0; nt < 4; nt++)
      #pragma unroll
      for (int i = 0; i < 4; i++){
        int row = mt*16 + hi*4 + i, col = cb + nt*16 + j;
        float x = leaky(acc[mt][nt][i] + bias_s[col]);
        SA[row*512 + ((((col >> 3) ^ (row & 7)) << 3) | (col & 7))] = f2bf(x);
      }
  __syncthreads();

  // ---- scores for batch b0+w: M=16 agents x N=16 heads(8 valid), K=512
  f32x4 qs = zero4;
  {
    size_t qbase = ((size_t)(b0 + w)*8 + (j & 7))*512;
    #pragma unroll
    for (int kk = 0; kk < 16; kk++){
      short8 bq = *(const short8*)&QKws[qbase + kk*32 + hi*8];
      if (j >= 8) bq = zero8;
      int row = w*16 + j;
      short8 afr = *(const short8*)&SA[row*512 + ((((kk << 2) | hi) ^ (row & 7)) << 3)];
      qs = __builtin_amdgcn_mfma_f32_16x16x32_bf16(afr, bq, qs, 0, 0, 0);
    }
  }
  // softmax over agents (rows) per head col j; lane holds scores[a=hi*4+i][h=j]
  {
    float sv0 = qs[0], sv1 = qs[1], sv2 = qs[2], sv3 = qs[3];
    sv3 = (hi == 3) ? -1e30f : sv3;         // mask pad agent a=15
    float m = fmaxf(fmaxf(sv0, sv1), fmaxf(sv2, sv3));
    m = fmaxf(m, __shfl_xor(m, 16)); m = fmaxf(m, __shfl_xor(m, 32));
    float e0 = __expf(sv0-m), e1 = __expf(sv1-m), e2 = __expf(sv2-m), e3 = __expf(sv3-m);
    float sum = e0 + e1 + e2 + e3;
    sum += __shfl_xor(sum, 16); sum += __shfl_xor(sum, 32);
    float inv = 1.f / sum;
    if (j < 8){
      Wl[w*128 + (hi*4+0)*8 + j] = e0*inv;
      Wl[w*128 + (hi*4+1)*8 + j] = e1*inv;
      Wl[w*128 + (hi*4+2)*8 + j] = e2*inv;
      Wl[w*128 + (hi*4+3)*8 + j] = e3*inv;
    }
  }

  // ---- GEMM2-V
  f32x4 va[8][4];
  #pragma unroll
  for (int a1 = 0; a1 < 8; a1++)
    #pragma unroll
    for (int a2 = 0; a2 < 4; a2++) va[a1][a2] = zero4;
  {
    short8 bcur[4], bnxt[4];
    #pragma unroll
    for (int nt = 0; nt < 4; nt++)
      bcur[nt] = *(const short8*)&WvT[(size_t)(cb + nt*16 + j)*512 + hi*8];
    #pragma unroll 1
    for (int kk = 0; kk < 16; kk++){
      if (kk < 15){
        #pragma unroll
        for (int nt = 0; nt < 4; nt++)
          bnxt[nt] = *(const short8*)&WvT[(size_t)(cb + nt*16 + j)*512 + (kk+1)*32 + hi*8];
      }
      #pragma unroll
      for (int mt = 0; mt < 8; mt++){
        int row = mt*16 + j;
        short8 afr = *(const short8*)&SA[row*512 + ((((kk << 2) | hi) ^ (row & 7)) << 3)];
        #pragma unroll
        for (int nt = 0; nt < 4; nt++)
          va[mt][nt] = __builtin_amdgcn_mfma_f32_16x16x32_bf16(afr, bcur[nt], va[mt][nt], 0, 0, 0);
      }
      #pragma unroll
      for (int nt = 0; nt < 4; nt++) bcur[nt] = bnxt[nt];
    }
  }
  __syncthreads();   // Wl writes (pre-V) now visible to all waves

  // ---- att = sum_a wgt * leaky(V); wave w = head w reads wgt[mt][a][w]
  #pragma unroll
  for (int mt = 0; mt < 8; mt++){
    float w0 = Wl[mt*128 + (hi*4+0)*8 + w];
    float w1 = Wl[mt*128 + (hi*4+1)*8 + w];
    float w2 = Wl[mt*128 + (hi*4+2)*8 + w];
    float w3 = Wl[mt*128 + (hi*4+3)*8 + w];
    float ap0 = w0*leaky(va[mt][0][0]) + w1*leaky(va[mt][0][1]) + w2*leaky(va[mt][0][2]) + w3*leaky(va[mt][0][3]);
    float ap1 = w0*leaky(va[mt][1][0]) + w1*leaky(va[mt][1][1]) + w2*leaky(va[mt][1][2]) + w3*leaky(va[mt][1][3]);
    float ap2 = w0*leaky(va[mt][2][0]) + w1*leaky(va[mt][2][1]) + w2*leaky(va[mt][2][2]) + w3*leaky(va[mt][2][3]);
    float ap3 = w0*leaky(va[mt][3][0]) + w1*leaky(va[mt][3][1]) + w2*leaky(va[mt][3][2]) + w3*leaky(va[mt][3][3]);
    ap0 += __shfl_xor(ap0, 16); ap0 += __shfl_xor(ap0, 32);
    ap1 += __shfl_xor(ap1, 16); ap1 += __shfl_xor(ap1, 32);
    ap2 += __shfl_xor(ap2, 16); ap2 += __shfl_xor(ap2, 32);
    ap3 += __shfl_xor(ap3, 16); ap3 += __shfl_xor(ap3, 32);
    float val = (hi == 0) ? ap0 : (hi == 1) ? ap1 : (hi == 2) ? ap2 : ap3;
    out[(size_t)(b0 + mt)*512 + cb + lane] = val;
  }
}

// ---------------- main kernel (fallback = R9) ----------------
__global__ __launch_bounds__(512) void ca_main_kernel(const float* __restrict__ state,
    const int* __restrict__ agp,
    const unsigned short* __restrict__ WcT, const float* __restrict__ bcp,
    const unsigned short* __restrict__ WkT, const unsigned short* __restrict__ WvT,
    const unsigned short* __restrict__ Qws, float* __restrict__ out){
  __shared__ unsigned short U[128*512];
  __shared__ unsigned short Qs[8*512];
  __shared__ float bias_s[512];
  unsigned short* Alds = U;
  unsigned short* SA = U;
  int tid = threadIdx.x, lane = tid & 63, w = tid >> 6;
  int j = lane & 15, hi = lane >> 4;
  int b0 = blockIdx.x * 8;
  int ag = agp[0];
  f32x4 zero4 = {0.f, 0.f, 0.f, 0.f};

  #pragma unroll
  for (int g = 0; g < 2; g++){
    f32x4 st0[4], st1[4];
    #pragma unroll
    for (int it = 0; it < 4; it++){
      int s = tid + 512*(g*4 + it);
      int row = s >> 5, kg = s & 31;
      int bl = row >> 4, ai = row & 15;
      if (ai < 15){
        int a = ai + (ai >= ag ? 1 : 0);
        const float* p = state + (((size_t)(b0 + bl) * 16 + a) << 8) + kg * 8;
        st0[it] = *(const f32x4*)p;
        st1[it] = *(const f32x4*)(p + 4);
      } else { st0[it] = zero4; st1[it] = zero4; }
    }
    #pragma unroll
    for (int it = 0; it < 4; it++){
      int s = tid + 512*(g*4 + it);
      int row = s >> 5, kg = s & 31;
      ushort8 hv;
      hv[0]=f2bf(st0[it][0]); hv[1]=f2bf(st0[it][1]); hv[2]=f2bf(st0[it][2]); hv[3]=f2bf(st0[it][3]);
      hv[4]=f2bf(st1[it][0]); hv[5]=f2bf(st1[it][1]); hv[6]=f2bf(st1[it][2]); hv[7]=f2bf(st1[it][3]);
      *(ushort8*)&Alds[row*256 + ((kg ^ (row & 7)) << 3)] = hv;
    }
  }
  *(ushort8*)&Qs[tid*8] = *(const ushort8*)&Qws[(size_t)b0*512 + tid*8];
  bias_s[tid] = bcp[tid];
  __syncthreads();

  int cb = w * 64;

  f32x4 acc[8][4];
  #pragma unroll
  for (int a1 = 0; a1 < 8; a1++)
    #pragma unroll
    for (int a2 = 0; a2 < 4; a2++) acc[a1][a2] = zero4;
  {
    short8 bcur[4], bnxt[4];
    #pragma unroll
    for (int nt = 0; nt < 4; nt++)
      bcur[nt] = *(const short8*)&WcT[(size_t)(cb + nt*16 + j)*256 + hi*8];
    #pragma unroll 1
    for (int kk = 0; kk < 8; kk++){
      if (kk < 7){
        #pragma unroll
        for (int nt = 0; nt < 4; nt++)
          bnxt[nt] = *(const short8*)&WcT[(size_t)(cb + nt*16 + j)*256 + (kk+1)*32 + hi*8];
      }
      #pragma unroll
      for (int mt = 0; mt < 8; mt++){
        int row = mt*16 + j;
        short8 afr = *(const short8*)&Alds[row*256 + ((((kk << 2) | hi) ^ (row & 7)) << 3)];
        #pragma unroll
        for (int nt = 0; nt < 4; nt++)
          acc[mt][nt] = __builtin_amdgcn_mfma_f32_16x16x32_bf16(afr, bcur[nt], acc[mt][nt], 0, 0, 0);
      }
      #pragma unroll
      for (int nt = 0; nt < 4; nt++) bcur[nt] = bnxt[nt];
    }
  }
  __syncthreads();
  #pragma unroll
  for (int mt = 0; mt < 8; mt++)
    #pragma unroll
    for (int nt = 0; nt < 4; nt++)
      #pragma unroll
      for (int i = 0; i < 4; i++){
        int row = mt*16 + hi*4 + i, col = cb + nt*16 + j;
        float x = leaky(acc[mt][nt][i] + bias_s[col]);
        SA[row*512 + ((((col >> 3) ^ (row & 7)) << 3) | (col & 7))] = f2bf(x);
      }
  __syncthreads();

  f32x4 ka[8][4];
  #pragma unroll
  for (int a1 = 0; a1 < 8; a1++)
    #pragma unroll
    for (int a2 = 0; a2 < 4; a2++) ka[a1][a2] = zero4;
  {
    short8 bcur[4], bnxt[4];
    #pragma unroll
    for (int nt = 0; nt < 4; nt++)
      bcur[nt] = *(const short8*)&WkT[(size_t)(cb + nt*16 + j)*512 + hi*8];
    #pragma unroll 1
    for (int kk = 0; kk < 16; kk++){
      if (kk < 15){
        #pragma unroll
        for (int nt = 0; nt < 4; nt++)
          bnxt[nt] = *(const short8*)&WkT[(size_t)(cb + nt*16 + j)*512 + (kk+1)*32 + hi*8];
      }
      #pragma unroll
      for (int mt = 0; mt < 8; mt++){
        int row = mt*16 + j;
        short8 afr = *(const short8*)&SA[row*512 + ((((kk << 2) | hi) ^ (row & 7)) << 3)];
        #pragma unroll
        for (int nt = 0; nt < 4; nt++)
          ka[mt][nt] = __builtin_amdgcn_mfma_f32_16x16x32_bf16(afr, bcur[nt], ka[mt][nt], 0, 0, 0);
      }
      #pragma unroll
      for (int nt = 0; nt < 4; nt++) bcur[nt] = bnxt[nt];
    }
  }

  float wgt[8][4];
  #pragma unroll
  for (int mt = 0; mt < 8; mt++){
    float sv[4];
    #pragma unroll
    for (int i = 0; i < 4; i++){
      float t = 0.f;
      #pragma unroll
      for (int nt = 0; nt < 4; nt++)
        t += bf2f(Qs[mt*512 + cb + nt*16 + j]) * ka[mt][nt][i];
      t += __shfl_xor(t, 1); t += __shfl_xor(t, 2);
      t += __shfl_xor(t, 4); t += __shfl_xor(t, 8);
      sv[i] = t;
    }
    sv[3] = (hi == 3) ? -1e30f : sv[3];
    float m = fmaxf(fmaxf(sv[0], sv[1]), fmaxf(sv[2], sv[3]));
    m = fmaxf(m, __shfl_xor(m, 16)); m = fmaxf(m, __shfl_xor(m, 32));
    float e0 = __expf(sv[0]-m), e1 = __expf(sv[1]-m), e2 = __expf(sv[2]-m), e3 = __expf(sv[3]-m);
    float sum = e0 + e1 + e2 + e3;
    sum += __shfl_xor(sum, 16); sum += __shfl_xor(sum, 32);
    float inv = 1.f / sum;
    wgt[mt][0] = e0*inv; wgt[mt][1] = e1*inv; wgt[mt][2] = e2*inv; wgt[mt][3] = e3*inv;
  }

  f32x4 va[8][4];
  #pragma unroll
  for (int a1 = 0; a1 < 8; a1++)
    #pragma unroll
    for (int a2 = 0; a2 < 4; a2++) va[a1][a2] = zero4;
  {
    short8 bcur[4], bnxt[4];
    #pragma unroll
    for (int nt = 0; nt < 4; nt++)
      bcur[nt] = *(const short8*)&WvT[(size_t)(cb + nt*16 + j)*512 + hi*8];
    #pragma unroll 1
    for (int kk = 0; kk < 16; kk++){
      if (kk < 15){
        #pragma unroll
        for (int nt = 0; nt < 4; nt++)
          bnxt[nt] = *(const short8*)&WvT[(size_t)(cb + nt*16 + j)*512 + (kk+1)*32 + hi*8];
      }
      #pragma unroll
      for (int mt = 0; mt < 8; mt++){
        int row = mt*16 + j;
        short8 afr = *(const short8*)&SA[row*512 + ((((kk << 2) | hi) ^ (row & 7)) << 3)];
        #pragma unroll
        for (int nt = 0; nt < 4; nt++)
          va[mt][nt] = __builtin_amdgcn_mfma_f32_16x16x32_bf16(afr, bcur[nt], va[mt][nt], 0, 0, 0);
      }
      #pragma unroll
      for (int nt = 0; nt < 4; nt++) bcur[nt] = bnxt[nt];
    }
  }

  #pragma unroll
  for (int mt = 0; mt < 8; mt++){
    float ap0 = 0.f, ap1 = 0.f, ap2 = 0.f, ap3 = 0.f;
    #pragma unroll
    for (int i = 0; i < 4; i++){
      float wv = wgt[mt][i];
      ap0 += wv * leaky(va[mt][0][i]);
      ap1 += wv * leaky(va[mt][1][i]);
      ap2 += wv * leaky(va[mt][2][i]);
      ap3 += wv * leaky(va[mt][3][i]);
    }
    ap0 += __shfl_xor(ap0, 16); ap0 += __shfl_xor(ap0, 32);
    ap1 += __shfl_xor(ap1, 16); ap1 += __shfl_xor(ap1, 32);
    ap2 += __shfl_xor(ap2, 16); ap2 += __shfl_xor(ap2, 32);
    ap3 += __shfl_xor(ap3, 16); ap3 += __shfl_xor(ap3, 32);
    float val = (hi == 0) ? ap0 : (hi == 1) ? ap1 : (hi == 2) ? ap2 : ap3;
    out[(size_t)(b0 + mt)*512 + cb + lane] = val;
  }
}

extern "C" void kernel_launch(void* const* d_in, const int* in_sizes, int n_in,
                              void* d_out, int out_size, void* d_ws, size_t ws_size,
                              hipStream_t stream) {
  const float* state = (const float*)d_in[0];
  const int*   agp   = (const int*)d_in[1];
  const float* Ws    = (const float*)d_in[2];
  const float* bs    = (const float*)d_in[3];
  const float* Wc    = (const float*)d_in[4];
  const float* bc    = (const float*)d_in[5];
  const float* Wk    = (const float*)d_in[6];
  const float* Wq    = (const float*)d_in[7];
  const float* Wv    = (const float*)d_in[8];
  float* out = (float*)d_out;
  int B = in_sizes[0] / 4096;   // state is (B,16,256)

  char* wsb = (char*)d_ws;
  float* part  = (float*)wsb;                                   // 1 MB
  float* stats = (float*)(wsb + (1 << 20));                     // 4 KB
  float* bsp   = (float*)(wsb + (1 << 20) + 4096);              // 2 KB
  float* bcp   = (float*)(wsb + (1 << 20) + 6144);              // 2 KB
  unsigned short* WsT  = (unsigned short*)(wsb + (1 << 20) + 8192);
  unsigned short* WcT  = WsT  + 512*256;
  unsigned short* WkT  = WcT  + 512*256;
  unsigned short* WvT  = WkT  + 512*512;
  unsigned short* WqT  = WvT  + 512*512;
  unsigned short* Wkbf = WqT  + 512*512;         // 8*512*64 = 262144
  unsigned short* Qws  = Wkbf + 512*512;         // B*512
  unsigned short* QKws = Qws  + (size_t)B*512;   // B*8*512

  size_t need = ((size_t)(1 << 20) + 8192)
              + 2ull*(512*256 + 512*256 + 512*512 + 512*512 + 512*512 + 512*512)
              + 2ull*B*512 + 2ull*B*8*512;
  bool qkp = (ws_size >= need);

  hipLaunchKernelGGL(ca_stats_partial, dim3(256), dim3(256), 0, stream, state, agp, part, B);
  hipLaunchKernelGGL(ca_stats_final,   dim3(1),   dim3(1024), 0, stream, part, stats, 256, B);
  hipLaunchKernelGGL(ca_prep_sc,       dim3(512), dim3(256), 0, stream, Ws, bs, Wc, bc, stats, WsT, WcT, bsp, bcp);
  hipLaunchKernelGGL(ca_prep_kvq,      dim3(2048),dim3(512), 0, stream, Wk, Wv, Wq, WkT, WvT, WqT, Wkbf);
  if (qkp){
    hipLaunchKernelGGL(ca_q_kernel_qk,   dim3(B/32),dim3(512), 0, stream, state, agp, WsT, bsp, WqT, Wkbf, QKws);
    hipLaunchKernelGGL(ca_main_kernel_qk,dim3(B/8), dim3(512), 0, stream, state, agp, WcT, bcp, WvT, QKws, out);
  } else {
    hipLaunchKernelGGL(ca_q_kernel,      dim3(B/32),dim3(512), 0, stream, state, agp, WsT, bsp, WqT, Qws);
    hipLaunchKernelGGL(ca_main_kernel,   dim3(B/8), dim3(512), 0, stream, state, agp, WcT, bcp, WkT, WvT, Qws, out);
  }
}

// Round 12
// 236.663 us; speedup vs baseline: 1.8762x; 1.1456x over previous
//
#include <hip/hip_runtime.h>

typedef __attribute__((ext_vector_type(8))) short short8;
typedef __attribute__((ext_vector_type(8))) unsigned short ushort8;
typedef __attribute__((ext_vector_type(4))) unsigned short bfu4;
typedef __attribute__((ext_vector_type(4))) float f32x4;

__device__ __forceinline__ unsigned short f2bf(float f){
  unsigned int u = __builtin_bit_cast(unsigned int, f);
  u += 0x7fffu + ((u >> 16) & 1u);           // round-to-nearest-even
  return (unsigned short)(u >> 16);
}
__device__ __forceinline__ float bf2f(unsigned short h){
  unsigned int u = ((unsigned int)h) << 16;
  return __builtin_bit_cast(float, u);
}
__device__ __forceinline__ float leaky(float x){ return x > 0.f ? x : 0.3f * x; }

// ---------------- BN statistics: stage 1 (per-block partial sums) ----------------
__global__ __launch_bounds__(256) void ca_stats_partial(const float* __restrict__ state,
    const int* __restrict__ agp, float* __restrict__ part, int B){
  int d = threadIdx.x;
  int ag = agp[0];
  int bPer = (B + 255) >> 8;
  int b0 = blockIdx.x * bPer;
  float sC = 0.f, ssC = 0.f, sO = 0.f, ssO = 0.f;
  for (int b = 0; b < bPer; b++){
    int bb = b0 + b;
    if (bb >= B) break;
    const float* row = state + ((size_t)bb << 12);   // *16*256
    #pragma unroll
    for (int a = 0; a < 16; a++){
      float v = row[a*256 + d];
      bool isC = (a == ag);
      sC  += isC ? v   : 0.f;
      ssC += isC ? v*v : 0.f;
      sO  += isC ? 0.f : v;
      ssO += isC ? 0.f : v*v;
    }
  }
  float* p = part + (size_t)blockIdx.x * 1024;
  p[d] = sC; p[d+256] = ssC; p[d+512] = sO; p[d+768] = ssO;
}

// ---------------- BN statistics: stage 2 (finalize rs, mean*rs), 1024 threads ----------------
__global__ __launch_bounds__(1024) void ca_stats_final(const float* __restrict__ part,
    float* __restrict__ stats, int nblk, int B){
  int d = threadIdx.x & 255, sl = threadIdx.x >> 8;
  float sC = 0.f, ssC = 0.f, sO = 0.f, ssO = 0.f;
  for (int g = sl; g < nblk; g += 4){
    const float* p = part + (size_t)g * 1024;
    sC += p[d]; ssC += p[d+256]; sO += p[d+512]; ssO += p[d+768];
  }
  __shared__ float red[4][4][256];
  red[sl][0][d] = sC; red[sl][1][d] = ssC; red[sl][2][d] = sO; red[sl][3][d] = ssO;
  __syncthreads();
  if (sl == 0){
    sC  = red[0][0][d] + red[1][0][d] + red[2][0][d] + red[3][0][d];
    ssC = red[0][1][d] + red[1][1][d] + red[2][1][d] + red[3][1][d];
    sO  = red[0][2][d] + red[1][2][d] + red[2][2][d] + red[3][2][d];
    ssO = red[0][3][d] + red[1][3][d] + red[2][3][d] + red[3][3][d];
    float nC = (float)B, nO = (float)B * 15.f;
    float mC = sC / nC, vC = ssC / nC - mC * mC;
    float mO = sO / nO, vO = ssO / nO - mO * mO;
    float rC = rsqrtf(vC + 1e-3f), rO = rsqrtf(vO + 1e-3f);
    stats[d] = rC; stats[d+256] = mC * rC; stats[d+512] = rO; stats[d+768] = mO * rO;
  }
}

// ---------------- weight prep: WsT/WcT + fragment-major WsF/WcF + biases ----------------
__global__ __launch_bounds__(256) void ca_prep_sc(const float* __restrict__ Ws,
    const float* __restrict__ bs, const float* __restrict__ Wc, const float* __restrict__ bc,
    const float* __restrict__ stats, unsigned short* __restrict__ WsT,
    unsigned short* __restrict__ WcT, unsigned short* __restrict__ WsF,
    unsigned short* __restrict__ WcF, float* __restrict__ bsp, float* __restrict__ bcp){
  int n = blockIdx.x, d = threadIdx.x;
  float rC = stats[d], mrC = stats[d+256], rO = stats[d+512], mrO = stats[d+768];
  float ws = Ws[(size_t)d*512 + n], wc = Wc[(size_t)d*512 + n];
  unsigned short wsb = f2bf(ws * rC), wcb = f2bf(wc * rO);
  WsT[(size_t)n*256 + d] = wsb;
  WcT[(size_t)n*256 + d] = wcb;
  // fragment-major: h=n>>6, nt=(n>>4)&3, j=n&15; kk=d>>5, hi=(d>>3)&3, e=d&7
  {
    int h = n >> 6, nt = (n >> 4) & 3, j = n & 15;
    int kk = d >> 5, hi = (d >> 3) & 3, e = d & 7;
    size_t fi = (size_t)((h*8 + kk)*4 + nt)*512 + (hi*16 + j)*8 + e;
    WsF[fi] = wsb;
    WcF[fi] = wcb;
  }
  __shared__ float red[256];
  red[d] = mrC * ws;
  __syncthreads();
  for (int s = 128; s > 0; s >>= 1){ if (d < s) red[d] += red[d+s]; __syncthreads(); }
  if (d == 0) bsp[n] = bs[n] - red[0];
  __syncthreads();
  red[d] = mrO * wc;
  __syncthreads();
  for (int s = 128; s > 0; s >>= 1){ if (d < s) red[d] += red[d+s]; __syncthreads(); }
  if (d == 0) bcp[n] = bc[n] - red[0];
}

// ---------------- weight prep: WkT/WvT/WqT + fragment-major WvF/WqF/WkF2 ----------------
__global__ __launch_bounds__(512) void ca_prep_kvq(const float* __restrict__ Wk,
    const float* __restrict__ Wv, const float* __restrict__ Wq,
    unsigned short* __restrict__ WkT, unsigned short* __restrict__ WvT,
    unsigned short* __restrict__ WqT, unsigned short* __restrict__ WkF2,
    unsigned short* __restrict__ WvF, unsigned short* __restrict__ WqF){
  int c = blockIdx.x & 511, m = blockIdx.x >> 9;
  int n = threadIdx.x;
  if (m == 3){   // WkF2: fragment-major Wk for the qk GEMM (A-operand, K=64)
    size_t idx = (size_t)c*512 + n;
    int h = (int)(idx >> 15), nn = (int)((idx >> 6) & 511), dd = (int)(idx & 63);
    int nt = nn >> 4, j = nn & 15, kq = dd >> 5, hi = (dd >> 3) & 3, e = dd & 7;
    WkF2[(size_t)((h*32 + nt)*2 + kq)*512 + (hi*16 + j)*8 + e] = f2bf(Wk[idx]);
    return;
  }
  int h = c >> 6, dd = c & 63;
  const float* W = (m == 0) ? Wk : (m == 1) ? Wv : Wq;
  unsigned short* O = (m == 0) ? WkT : (m == 1) ? WvT : WqT;
  float scale = (m == 2) ? 0.125f : 1.f;
  unsigned short v = f2bf(W[((size_t)h*512 + n)*64 + dd] * scale);
  O[(size_t)c*512 + n] = v;
  if (m != 0){   // fragment-major (K=512): kk=n>>5, hi=(n>>3)&3, e=n&7; nt=(c>>4)&3, j=c&15
    int nt = (c >> 4) & 3, j = c & 15;
    int kk = n >> 5, hi = (n >> 3) & 3, e = n & 7;
    size_t fi = (size_t)((h*16 + kk)*4 + nt)*512 + (hi*16 + j)*8 + e;
    if (m == 1) WvF[fi] = v; else WqF[fi] = v;
  }
}

// ---------------- Q kernel (fallback path): s_enc -> q -> Qws  (32 b-rows / block) ----------------
__global__ __launch_bounds__(512) void ca_q_kernel(const float* __restrict__ state,
    const int* __restrict__ agp,
    const unsigned short* __restrict__ WsT, const float* __restrict__ bsp,
    const unsigned short* __restrict__ WqT, unsigned short* __restrict__ Qws){
  __shared__ unsigned short U[32*512];
  __shared__ float bias_s[512];
  unsigned short* Alds = U;
  unsigned short* SE = U;
  int tid = threadIdx.x, lane = tid & 63, w = tid >> 6;
  int j = lane & 15, hi = lane >> 4;
  int b0 = blockIdx.x * 32;
  int ag = agp[0];

  for (int s = tid; s < 32*32; s += 512){
    int row = s >> 5, kg = s & 31;
    const float* p = state + (((size_t)(b0 + row) * 16 + ag) << 8) + kg * 8;
    f32x4 v0 = *(const f32x4*)p, v1 = *(const f32x4*)(p + 4);
    ushort8 hv;
    hv[0]=f2bf(v0[0]); hv[1]=f2bf(v0[1]); hv[2]=f2bf(v0[2]); hv[3]=f2bf(v0[3]);
    hv[4]=f2bf(v1[0]); hv[5]=f2bf(v1[1]); hv[6]=f2bf(v1[2]); hv[7]=f2bf(v1[3]);
    *(ushort8*)&Alds[row*256 + ((kg ^ (row & 7)) << 3)] = hv;
  }
  bias_s[tid & 511] = bsp[tid & 511];
  __syncthreads();

  int cb = w * 64;
  f32x4 zero4 = {0.f, 0.f, 0.f, 0.f};
  f32x4 acc[2][4];
  #pragma unroll
  for (int a1 = 0; a1 < 2; a1++)
    #pragma unroll
    for (int a2 = 0; a2 < 4; a2++) acc[a1][a2] = zero4;

  #pragma unroll
  for (int kk = 0; kk < 8; kk++){
    short8 bfr[4];
    #pragma unroll
    for (int nt = 0; nt < 4; nt++)
      bfr[nt] = *(const short8*)&WsT[(size_t)(cb + nt*16 + j)*256 + kk*32 + hi*8];
    #pragma unroll
    for (int mt = 0; mt < 2; mt++){
      int row = mt*16 + j;
      short8 afr = *(const short8*)&Alds[row*256 + ((((kk << 2) | hi) ^ (row & 7)) << 3)];
      #pragma unroll
      for (int nt = 0; nt < 4; nt++)
        acc[mt][nt] = __builtin_amdgcn_mfma_f32_16x16x32_bf16(afr, bfr[nt], acc[mt][nt], 0, 0, 0);
    }
  }
  __syncthreads();
  #pragma unroll
  for (int mt = 0; mt < 2; mt++)
    #pragma unroll
    for (int nt = 0; nt < 4; nt++)
      #pragma unroll
      for (int i = 0; i < 4; i++){
        int row = mt*16 + hi*4 + i, col = cb + nt*16 + j;
        float x = leaky(acc[mt][nt][i] + bias_s[col]);
        SE[row*512 + ((((col >> 3) ^ (row & 7)) << 3) | (col & 7))] = f2bf(x);
      }
  __syncthreads();

  f32x4 qa[2][4];
  #pragma unroll
  for (int a1 = 0; a1 < 2; a1++)
    #pragma unroll
    for (int a2 = 0; a2 < 4; a2++) qa[a1][a2] = zero4;
  #pragma unroll
  for (int kk = 0; kk < 16; kk++){
    short8 bfr[4];
    #pragma unroll
    for (int nt = 0; nt < 4; nt++)
      bfr[nt] = *(const short8*)&WqT[(size_t)(cb + nt*16 + j)*512 + kk*32 + hi*8];
    #pragma unroll
    for (int mt = 0; mt < 2; mt++){
      int row = mt*16 + j;
      short8 afr = *(const short8*)&SE[row*512 + ((((kk << 2) | hi) ^ (row & 7)) << 3)];
      #pragma unroll
      for (int nt = 0; nt < 4; nt++)
        qa[mt][nt] = __builtin_amdgcn_mfma_f32_16x16x32_bf16(afr, bfr[nt], qa[mt][nt], 0, 0, 0);
    }
  }
  #pragma unroll
  for (int mt = 0; mt < 2; mt++)
    #pragma unroll
    for (int nt = 0; nt < 4; nt++)
      #pragma unroll
      for (int i = 0; i < 4; i++)
        Qws[(size_t)(b0 + mt*16 + hi*4 + i)*512 + cb + nt*16 + j] = f2bf(qa[mt][nt][i]);
}

// ---------------- Q kernel (qk path): s_enc -> q -> qk -> QKws[b][8][512] ----------------
// Fragment-major WsF/WqF loads (coalesced 1KB wave-loads). qk GEMM uses SWAPPED
// operands mfma(Wk_frag, q_frag) so C rows = n -> each lane packs 4 consecutive n
// into one bfu4 store (64 stores vs 256 scalar).
__global__ __launch_bounds__(512) void ca_q_kernel_qk(const float* __restrict__ state,
    const int* __restrict__ agp,
    const unsigned short* __restrict__ WsF, const float* __restrict__ bsp,
    const unsigned short* __restrict__ WqF, const unsigned short* __restrict__ WkF2,
    unsigned short* __restrict__ QKws){
  __shared__ unsigned short U[32*512];      // 32KB union: Alds / SE / Qlds
  __shared__ float bias_s[512];
  unsigned short* Alds = U;
  unsigned short* SE = U;
  unsigned short* Qlds = U;
  int tid = threadIdx.x, lane = tid & 63, w = tid >> 6;
  int j = lane & 15, hi = lane >> 4;
  int b0 = blockIdx.x * 32;
  int ag = agp[0];

  for (int s = tid; s < 32*32; s += 512){
    int row = s >> 5, kg = s & 31;
    const float* p = state + (((size_t)(b0 + row) * 16 + ag) << 8) + kg * 8;
    f32x4 v0 = *(const f32x4*)p, v1 = *(const f32x4*)(p + 4);
    ushort8 hv;
    hv[0]=f2bf(v0[0]); hv[1]=f2bf(v0[1]); hv[2]=f2bf(v0[2]); hv[3]=f2bf(v0[3]);
    hv[4]=f2bf(v1[0]); hv[5]=f2bf(v1[1]); hv[6]=f2bf(v1[2]); hv[7]=f2bf(v1[3]);
    *(ushort8*)&Alds[row*256 + ((kg ^ (row & 7)) << 3)] = hv;
  }
  bias_s[tid & 511] = bsp[tid & 511];
  __syncthreads();

  int cb = w * 64;
  f32x4 zero4 = {0.f, 0.f, 0.f, 0.f};
  f32x4 acc[2][4];
  #pragma unroll
  for (int a1 = 0; a1 < 2; a1++)
    #pragma unroll
    for (int a2 = 0; a2 < 4; a2++) acc[a1][a2] = zero4;

  #pragma unroll
  for (int kk = 0; kk < 8; kk++){
    short8 bfr[4];
    #pragma unroll
    for (int nt = 0; nt < 4; nt++)
      bfr[nt] = *(const short8*)&WsF[(size_t)((w*8 + kk)*4 + nt)*512 + lane*8];
    #pragma unroll
    for (int mt = 0; mt < 2; mt++){
      int row = mt*16 + j;
      short8 afr = *(const short8*)&Alds[row*256 + ((((kk << 2) | hi) ^ (row & 7)) << 3)];
      #pragma unroll
      for (int nt = 0; nt < 4; nt++)
        acc[mt][nt] = __builtin_amdgcn_mfma_f32_16x16x32_bf16(afr, bfr[nt], acc[mt][nt], 0, 0, 0);
    }
  }
  __syncthreads();   // Alds dead; SE overlays it
  #pragma unroll
  for (int mt = 0; mt < 2; mt++)
    #pragma unroll
    for (int nt = 0; nt < 4; nt++)
      #pragma unroll
      for (int i = 0; i < 4; i++){
        int row = mt*16 + hi*4 + i, col = cb + nt*16 + j;
        float x = leaky(acc[mt][nt][i] + bias_s[col]);
        SE[row*512 + ((((col >> 3) ^ (row & 7)) << 3) | (col & 7))] = f2bf(x);
      }
  __syncthreads();

  // q = s_enc @ WqT (1/8 folded), kept in registers
  f32x4 qa[2][4];
  #pragma unroll
  for (int a1 = 0; a1 < 2; a1++)
    #pragma unroll
    for (int a2 = 0; a2 < 4; a2++) qa[a1][a2] = zero4;
  #pragma unroll
  for (int kk = 0; kk < 16; kk++){
    short8 bfr[4];
    #pragma unroll
    for (int nt = 0; nt < 4; nt++)
      bfr[nt] = *(const short8*)&WqF[(size_t)((w*16 + kk)*4 + nt)*512 + lane*8];
    #pragma unroll
    for (int mt = 0; mt < 2; mt++){
      int row = mt*16 + j;
      short8 afr = *(const short8*)&SE[row*512 + ((((kk << 2) | hi) ^ (row & 7)) << 3)];
      #pragma unroll
      for (int nt = 0; nt < 4; nt++)
        qa[mt][nt] = __builtin_amdgcn_mfma_f32_16x16x32_bf16(afr, bfr[nt], qa[mt][nt], 0, 0, 0);
    }
  }
  __syncthreads();   // SE dead; Qlds overlays it
  #pragma unroll
  for (int mt = 0; mt < 2; mt++)
    #pragma unroll
    for (int nt = 0; nt < 4; nt++)
      #pragma unroll
      for (int i = 0; i < 4; i++){
        int row = mt*16 + hi*4 + i, col = cb + nt*16 + j;
        Qlds[row*512 + ((((col >> 3) ^ (row & 7)) << 3) | (col & 7))] = f2bf(qa[mt][nt][i]);
      }
  __syncthreads();

  // qk[b][h=w][n] = sum_d q[b][w*64+d]*Wk[w][n][d]; swapped operands: C rows = n
  short8 aq[2][2];
  #pragma unroll
  for (int bt = 0; bt < 2; bt++)
    #pragma unroll
    for (int kq = 0; kq < 2; kq++){
      int row = bt*16 + j;
      int col = w*64 + kq*32 + hi*8;
      aq[bt][kq] = *(const short8*)&Qlds[row*512 + ((((col >> 3) ^ (row & 7)) << 3))];
    }
  for (int nt = 0; nt < 32; nt++){
    short8 bf0 = *(const short8*)&WkF2[(size_t)((w*32 + nt)*2 + 0)*512 + lane*8];
    short8 bf1 = *(const short8*)&WkF2[(size_t)((w*32 + nt)*2 + 1)*512 + lane*8];
    #pragma unroll
    for (int bt = 0; bt < 2; bt++){
      f32x4 qt = zero4;
      qt = __builtin_amdgcn_mfma_f32_16x16x32_bf16(bf0, aq[bt][0], qt, 0, 0, 0);
      qt = __builtin_amdgcn_mfma_f32_16x16x32_bf16(bf1, aq[bt][1], qt, 0, 0, 0);
      // lane: col = batch j, rows = n = nt*16 + hi*4 + i (4 consecutive n)
      bfu4 pk;
      pk[0] = f2bf(qt[0]); pk[1] = f2bf(qt[1]); pk[2] = f2bf(qt[2]); pk[3] = f2bf(qt[3]);
      *(bfu4*)&QKws[((size_t)(b0 + bt*16 + j)*8 + w)*512 + nt*16 + hi*4] = pk;
    }
  }
}

// ---------------- main kernel (qk path): sa_enc -> scores(qk) -> softmax -> V -> att ----------------
// Fragment-major WcF/WvF: every weight B-load is one coalesced 1KB wave-load.
__global__ __launch_bounds__(512) void ca_main_kernel_qk(const float* __restrict__ state,
    const int* __restrict__ agp,
    const unsigned short* __restrict__ WcF, const float* __restrict__ bcp,
    const unsigned short* __restrict__ WvF, const unsigned short* __restrict__ QKws,
    float* __restrict__ out){
  __shared__ unsigned short U[128*512];     // 128KB union: Alds (first 64KB), then SA
  __shared__ float bias_s[512];
  __shared__ float Wl[8*16*8];              // wgt[b][a][h], 4KB
  unsigned short* Alds = U;
  unsigned short* SA = U;
  int tid = threadIdx.x, lane = tid & 63, w = tid >> 6;
  int j = lane & 15, hi = lane >> 4;
  int b0 = blockIdx.x * 8;
  int ag = agp[0];
  f32x4 zero4 = {0.f, 0.f, 0.f, 0.f};
  short8 zero8 = {0,0,0,0,0,0,0,0};

  #pragma unroll
  for (int g = 0; g < 2; g++){
    f32x4 st0[4], st1[4];
    #pragma unroll
    for (int it = 0; it < 4; it++){
      int s = tid + 512*(g*4 + it);
      int row = s >> 5, kg = s & 31;
      int bl = row >> 4, ai = row & 15;
      if (ai < 15){
        int a = ai + (ai >= ag ? 1 : 0);
        const float* p = state + (((size_t)(b0 + bl) * 16 + a) << 8) + kg * 8;
        st0[it] = *(const f32x4*)p;
        st1[it] = *(const f32x4*)(p + 4);
      } else { st0[it] = zero4; st1[it] = zero4; }
    }
    #pragma unroll
    for (int it = 0; it < 4; it++){
      int s = tid + 512*(g*4 + it);
      int row = s >> 5, kg = s & 31;
      ushort8 hv;
      hv[0]=f2bf(st0[it][0]); hv[1]=f2bf(st0[it][1]); hv[2]=f2bf(st0[it][2]); hv[3]=f2bf(st0[it][3]);
      hv[4]=f2bf(st1[it][0]); hv[5]=f2bf(st1[it][1]); hv[6]=f2bf(st1[it][2]); hv[7]=f2bf(st1[it][3]);
      *(ushort8*)&Alds[row*256 + ((kg ^ (row & 7)) << 3)] = hv;
    }
  }
  bias_s[tid] = bcp[tid];
  __syncthreads();

  int cb = w * 64;

  // ---- GEMM1: sa_enc rows [0,128) x cols [cb,cb+64); WcF coalesced B-loads
  f32x4 acc[8][4];
  #pragma unroll
  for (int a1 = 0; a1 < 8; a1++)
    #pragma unroll
    for (int a2 = 0; a2 < 4; a2++) acc[a1][a2] = zero4;
  {
    short8 bcur[4], bnxt[4];
    #pragma unroll
    for (int nt = 0; nt < 4; nt++)
      bcur[nt] = *(const short8*)&WcF[(size_t)((w*8 + 0)*4 + nt)*512 + lane*8];
    #pragma unroll 1
    for (int kk = 0; kk < 8; kk++){
      if (kk < 7){
        #pragma unroll
        for (int nt = 0; nt < 4; nt++)
          bnxt[nt] = *(const short8*)&WcF[(size_t)((w*8 + kk + 1)*4 + nt)*512 + lane*8];
      }
      #pragma unroll
      for (int mt = 0; mt < 8; mt++){
        int row = mt*16 + j;
        short8 afr = *(const short8*)&Alds[row*256 + ((((kk << 2) | hi) ^ (row & 7)) << 3)];
        #pragma unroll
        for (int nt = 0; nt < 4; nt++)
          acc[mt][nt] = __builtin_amdgcn_mfma_f32_16x16x32_bf16(afr, bcur[nt], acc[mt][nt], 0, 0, 0);
      }
      #pragma unroll
      for (int nt = 0; nt < 4; nt++) bcur[nt] = bnxt[nt];
    }
  }
  __syncthreads();
  #pragma unroll
  for (int mt = 0; mt < 8; mt++)
    #pragma unroll
    for (int nt = 0; nt < 4; nt++)
      #pragma unroll
      for (int i = 0; i < 4; i++){
        int row = mt*16 + hi*4 + i, col = cb + nt*16 + j;
        float x = leaky(acc[mt][nt][i] + bias_s[col]);
        SA[row*512 + ((((col >> 3) ^ (row & 7)) << 3) | (col & 7))] = f2bf(x);
      }
  __syncthreads();

  // ---- scores for batch b0+w: M=16 agents x N=16 heads(8 valid), K=512
  f32x4 qs = zero4;
  {
    size_t qbase = ((size_t)(b0 + w)*8 + (j & 7))*512;
    #pragma unroll
    for (int kk = 0; kk < 16; kk++){
      short8 bq = *(const short8*)&QKws[qbase + kk*32 + hi*8];
      if (j >= 8) bq = zero8;
      int row = w*16 + j;
      short8 afr = *(const short8*)&SA[row*512 + ((((kk << 2) | hi) ^ (row & 7)) << 3)];
      qs = __builtin_amdgcn_mfma_f32_16x16x32_bf16(afr, bq, qs, 0, 0, 0);
    }
  }
  // softmax over agents (rows) per head col j
  {
    float sv0 = qs[0], sv1 = qs[1], sv2 = qs[2], sv3 = qs[3];
    sv3 = (hi == 3) ? -1e30f : sv3;         // mask pad agent a=15
    float m = fmaxf(fmaxf(sv0, sv1), fmaxf(sv2, sv3));
    m = fmaxf(m, __shfl_xor(m, 16)); m = fmaxf(m, __shfl_xor(m, 32));
    float e0 = __expf(sv0-m), e1 = __expf(sv1-m), e2 = __expf(sv2-m), e3 = __expf(sv3-m);
    float sum = e0 + e1 + e2 + e3;
    sum += __shfl_xor(sum, 16); sum += __shfl_xor(sum, 32);
    float inv = 1.f / sum;
    if (j < 8){
      Wl[w*128 + (hi*4+0)*8 + j] = e0*inv;
      Wl[w*128 + (hi*4+1)*8 + j] = e1*inv;
      Wl[w*128 + (hi*4+2)*8 + j] = e2*inv;
      Wl[w*128 + (hi*4+3)*8 + j] = e3*inv;
    }
  }

  // ---- GEMM2-V; WvF coalesced B-loads
  f32x4 va[8][4];
  #pragma unroll
  for (int a1 = 0; a1 < 8; a1++)
    #pragma unroll
    for (int a2 = 0; a2 < 4; a2++) va[a1][a2] = zero4;
  {
    short8 bcur[4], bnxt[4];
    #pragma unroll
    for (int nt = 0; nt < 4; nt++)
      bcur[nt] = *(const short8*)&WvF[(size_t)((w*16 + 0)*4 + nt)*512 + lane*8];
    #pragma unroll 1
    for (int kk = 0; kk < 16; kk++){
      if (kk < 15){
        #pragma unroll
        for (int nt = 0; nt < 4; nt++)
          bnxt[nt] = *(const short8*)&WvF[(size_t)((w*16 + kk + 1)*4 + nt)*512 + lane*8];
      }
      #pragma unroll
      for (int mt = 0; mt < 8; mt++){
        int row = mt*16 + j;
        short8 afr = *(const short8*)&SA[row*512 + ((((kk << 2) | hi) ^ (row & 7)) << 3)];
        #pragma unroll
        for (int nt = 0; nt < 4; nt++)
          va[mt][nt] = __builtin_amdgcn_mfma_f32_16x16x32_bf16(afr, bcur[nt], va[mt][nt], 0, 0, 0);
      }
      #pragma unroll
      for (int nt = 0; nt < 4; nt++) bcur[nt] = bnxt[nt];
    }
  }
  __syncthreads();   // Wl writes (pre-V) now visible to all waves

  // ---- att = sum_a wgt * leaky(V); wave w = head w reads wgt[mt][a][w]
  #pragma unroll
  for (int mt = 0; mt < 8; mt++){
    float w0 = Wl[mt*128 + (hi*4+0)*8 + w];
    float w1 = Wl[mt*128 + (hi*4+1)*8 + w];
    float w2 = Wl[mt*128 + (hi*4+2)*8 + w];
    float w3 = Wl[mt*128 + (hi*4+3)*8 + w];
    float ap0 = w0*leaky(va[mt][0][0]) + w1*leaky(va[mt][0][1]) + w2*leaky(va[mt][0][2]) + w3*leaky(va[mt][0][3]);
    float ap1 = w0*leaky(va[mt][1][0]) + w1*leaky(va[mt][1][1]) + w2*leaky(va[mt][1][2]) + w3*leaky(va[mt][1][3]);
    float ap2 = w0*leaky(va[mt][2][0]) + w1*leaky(va[mt][2][1]) + w2*leaky(va[mt][2][2]) + w3*leaky(va[mt][2][3]);
    float ap3 = w0*leaky(va[mt][3][0]) + w1*leaky(va[mt][3][1]) + w2*leaky(va[mt][3][2]) + w3*leaky(va[mt][3][3]);
    ap0 += __shfl_xor(ap0, 16); ap0 += __shfl_xor(ap0, 32);
    ap1 += __shfl_xor(ap1, 16); ap1 += __shfl_xor(ap1, 32);
    ap2 += __shfl_xor(ap2, 16); ap2 += __shfl_xor(ap2, 32);
    ap3 += __shfl_xor(ap3, 16); ap3 += __shfl_xor(ap3, 32);
    float val = (hi == 0) ? ap0 : (hi == 1) ? ap1 : (hi == 2) ? ap2 : ap3;
    out[(size_t)(b0 + mt)*512 + cb + lane] = val;
  }
}

// ---------------- main kernel (fallback = R9) ----------------
__global__ __launch_bounds__(512) void ca_main_kernel(const float* __restrict__ state,
    const int* __restrict__ agp,
    const unsigned short* __restrict__ WcT, const float* __restrict__ bcp,
    const unsigned short* __restrict__ WkT, const unsigned short* __restrict__ WvT,
    const unsigned short* __restrict__ Qws, float* __restrict__ out){
  __shared__ unsigned short U[128*512];
  __shared__ unsigned short Qs[8*512];
  __shared__ float bias_s[512];
  unsigned short* Alds = U;
  unsigned short* SA = U;
  int tid = threadIdx.x, lane = tid & 63, w = tid >> 6;
  int j = lane & 15, hi = lane >> 4;
  int b0 = blockIdx.x * 8;
  int ag = agp[0];
  f32x4 zero4 = {0.f, 0.f, 0.f, 0.f};

  #pragma unroll
  for (int g = 0; g < 2; g++){
    f32x4 st0[4], st1[4];
    #pragma unroll
    for (int it = 0; it < 4; it++){
      int s = tid + 512*(g*4 + it);
      int row = s >> 5, kg = s & 31;
      int bl = row >> 4, ai = row & 15;
      if (ai < 15){
        int a = ai + (ai >= ag ? 1 : 0);
        const float* p = state + (((size_t)(b0 + bl) * 16 + a) << 8) + kg * 8;
        st0[it] = *(const f32x4*)p;
        st1[it] = *(const f32x4*)(p + 4);
      } else { st0[it] = zero4; st1[it] = zero4; }
    }
    #pragma unroll
    for (int it = 0; it < 4; it++){
      int s = tid + 512*(g*4 + it);
      int row = s >> 5, kg = s & 31;
      ushort8 hv;
      hv[0]=f2bf(st0[it][0]); hv[1]=f2bf(st0[it][1]); hv[2]=f2bf(st0[it][2]); hv[3]=f2bf(st0[it][3]);
      hv[4]=f2bf(st1[it][0]); hv[5]=f2bf(st1[it][1]); hv[6]=f2bf(st1[it][2]); hv[7]=f2bf(st1[it][3]);
      *(ushort8*)&Alds[row*256 + ((kg ^ (row & 7)) << 3)] = hv;
    }
  }
  *(ushort8*)&Qs[tid*8] = *(const ushort8*)&Qws[(size_t)b0*512 + tid*8];
  bias_s[tid] = bcp[tid];
  __syncthreads();

  int cb = w * 64;

  f32x4 acc[8][4];
  #pragma unroll
  for (int a1 = 0; a1 < 8; a1++)
    #pragma unroll
    for (int a2 = 0; a2 < 4; a2++) acc[a1][a2] = zero4;
  {
    short8 bcur[4], bnxt[4];
    #pragma unroll
    for (int nt = 0; nt < 4; nt++)
      bcur[nt] = *(const short8*)&WcT[(size_t)(cb + nt*16 + j)*256 + hi*8];
    #pragma unroll 1
    for (int kk = 0; kk < 8; kk++){
      if (kk < 7){
        #pragma unroll
        for (int nt = 0; nt < 4; nt++)
          bnxt[nt] = *(const short8*)&WcT[(size_t)(cb + nt*16 + j)*256 + (kk+1)*32 + hi*8];
      }
      #pragma unroll
      for (int mt = 0; mt < 8; mt++){
        int row = mt*16 + j;
        short8 afr = *(const short8*)&Alds[row*256 + ((((kk << 2) | hi) ^ (row & 7)) << 3)];
        #pragma unroll
        for (int nt = 0; nt < 4; nt++)
          acc[mt][nt] = __builtin_amdgcn_mfma_f32_16x16x32_bf16(afr, bcur[nt], acc[mt][nt], 0, 0, 0);
      }
      #pragma unroll
      for (int nt = 0; nt < 4; nt++) bcur[nt] = bnxt[nt];
    }
  }
  __syncthreads();
  #pragma unroll
  for (int mt = 0; mt < 8; mt++)
    #pragma unroll
    for (int nt = 0; nt < 4; nt++)
      #pragma unroll
      for (int i = 0; i < 4; i++){
        int row = mt*16 + hi*4 + i, col = cb + nt*16 + j;
        float x = leaky(acc[mt][nt][i] + bias_s[col]);
        SA[row*512 + ((((col >> 3) ^ (row & 7)) << 3) | (col & 7))] = f2bf(x);
      }
  __syncthreads();

  f32x4 ka[8][4];
  #pragma unroll
  for (int a1 = 0; a1 < 8; a1++)
    #pragma unroll
    for (int a2 = 0; a2 < 4; a2++) ka[a1][a2] = zero4;
  {
    short8 bcur[4], bnxt[4];
    #pragma unroll
    for (int nt = 0; nt < 4; nt++)
      bcur[nt] = *(const short8*)&WkT[(size_t)(cb + nt*16 + j)*512 + hi*8];
    #pragma unroll 1
    for (int kk = 0; kk < 16; kk++){
      if (kk < 15){
        #pragma unroll
        for (int nt = 0; nt < 4; nt++)
          bnxt[nt] = *(const short8*)&WkT[(size_t)(cb + nt*16 + j)*512 + (kk+1)*32 + hi*8];
      }
      #pragma unroll
      for (int mt = 0; mt < 8; mt++){
        int row = mt*16 + j;
        short8 afr = *(const short8*)&SA[row*512 + ((((kk << 2) | hi) ^ (row & 7)) << 3)];
        #pragma unroll
        for (int nt = 0; nt < 4; nt++)
          ka[mt][nt] = __builtin_amdgcn_mfma_f32_16x16x32_bf16(afr, bcur[nt], ka[mt][nt], 0, 0, 0);
      }
      #pragma unroll
      for (int nt = 0; nt < 4; nt++) bcur[nt] = bnxt[nt];
    }
  }

  float wgt[8][4];
  #pragma unroll
  for (int mt = 0; mt < 8; mt++){
    float sv[4];
    #pragma unroll
    for (int i = 0; i < 4; i++){
      float t = 0.f;
      #pragma unroll
      for (int nt = 0; nt < 4; nt++)
        t += bf2f(Qs[mt*512 + cb + nt*16 + j]) * ka[mt][nt][i];
      t += __shfl_xor(t, 1); t += __shfl_xor(t, 2);
      t += __shfl_xor(t, 4); t += __shfl_xor(t, 8);
      sv[i] = t;
    }
    sv[3] = (hi == 3) ? -1e30f : sv[3];
    float m = fmaxf(fmaxf(sv[0], sv[1]), fmaxf(sv[2], sv[3]));
    m = fmaxf(m, __shfl_xor(m, 16)); m = fmaxf(m, __shfl_xor(m, 32));
    float e0 = __expf(sv[0]-m), e1 = __expf(sv[1]-m), e2 = __expf(sv[2]-m), e3 = __expf(sv[3]-m);
    float sum = e0 + e1 + e2 + e3;
    sum += __shfl_xor(sum, 16); sum += __shfl_xor(sum, 32);
    float inv = 1.f / sum;
    wgt[mt][0] = e0*inv; wgt[mt][1] = e1*inv; wgt[mt][2] = e2*inv; wgt[mt][3] = e3*inv;
  }

  f32x4 va[8][4];
  #pragma unroll
  for (int a1 = 0; a1 < 8; a1++)
    #pragma unroll
    for (int a2 = 0; a2 < 4; a2++) va[a1][a2] = zero4;
  {
    short8 bcur[4], bnxt[4];
    #pragma unroll
    for (int nt = 0; nt < 4; nt++)
      bcur[nt] = *(const short8*)&WvT[(size_t)(cb + nt*16 + j)*512 + hi*8];
    #pragma unroll 1
    for (int kk = 0; kk < 16; kk++){
      if (kk < 15){
        #pragma unroll
        for (int nt = 0; nt < 4; nt++)
          bnxt[nt] = *(const short8*)&WvT[(size_t)(cb + nt*16 + j)*512 + (kk+1)*32 + hi*8];
      }
      #pragma unroll
      for (int mt = 0; mt < 8; mt++){
        int row = mt*16 + j;
        short8 afr = *(const short8*)&SA[row*512 + ((((kk << 2) | hi) ^ (row & 7)) << 3)];
        #pragma unroll
        for (int nt = 0; nt < 4; nt++)
          va[mt][nt] = __builtin_amdgcn_mfma_f32_16x16x32_bf16(afr, bcur[nt], va[mt][nt], 0, 0, 0);
      }
      #pragma unroll
      for (int nt = 0; nt < 4; nt++) bcur[nt] = bnxt[nt];
    }
  }

  #pragma unroll
  for (int mt = 0; mt < 8; mt++){
    float ap0 = 0.f, ap1 = 0.f, ap2 = 0.f, ap3 = 0.f;
    #pragma unroll
    for (int i = 0; i < 4; i++){
      float wv = wgt[mt][i];
      ap0 += wv * leaky(va[mt][0][i]);
      ap1 += wv * leaky(va[mt][1][i]);
      ap2 += wv * leaky(va[mt][2][i]);
      ap3 += wv * leaky(va[mt][3][i]);
    }
    ap0 += __shfl_xor(ap0, 16); ap0 += __shfl_xor(ap0, 32);
    ap1 += __shfl_xor(ap1, 16); ap1 += __shfl_xor(ap1, 32);
    ap2 += __shfl_xor(ap2, 16); ap2 += __shfl_xor(ap2, 32);
    ap3 += __shfl_xor(ap3, 16); ap3 += __shfl_xor(ap3, 32);
    float val = (hi == 0) ? ap0 : (hi == 1) ? ap1 : (hi == 2) ? ap2 : ap3;
    out[(size_t)(b0 + mt)*512 + cb + lane] = val;
  }
}

extern "C" void kernel_launch(void* const* d_in, const int* in_sizes, int n_in,
                              void* d_out, int out_size, void* d_ws, size_t ws_size,
                              hipStream_t stream) {
  const float* state = (const float*)d_in[0];
  const int*   agp   = (const int*)d_in[1];
  const float* Ws    = (const float*)d_in[2];
  const float* bs    = (const float*)d_in[3];
  const float* Wc    = (const float*)d_in[4];
  const float* bc    = (const float*)d_in[5];
  const float* Wk    = (const float*)d_in[6];
  const float* Wq    = (const float*)d_in[7];
  const float* Wv    = (const float*)d_in[8];
  float* out = (float*)d_out;
  int B = in_sizes[0] / 4096;   // state is (B,16,256)

  char* wsb = (char*)d_ws;
  float* part  = (float*)wsb;                                   // 1 MB
  float* stats = (float*)(wsb + (1 << 20));                     // 4 KB
  float* bsp   = (float*)(wsb + (1 << 20) + 4096);              // 2 KB
  float* bcp   = (float*)(wsb + (1 << 20) + 6144);              // 2 KB
  unsigned short* WsT  = (unsigned short*)(wsb + (1 << 20) + 8192);
  unsigned short* WcT  = WsT  + 512*256;
  unsigned short* WkT  = WcT  + 512*256;
  unsigned short* WvT  = WkT  + 512*512;
  unsigned short* WqT  = WvT  + 512*512;
  unsigned short* WkF2 = WqT  + 512*512;         // fragment-major Wk (qk GEMM)
  unsigned short* Qws  = WkF2 + 512*512;         // B*512  (fallback only)
  unsigned short* QKws = Qws  + (size_t)B*512;   // B*8*512
  // fragment-major layouts overlay Qws (unused in qk path; fallback q_kernel
  // overwrites this region AFTER prep, before any fallback consumer reads it)
  unsigned short* WsF  = Qws;                    // 512*256
  unsigned short* WcF  = WsF + 512*256;          // 512*256
  unsigned short* WqF  = WcF + 512*256;          // 512*512
  unsigned short* WvF  = WqF + 512*512;          // 512*512  (total 2.1MB < 8MB Qws)

  size_t need = ((size_t)(1 << 20) + 8192)
              + 2ull*(512*256 + 512*256 + 512*512 + 512*512 + 512*512 + 512*512)
              + 2ull*B*512 + 2ull*B*8*512;
  bool qkp = (ws_size >= need);

  hipLaunchKernelGGL(ca_stats_partial, dim3(256), dim3(256), 0, stream, state, agp, part, B);
  hipLaunchKernelGGL(ca_stats_final,   dim3(1),   dim3(1024), 0, stream, part, stats, 256, B);
  hipLaunchKernelGGL(ca_prep_sc,       dim3(512), dim3(256), 0, stream, Ws, bs, Wc, bc, stats, WsT, WcT, WsF, WcF, bsp, bcp);
  hipLaunchKernelGGL(ca_prep_kvq,      dim3(2048),dim3(512), 0, stream, Wk, Wv, Wq, WkT, WvT, WqT, WkF2, WvF, WqF);
  if (qkp){
    hipLaunchKernelGGL(ca_q_kernel_qk,   dim3(B/32),dim3(512), 0, stream, state, agp, WsF, bsp, WqF, WkF2, QKws);
    hipLaunchKernelGGL(ca_main_kernel_qk,dim3(B/8), dim3(512), 0, stream, state, agp, WcF, bcp, WvF, QKws, out);
  } else {
    hipLaunchKernelGGL(ca_q_kernel,      dim3(B/32),dim3(512), 0, stream, state, agp, WsT, bsp, WqT, Qws);
    hipLaunchKernelGGL(ca_main_kernel,   dim3(B/8), dim3(512), 0, stream, state, agp, WcT, bcp, WkT, WvT, Qws, out);
  }
}

// Round 13
// 234.623 us; speedup vs baseline: 1.8925x; 1.0087x over previous
//
#include <hip/hip_runtime.h>

typedef __attribute__((ext_vector_type(8))) short short8;
typedef __attribute__((ext_vector_type(8))) unsigned short ushort8;
typedef __attribute__((ext_vector_type(4))) unsigned short bfu4;
typedef __attribute__((ext_vector_type(4))) float f32x4;

__device__ __forceinline__ unsigned short f2bf(float f){
  unsigned int u = __builtin_bit_cast(unsigned int, f);
  u += 0x7fffu + ((u >> 16) & 1u);           // round-to-nearest-even
  return (unsigned short)(u >> 16);
}
__device__ __forceinline__ float bf2f(unsigned short h){
  unsigned int u = ((unsigned int)h) << 16;
  return __builtin_bit_cast(float, u);
}
__device__ __forceinline__ float leaky(float x){ return x > 0.f ? x : 0.3f * x; }

#define SAS 520   // SA/SE/Qlds row stride in elements (1040B: 16B-aligned, not 0 mod 128)

// ---------------- BN statistics: stage 1 (1024 thr: 4 batch-slices + LDS reduce) ----------------
__global__ __launch_bounds__(1024) void ca_stats_partial(const float* __restrict__ state,
    const int* __restrict__ agp, float* __restrict__ part, int B){
  int d = threadIdx.x & 255, sl = threadIdx.x >> 8;
  int ag = agp[0];
  int bPer = (B + 255) >> 8;
  int b0 = blockIdx.x * bPer;
  float sC = 0.f, ssC = 0.f, sO = 0.f, ssO = 0.f;
  for (int b = sl; b < bPer; b += 4){
    int bb = b0 + b;
    if (bb >= B) continue;
    const float* row = state + ((size_t)bb << 12);   // *16*256
    #pragma unroll
    for (int a = 0; a < 16; a++){
      float v = row[a*256 + d];
      bool isC = (a == ag);
      sC  += isC ? v   : 0.f;
      ssC += isC ? v*v : 0.f;
      sO  += isC ? 0.f : v;
      ssO += isC ? 0.f : v*v;
    }
  }
  __shared__ float red[4][4][256];
  red[sl][0][d] = sC; red[sl][1][d] = ssC; red[sl][2][d] = sO; red[sl][3][d] = ssO;
  __syncthreads();
  if (sl == 0){
    float* p = part + (size_t)blockIdx.x * 1024;
    p[d]     = red[0][0][d] + red[1][0][d] + red[2][0][d] + red[3][0][d];
    p[d+256] = red[0][1][d] + red[1][1][d] + red[2][1][d] + red[3][1][d];
    p[d+512] = red[0][2][d] + red[1][2][d] + red[2][2][d] + red[3][2][d];
    p[d+768] = red[0][3][d] + red[1][3][d] + red[2][3][d] + red[3][3][d];
  }
}

// ---------------- BN statistics: stage 2 (finalize rs, mean*rs), 1024 threads ----------------
__global__ __launch_bounds__(1024) void ca_stats_final(const float* __restrict__ part,
    float* __restrict__ stats, int nblk, int B){
  int d = threadIdx.x & 255, sl = threadIdx.x >> 8;
  float sC = 0.f, ssC = 0.f, sO = 0.f, ssO = 0.f;
  for (int g = sl; g < nblk; g += 4){
    const float* p = part + (size_t)g * 1024;
    sC += p[d]; ssC += p[d+256]; sO += p[d+512]; ssO += p[d+768];
  }
  __shared__ float red[4][4][256];
  red[sl][0][d] = sC; red[sl][1][d] = ssC; red[sl][2][d] = sO; red[sl][3][d] = ssO;
  __syncthreads();
  if (sl == 0){
    sC  = red[0][0][d] + red[1][0][d] + red[2][0][d] + red[3][0][d];
    ssC = red[0][1][d] + red[1][1][d] + red[2][1][d] + red[3][1][d];
    sO  = red[0][2][d] + red[1][2][d] + red[2][2][d] + red[3][2][d];
    ssO = red[0][3][d] + red[1][3][d] + red[2][3][d] + red[3][3][d];
    float nC = (float)B, nO = (float)B * 15.f;
    float mC = sC / nC, vC = ssC / nC - mC * mC;
    float mO = sO / nO, vO = ssO / nO - mO * mO;
    float rC = rsqrtf(vC + 1e-3f), rO = rsqrtf(vO + 1e-3f);
    stats[d] = rC; stats[d+256] = mC * rC; stats[d+512] = rO; stats[d+768] = mO * rO;
  }
}

// ---------------- weight prep: WsT/WcT + fragment-major WsF/WcF + biases ----------------
__global__ __launch_bounds__(256) void ca_prep_sc(const float* __restrict__ Ws,
    const float* __restrict__ bs, const float* __restrict__ Wc, const float* __restrict__ bc,
    const float* __restrict__ stats, unsigned short* __restrict__ WsT,
    unsigned short* __restrict__ WcT, unsigned short* __restrict__ WsF,
    unsigned short* __restrict__ WcF, float* __restrict__ bsp, float* __restrict__ bcp){
  int n = blockIdx.x, d = threadIdx.x;
  float rC = stats[d], mrC = stats[d+256], rO = stats[d+512], mrO = stats[d+768];
  float ws = Ws[(size_t)d*512 + n], wc = Wc[(size_t)d*512 + n];
  unsigned short wsb = f2bf(ws * rC), wcb = f2bf(wc * rO);
  WsT[(size_t)n*256 + d] = wsb;
  WcT[(size_t)n*256 + d] = wcb;
  {
    int h = n >> 6, nt = (n >> 4) & 3, j = n & 15;
    int kk = d >> 5, hi = (d >> 3) & 3, e = d & 7;
    size_t fi = (size_t)((h*8 + kk)*4 + nt)*512 + (hi*16 + j)*8 + e;
    WsF[fi] = wsb;
    WcF[fi] = wcb;
  }
  __shared__ float red[256];
  red[d] = mrC * ws;
  __syncthreads();
  for (int s = 128; s > 0; s >>= 1){ if (d < s) red[d] += red[d+s]; __syncthreads(); }
  if (d == 0) bsp[n] = bs[n] - red[0];
  __syncthreads();
  red[d] = mrO * wc;
  __syncthreads();
  for (int s = 128; s > 0; s >>= 1){ if (d < s) red[d] += red[d+s]; __syncthreads(); }
  if (d == 0) bcp[n] = bc[n] - red[0];
}

// ---------------- weight prep: WkT/WvT/WqT + fragment-major WvF/WqF/WkF2 ----------------
__global__ __launch_bounds__(512) void ca_prep_kvq(const float* __restrict__ Wk,
    const float* __restrict__ Wv, const float* __restrict__ Wq,
    unsigned short* __restrict__ WkT, unsigned short* __restrict__ WvT,
    unsigned short* __restrict__ WqT, unsigned short* __restrict__ WkF2,
    unsigned short* __restrict__ WvF, unsigned short* __restrict__ WqF){
  int c = blockIdx.x & 511, m = blockIdx.x >> 9;
  int n = threadIdx.x;
  if (m == 3){   // WkF2: fragment-major Wk for the qk GEMM (A-operand, K=64)
    size_t idx = (size_t)c*512 + n;
    int h = (int)(idx >> 15), nn = (int)((idx >> 6) & 511), dd = (int)(idx & 63);
    int nt = nn >> 4, j = nn & 15, kq = dd >> 5, hi = (dd >> 3) & 3, e = dd & 7;
    WkF2[(size_t)((h*32 + nt)*2 + kq)*512 + (hi*16 + j)*8 + e] = f2bf(Wk[idx]);
    return;
  }
  int h = c >> 6, dd = c & 63;
  const float* W = (m == 0) ? Wk : (m == 1) ? Wv : Wq;
  unsigned short* O = (m == 0) ? WkT : (m == 1) ? WvT : WqT;
  float scale = (m == 2) ? 0.125f : 1.f;
  unsigned short v = f2bf(W[((size_t)h*512 + n)*64 + dd] * scale);
  O[(size_t)c*512 + n] = v;
  if (m != 0){
    int nt = (c >> 4) & 3, j = c & 15;
    int kk = n >> 5, hi = (n >> 3) & 3, e = n & 7;
    size_t fi = (size_t)((h*16 + kk)*4 + nt)*512 + (hi*16 + j)*8 + e;
    if (m == 1) WvF[fi] = v; else WqF[fi] = v;
  }
}

// ---------------- Q kernel (fallback path, unchanged R9 structure) ----------------
__global__ __launch_bounds__(512) void ca_q_kernel(const float* __restrict__ state,
    const int* __restrict__ agp,
    const unsigned short* __restrict__ WsT, const float* __restrict__ bsp,
    const unsigned short* __restrict__ WqT, unsigned short* __restrict__ Qws){
  __shared__ unsigned short U[32*512];
  __shared__ float bias_s[512];
  unsigned short* Alds = U;
  unsigned short* SE = U;
  int tid = threadIdx.x, lane = tid & 63, w = tid >> 6;
  int j = lane & 15, hi = lane >> 4;
  int b0 = blockIdx.x * 32;
  int ag = agp[0];

  for (int s = tid; s < 32*32; s += 512){
    int row = s >> 5, kg = s & 31;
    const float* p = state + (((size_t)(b0 + row) * 16 + ag) << 8) + kg * 8;
    f32x4 v0 = *(const f32x4*)p, v1 = *(const f32x4*)(p + 4);
    ushort8 hv;
    hv[0]=f2bf(v0[0]); hv[1]=f2bf(v0[1]); hv[2]=f2bf(v0[2]); hv[3]=f2bf(v0[3]);
    hv[4]=f2bf(v1[0]); hv[5]=f2bf(v1[1]); hv[6]=f2bf(v1[2]); hv[7]=f2bf(v1[3]);
    *(ushort8*)&Alds[row*256 + ((kg ^ (row & 7)) << 3)] = hv;
  }
  bias_s[tid & 511] = bsp[tid & 511];
  __syncthreads();

  int cb = w * 64;
  f32x4 zero4 = {0.f, 0.f, 0.f, 0.f};
  f32x4 acc[2][4];
  #pragma unroll
  for (int a1 = 0; a1 < 2; a1++)
    #pragma unroll
    for (int a2 = 0; a2 < 4; a2++) acc[a1][a2] = zero4;

  #pragma unroll
  for (int kk = 0; kk < 8; kk++){
    short8 bfr[4];
    #pragma unroll
    for (int nt = 0; nt < 4; nt++)
      bfr[nt] = *(const short8*)&WsT[(size_t)(cb + nt*16 + j)*256 + kk*32 + hi*8];
    #pragma unroll
    for (int mt = 0; mt < 2; mt++){
      int row = mt*16 + j;
      short8 afr = *(const short8*)&Alds[row*256 + ((((kk << 2) | hi) ^ (row & 7)) << 3)];
      #pragma unroll
      for (int nt = 0; nt < 4; nt++)
        acc[mt][nt] = __builtin_amdgcn_mfma_f32_16x16x32_bf16(afr, bfr[nt], acc[mt][nt], 0, 0, 0);
    }
  }
  __syncthreads();
  #pragma unroll
  for (int mt = 0; mt < 2; mt++)
    #pragma unroll
    for (int nt = 0; nt < 4; nt++)
      #pragma unroll
      for (int i = 0; i < 4; i++){
        int row = mt*16 + hi*4 + i, col = cb + nt*16 + j;
        float x = leaky(acc[mt][nt][i] + bias_s[col]);
        SE[row*512 + ((((col >> 3) ^ (row & 7)) << 3) | (col & 7))] = f2bf(x);
      }
  __syncthreads();

  f32x4 qa[2][4];
  #pragma unroll
  for (int a1 = 0; a1 < 2; a1++)
    #pragma unroll
    for (int a2 = 0; a2 < 4; a2++) qa[a1][a2] = zero4;
  #pragma unroll
  for (int kk = 0; kk < 16; kk++){
    short8 bfr[4];
    #pragma unroll
    for (int nt = 0; nt < 4; nt++)
      bfr[nt] = *(const short8*)&WqT[(size_t)(cb + nt*16 + j)*512 + kk*32 + hi*8];
    #pragma unroll
    for (int mt = 0; mt < 2; mt++){
      int row = mt*16 + j;
      short8 afr = *(const short8*)&SE[row*512 + ((((kk << 2) | hi) ^ (row & 7)) << 3)];
      #pragma unroll
      for (int nt = 0; nt < 4; nt++)
        qa[mt][nt] = __builtin_amdgcn_mfma_f32_16x16x32_bf16(afr, bfr[nt], qa[mt][nt], 0, 0, 0);
    }
  }
  #pragma unroll
  for (int mt = 0; mt < 2; mt++)
    #pragma unroll
    for (int nt = 0; nt < 4; nt++)
      #pragma unroll
      for (int i = 0; i < 4; i++)
        Qws[(size_t)(b0 + mt*16 + hi*4 + i)*512 + cb + nt*16 + j] = f2bf(qa[mt][nt][i]);
}

// ---------------- Q kernel (qk path): 16 batches/block, stride-520, swapped GEMMs ----------------
__global__ __launch_bounds__(512) void ca_q_kernel_qk(const float* __restrict__ state,
    const int* __restrict__ agp,
    const unsigned short* __restrict__ WsF, const float* __restrict__ bsp,
    const unsigned short* __restrict__ WqF, const unsigned short* __restrict__ WkF2,
    unsigned short* __restrict__ QKws){
  __shared__ unsigned short U[16*SAS];      // ~16.6KB union: Alds (stride 256) / SE / Qlds
  __shared__ float bias_s[512];
  unsigned short* Alds = U;
  unsigned short* SE = U;
  unsigned short* Qlds = U;
  int tid = threadIdx.x, lane = tid & 63, w = tid >> 6;
  int j = lane & 15, hi = lane >> 4;
  int b0 = blockIdx.x * 16;
  int ag = agp[0];
  f32x4 zero4 = {0.f, 0.f, 0.f, 0.f};

  {
    int row = tid >> 5, kg = tid & 31;
    const float* p = state + (((size_t)(b0 + row) * 16 + ag) << 8) + kg * 8;
    f32x4 v0 = *(const f32x4*)p, v1 = *(const f32x4*)(p + 4);
    ushort8 hv;
    hv[0]=f2bf(v0[0]); hv[1]=f2bf(v0[1]); hv[2]=f2bf(v0[2]); hv[3]=f2bf(v0[3]);
    hv[4]=f2bf(v1[0]); hv[5]=f2bf(v1[1]); hv[6]=f2bf(v1[2]); hv[7]=f2bf(v1[3]);
    *(ushort8*)&Alds[row*256 + ((kg ^ (row & 7)) << 3)] = hv;
  }
  bias_s[tid] = bsp[tid];
  __syncthreads();

  int cb = w * 64;

  // GEMM1 (swapped): acc[nt] rows = s_enc cols, cols = batch rows
  f32x4 acc[4];
  #pragma unroll
  for (int a2 = 0; a2 < 4; a2++) acc[a2] = zero4;
  #pragma unroll
  for (int kk = 0; kk < 8; kk++){
    short8 bfr[4];
    #pragma unroll
    for (int nt = 0; nt < 4; nt++)
      bfr[nt] = *(const short8*)&WsF[(size_t)((w*8 + kk)*4 + nt)*512 + lane*8];
    short8 afr = *(const short8*)&Alds[j*256 + ((((kk << 2) | hi) ^ (j & 7)) << 3)];
    #pragma unroll
    for (int nt = 0; nt < 4; nt++)
      acc[nt] = __builtin_amdgcn_mfma_f32_16x16x32_bf16(bfr[nt], afr, acc[nt], 0, 0, 0);
  }
  __syncthreads();   // Alds dead; SE overlays it
  #pragma unroll
  for (int nt = 0; nt < 4; nt++){
    int nb = cb + nt*16 + hi*4;
    bfu4 pk;
    #pragma unroll
    for (int i = 0; i < 4; i++) pk[i] = f2bf(leaky(acc[nt][i] + bias_s[nb + i]));
    *(bfu4*)&SE[j*SAS + nb] = pk;
  }
  __syncthreads();

  // q-GEMM (swapped): qa[nt] rows = q cols, cols = batch rows
  f32x4 qa[4];
  #pragma unroll
  for (int a2 = 0; a2 < 4; a2++) qa[a2] = zero4;
  #pragma unroll
  for (int kk = 0; kk < 16; kk++){
    short8 bfr[4];
    #pragma unroll
    for (int nt = 0; nt < 4; nt++)
      bfr[nt] = *(const short8*)&WqF[(size_t)((w*16 + kk)*4 + nt)*512 + lane*8];
    short8 afr = *(const short8*)&SE[j*SAS + kk*32 + hi*8];
    #pragma unroll
    for (int nt = 0; nt < 4; nt++)
      qa[nt] = __builtin_amdgcn_mfma_f32_16x16x32_bf16(bfr[nt], afr, qa[nt], 0, 0, 0);
  }
  __syncthreads();   // SE dead; Qlds overlays it
  #pragma unroll
  for (int nt = 0; nt < 4; nt++){
    int nb = cb + nt*16 + hi*4;
    bfu4 pk;
    #pragma unroll
    for (int i = 0; i < 4; i++) pk[i] = f2bf(qa[nt][i]);
    *(bfu4*)&Qlds[j*SAS + nb] = pk;
  }
  __syncthreads();

  // qk GEMM (swapped): C rows = n, cols = batch j; packed 8B stores
  short8 aq[2];
  #pragma unroll
  for (int kq = 0; kq < 2; kq++)
    aq[kq] = *(const short8*)&Qlds[j*SAS + w*64 + kq*32 + hi*8];
  for (int nt = 0; nt < 32; nt++){
    short8 bf0 = *(const short8*)&WkF2[(size_t)((w*32 + nt)*2 + 0)*512 + lane*8];
    short8 bf1 = *(const short8*)&WkF2[(size_t)((w*32 + nt)*2 + 1)*512 + lane*8];
    f32x4 qt = zero4;
    qt = __builtin_amdgcn_mfma_f32_16x16x32_bf16(bf0, aq[0], qt, 0, 0, 0);
    qt = __builtin_amdgcn_mfma_f32_16x16x32_bf16(bf1, aq[1], qt, 0, 0, 0);
    bfu4 pk;
    pk[0] = f2bf(qt[0]); pk[1] = f2bf(qt[1]); pk[2] = f2bf(qt[2]); pk[3] = f2bf(qt[3]);
    *(bfu4*)&QKws[((size_t)(b0 + j)*8 + w)*512 + nt*16 + hi*4] = pk;
  }
}

// ---------------- main kernel (qk path): stride-520 SA, swapped GEMM1, packed writes ----------------
__global__ __launch_bounds__(512) void ca_main_kernel_qk(const float* __restrict__ state,
    const int* __restrict__ agp,
    const unsigned short* __restrict__ WcF, const float* __restrict__ bcp,
    const unsigned short* __restrict__ WvF, const unsigned short* __restrict__ QKws,
    float* __restrict__ out){
  __shared__ unsigned short U[128*SAS];     // 130KB union: Alds (first 64KB, stride 256), SA (stride 520)
  __shared__ float bias_s[512];
  __shared__ float Wl[8*16*8];              // wgt[b][a][h], 4KB
  unsigned short* Alds = U;
  unsigned short* SA = U;
  int tid = threadIdx.x, lane = tid & 63, w = tid >> 6;
  int j = lane & 15, hi = lane >> 4;
  int b0 = blockIdx.x * 8;
  int ag = agp[0];
  f32x4 zero4 = {0.f, 0.f, 0.f, 0.f};
  short8 zero8 = {0,0,0,0,0,0,0,0};

  #pragma unroll
  for (int g = 0; g < 2; g++){
    f32x4 st0[4], st1[4];
    #pragma unroll
    for (int it = 0; it < 4; it++){
      int s = tid + 512*(g*4 + it);
      int row = s >> 5, kg = s & 31;
      int bl = row >> 4, ai = row & 15;
      if (ai < 15){
        int a = ai + (ai >= ag ? 1 : 0);
        const float* p = state + (((size_t)(b0 + bl) * 16 + a) << 8) + kg * 8;
        st0[it] = *(const f32x4*)p;
        st1[it] = *(const f32x4*)(p + 4);
      } else { st0[it] = zero4; st1[it] = zero4; }
    }
    #pragma unroll
    for (int it = 0; it < 4; it++){
      int s = tid + 512*(g*4 + it);
      int row = s >> 5, kg = s & 31;
      ushort8 hv;
      hv[0]=f2bf(st0[it][0]); hv[1]=f2bf(st0[it][1]); hv[2]=f2bf(st0[it][2]); hv[3]=f2bf(st0[it][3]);
      hv[4]=f2bf(st1[it][0]); hv[5]=f2bf(st1[it][1]); hv[6]=f2bf(st1[it][2]); hv[7]=f2bf(st1[it][3]);
      *(ushort8*)&Alds[row*256 + ((kg ^ (row & 7)) << 3)] = hv;
    }
  }
  bias_s[tid] = bcp[tid];
  __syncthreads();

  int cb = w * 64;

  // ---- GEMM1 (swapped): acc[mt][nt] rows = sa cols (hi*4+i), cols = sa rows (j)
  f32x4 acc[8][4];
  #pragma unroll
  for (int a1 = 0; a1 < 8; a1++)
    #pragma unroll
    for (int a2 = 0; a2 < 4; a2++) acc[a1][a2] = zero4;
  {
    short8 bcur[4], bnxt[4];
    #pragma unroll
    for (int nt = 0; nt < 4; nt++)
      bcur[nt] = *(const short8*)&WcF[(size_t)((w*8 + 0)*4 + nt)*512 + lane*8];
    #pragma unroll 1
    for (int kk = 0; kk < 8; kk++){
      if (kk < 7){
        #pragma unroll
        for (int nt = 0; nt < 4; nt++)
          bnxt[nt] = *(const short8*)&WcF[(size_t)((w*8 + kk + 1)*4 + nt)*512 + lane*8];
      }
      #pragma unroll
      for (int mt = 0; mt < 8; mt++){
        int row = mt*16 + j;
        short8 afr = *(const short8*)&Alds[row*256 + ((((kk << 2) | hi) ^ (row & 7)) << 3)];
        #pragma unroll
        for (int nt = 0; nt < 4; nt++)
          acc[mt][nt] = __builtin_amdgcn_mfma_f32_16x16x32_bf16(bcur[nt], afr, acc[mt][nt], 0, 0, 0);
      }
      #pragma unroll
      for (int nt = 0; nt < 4; nt++) bcur[nt] = bnxt[nt];
    }
  }
  __syncthreads();   // Alds dead; SA overlays
  #pragma unroll
  for (int mt = 0; mt < 8; mt++)
    #pragma unroll
    for (int nt = 0; nt < 4; nt++){
      int m = mt*16 + j;
      int nb = cb + nt*16 + hi*4;
      bfu4 pk;
      #pragma unroll
      for (int i = 0; i < 4; i++) pk[i] = f2bf(leaky(acc[mt][nt][i] + bias_s[nb + i]));
      *(bfu4*)&SA[m*SAS + nb] = pk;
    }
  __syncthreads();

  // ---- scores for batch b0+w: M=16 agents x N=16 heads(8 valid), K=512
  f32x4 qs = zero4;
  {
    size_t qbase = ((size_t)(b0 + w)*8 + (j & 7))*512;
    #pragma unroll
    for (int kk = 0; kk < 16; kk++){
      short8 bq = *(const short8*)&QKws[qbase + kk*32 + hi*8];
      if (j >= 8) bq = zero8;
      short8 afr = *(const short8*)&SA[(w*16 + j)*SAS + kk*32 + hi*8];
      qs = __builtin_amdgcn_mfma_f32_16x16x32_bf16(afr, bq, qs, 0, 0, 0);
    }
  }
  // softmax over agents (rows) per head col j
  {
    float sv0 = qs[0], sv1 = qs[1], sv2 = qs[2], sv3 = qs[3];
    sv3 = (hi == 3) ? -1e30f : sv3;         // mask pad agent a=15
    float m = fmaxf(fmaxf(sv0, sv1), fmaxf(sv2, sv3));
    m = fmaxf(m, __shfl_xor(m, 16)); m = fmaxf(m, __shfl_xor(m, 32));
    float e0 = __expf(sv0-m), e1 = __expf(sv1-m), e2 = __expf(sv2-m), e3 = __expf(sv3-m);
    float sum = e0 + e1 + e2 + e3;
    sum += __shfl_xor(sum, 16); sum += __shfl_xor(sum, 32);
    float inv = 1.f / sum;
    if (j < 8){
      Wl[w*128 + (hi*4+0)*8 + j] = e0*inv;
      Wl[w*128 + (hi*4+1)*8 + j] = e1*inv;
      Wl[w*128 + (hi*4+2)*8 + j] = e2*inv;
      Wl[w*128 + (hi*4+3)*8 + j] = e3*inv;
    }
  }

  // ---- GEMM2-V (unswapped: lane reduction over agents stays hi/i-local)
  f32x4 va[8][4];
  #pragma unroll
  for (int a1 = 0; a1 < 8; a1++)
    #pragma unroll
    for (int a2 = 0; a2 < 4; a2++) va[a1][a2] = zero4;
  {
    short8 bcur[4], bnxt[4];
    #pragma unroll
    for (int nt = 0; nt < 4; nt++)
      bcur[nt] = *(const short8*)&WvF[(size_t)((w*16 + 0)*4 + nt)*512 + lane*8];
    #pragma unroll 1
    for (int kk = 0; kk < 16; kk++){
      if (kk < 15){
        #pragma unroll
        for (int nt = 0; nt < 4; nt++)
          bnxt[nt] = *(const short8*)&WvF[(size_t)((w*16 + kk + 1)*4 + nt)*512 + lane*8];
      }
      #pragma unroll
      for (int mt = 0; mt < 8; mt++){
        short8 afr = *(const short8*)&SA[(mt*16 + j)*SAS + kk*32 + hi*8];
        #pragma unroll
        for (int nt = 0; nt < 4; nt++)
          va[mt][nt] = __builtin_amdgcn_mfma_f32_16x16x32_bf16(afr, bcur[nt], va[mt][nt], 0, 0, 0);
      }
      #pragma unroll
      for (int nt = 0; nt < 4; nt++) bcur[nt] = bnxt[nt];
    }
  }
  __syncthreads();   // Wl writes (pre-V) now visible to all waves

  // ---- att = sum_a wgt * leaky(V); wave w = head w reads wgt[mt][a][w]
  #pragma unroll
  for (int mt = 0; mt < 8; mt++){
    float w0 = Wl[mt*128 + (hi*4+0)*8 + w];
    float w1 = Wl[mt*128 + (hi*4+1)*8 + w];
    float w2 = Wl[mt*128 + (hi*4+2)*8 + w];
    float w3 = Wl[mt*128 + (hi*4+3)*8 + w];
    float ap0 = w0*leaky(va[mt][0][0]) + w1*leaky(va[mt][0][1]) + w2*leaky(va[mt][0][2]) + w3*leaky(va[mt][0][3]);
    float ap1 = w0*leaky(va[mt][1][0]) + w1*leaky(va[mt][1][1]) + w2*leaky(va[mt][1][2]) + w3*leaky(va[mt][1][3]);
    float ap2 = w0*leaky(va[mt][2][0]) + w1*leaky(va[mt][2][1]) + w2*leaky(va[mt][2][2]) + w3*leaky(va[mt][2][3]);
    float ap3 = w0*leaky(va[mt][3][0]) + w1*leaky(va[mt][3][1]) + w2*leaky(va[mt][3][2]) + w3*leaky(va[mt][3][3]);
    ap0 += __shfl_xor(ap0, 16); ap0 += __shfl_xor(ap0, 32);
    ap1 += __shfl_xor(ap1, 16); ap1 += __shfl_xor(ap1, 32);
    ap2 += __shfl_xor(ap2, 16); ap2 += __shfl_xor(ap2, 32);
    ap3 += __shfl_xor(ap3, 16); ap3 += __shfl_xor(ap3, 32);
    float val = (hi == 0) ? ap0 : (hi == 1) ? ap1 : (hi == 2) ? ap2 : ap3;
    out[(size_t)(b0 + mt)*512 + cb + lane] = val;
  }
}

// ---------------- main kernel (fallback = R9, unchanged) ----------------
__global__ __launch_bounds__(512) void ca_main_kernel(const float* __restrict__ state,
    const int* __restrict__ agp,
    const unsigned short* __restrict__ WcT, const float* __restrict__ bcp,
    const unsigned short* __restrict__ WkT, const unsigned short* __restrict__ WvT,
    const unsigned short* __restrict__ Qws, float* __restrict__ out){
  __shared__ unsigned short U[128*512];
  __shared__ unsigned short Qs[8*512];
  __shared__ float bias_s[512];
  unsigned short* Alds = U;
  unsigned short* SA = U;
  int tid = threadIdx.x, lane = tid & 63, w = tid >> 6;
  int j = lane & 15, hi = lane >> 4;
  int b0 = blockIdx.x * 8;
  int ag = agp[0];
  f32x4 zero4 = {0.f, 0.f, 0.f, 0.f};

  #pragma unroll
  for (int g = 0; g < 2; g++){
    f32x4 st0[4], st1[4];
    #pragma unroll
    for (int it = 0; it < 4; it++){
      int s = tid + 512*(g*4 + it);
      int row = s >> 5, kg = s & 31;
      int bl = row >> 4, ai = row & 15;
      if (ai < 15){
        int a = ai + (ai >= ag ? 1 : 0);
        const float* p = state + (((size_t)(b0 + bl) * 16 + a) << 8) + kg * 8;
        st0[it] = *(const f32x4*)p;
        st1[it] = *(const f32x4*)(p + 4);
      } else { st0[it] = zero4; st1[it] = zero4; }
    }
    #pragma unroll
    for (int it = 0; it < 4; it++){
      int s = tid + 512*(g*4 + it);
      int row = s >> 5, kg = s & 31;
      ushort8 hv;
      hv[0]=f2bf(st0[it][0]); hv[1]=f2bf(st0[it][1]); hv[2]=f2bf(st0[it][2]); hv[3]=f2bf(st0[it][3]);
      hv[4]=f2bf(st1[it][0]); hv[5]=f2bf(st1[it][1]); hv[6]=f2bf(st1[it][2]); hv[7]=f2bf(st1[it][3]);
      *(ushort8*)&Alds[row*256 + ((kg ^ (row & 7)) << 3)] = hv;
    }
  }
  *(ushort8*)&Qs[tid*8] = *(const ushort8*)&Qws[(size_t)b0*512 + tid*8];
  bias_s[tid] = bcp[tid];
  __syncthreads();

  int cb = w * 64;

  f32x4 acc[8][4];
  #pragma unroll
  for (int a1 = 0; a1 < 8; a1++)
    #pragma unroll
    for (int a2 = 0; a2 < 4; a2++) acc[a1][a2] = zero4;
  {
    short8 bcur[4], bnxt[4];
    #pragma unroll
    for (int nt = 0; nt < 4; nt++)
      bcur[nt] = *(const short8*)&WcT[(size_t)(cb + nt*16 + j)*256 + hi*8];
    #pragma unroll 1
    for (int kk = 0; kk < 8; kk++){
      if (kk < 7){
        #pragma unroll
        for (int nt = 0; nt < 4; nt++)
          bnxt[nt] = *(const short8*)&WcT[(size_t)(cb + nt*16 + j)*256 + (kk+1)*32 + hi*8];
      }
      #pragma unroll
      for (int mt = 0; mt < 8; mt++){
        int row = mt*16 + j;
        short8 afr = *(const short8*)&Alds[row*256 + ((((kk << 2) | hi) ^ (row & 7)) << 3)];
        #pragma unroll
        for (int nt = 0; nt < 4; nt++)
          acc[mt][nt] = __builtin_amdgcn_mfma_f32_16x16x32_bf16(afr, bcur[nt], acc[mt][nt], 0, 0, 0);
      }
      #pragma unroll
      for (int nt = 0; nt < 4; nt++) bcur[nt] = bnxt[nt];
    }
  }
  __syncthreads();
  #pragma unroll
  for (int mt = 0; mt < 8; mt++)
    #pragma unroll
    for (int nt = 0; nt < 4; nt++)
      #pragma unroll
      for (int i = 0; i < 4; i++){
        int row = mt*16 + hi*4 + i, col = cb + nt*16 + j;
        float x = leaky(acc[mt][nt][i] + bias_s[col]);
        SA[row*512 + ((((col >> 3) ^ (row & 7)) << 3) | (col & 7))] = f2bf(x);
      }
  __syncthreads();

  f32x4 ka[8][4];
  #pragma unroll
  for (int a1 = 0; a1 < 8; a1++)
    #pragma unroll
    for (int a2 = 0; a2 < 4; a2++) ka[a1][a2] = zero4;
  {
    short8 bcur[4], bnxt[4];
    #pragma unroll
    for (int nt = 0; nt < 4; nt++)
      bcur[nt] = *(const short8*)&WkT[(size_t)(cb + nt*16 + j)*512 + hi*8];
    #pragma unroll 1
    for (int kk = 0; kk < 16; kk++){
      if (kk < 15){
        #pragma unroll
        for (int nt = 0; nt < 4; nt++)
          bnxt[nt] = *(const short8*)&WkT[(size_t)(cb + nt*16 + j)*512 + (kk+1)*32 + hi*8];
      }
      #pragma unroll
      for (int mt = 0; mt < 8; mt++){
        int row = mt*16 + j;
        short8 afr = *(const short8*)&SA[row*512 + ((((kk << 2) | hi) ^ (row & 7)) << 3)];
        #pragma unroll
        for (int nt = 0; nt < 4; nt++)
          ka[mt][nt] = __builtin_amdgcn_mfma_f32_16x16x32_bf16(afr, bcur[nt], ka[mt][nt], 0, 0, 0);
      }
      #pragma unroll
      for (int nt = 0; nt < 4; nt++) bcur[nt] = bnxt[nt];
    }
  }

  float wgt[8][4];
  #pragma unroll
  for (int mt = 0; mt < 8; mt++){
    float sv[4];
    #pragma unroll
    for (int i = 0; i < 4; i++){
      float t = 0.f;
      #pragma unroll
      for (int nt = 0; nt < 4; nt++)
        t += bf2f(Qs[mt*512 + cb + nt*16 + j]) * ka[mt][nt][i];
      t += __shfl_xor(t, 1); t += __shfl_xor(t, 2);
      t += __shfl_xor(t, 4); t += __shfl_xor(t, 8);
      sv[i] = t;
    }
    sv[3] = (hi == 3) ? -1e30f : sv[3];
    float m = fmaxf(fmaxf(sv[0], sv[1]), fmaxf(sv[2], sv[3]));
    m = fmaxf(m, __shfl_xor(m, 16)); m = fmaxf(m, __shfl_xor(m, 32));
    float e0 = __expf(sv[0]-m), e1 = __expf(sv[1]-m), e2 = __expf(sv[2]-m), e3 = __expf(sv[3]-m);
    float sum = e0 + e1 + e2 + e3;
    sum += __shfl_xor(sum, 16); sum += __shfl_xor(sum, 32);
    float inv = 1.f / sum;
    wgt[mt][0] = e0*inv; wgt[mt][1] = e1*inv; wgt[mt][2] = e2*inv; wgt[mt][3] = e3*inv;
  }

  f32x4 va[8][4];
  #pragma unroll
  for (int a1 = 0; a1 < 8; a1++)
    #pragma unroll
    for (int a2 = 0; a2 < 4; a2++) va[a1][a2] = zero4;
  {
    short8 bcur[4], bnxt[4];
    #pragma unroll
    for (int nt = 0; nt < 4; nt++)
      bcur[nt] = *(const short8*)&WvT[(size_t)(cb + nt*16 + j)*512 + hi*8];
    #pragma unroll 1
    for (int kk = 0; kk < 16; kk++){
      if (kk < 15){
        #pragma unroll
        for (int nt = 0; nt < 4; nt++)
          bnxt[nt] = *(const short8*)&WvT[(size_t)(cb + nt*16 + j)*512 + (kk+1)*32 + hi*8];
      }
      #pragma unroll
      for (int mt = 0; mt < 8; mt++){
        int row = mt*16 + j;
        short8 afr = *(const short8*)&SA[row*512 + ((((kk << 2) | hi) ^ (row & 7)) << 3)];
        #pragma unroll
        for (int nt = 0; nt < 4; nt++)
          va[mt][nt] = __builtin_amdgcn_mfma_f32_16x16x32_bf16(afr, bcur[nt], va[mt][nt], 0, 0, 0);
      }
      #pragma unroll
      for (int nt = 0; nt < 4; nt++) bcur[nt] = bnxt[nt];
    }
  }

  #pragma unroll
  for (int mt = 0; mt < 8; mt++){
    float ap0 = 0.f, ap1 = 0.f, ap2 = 0.f, ap3 = 0.f;
    #pragma unroll
    for (int i = 0; i < 4; i++){
      float wv = wgt[mt][i];
      ap0 += wv * leaky(va[mt][0][i]);
      ap1 += wv * leaky(va[mt][1][i]);
      ap2 += wv * leaky(va[mt][2][i]);
      ap3 += wv * leaky(va[mt][3][i]);
    }
    ap0 += __shfl_xor(ap0, 16); ap0 += __shfl_xor(ap0, 32);
    ap1 += __shfl_xor(ap1, 16); ap1 += __shfl_xor(ap1, 32);
    ap2 += __shfl_xor(ap2, 16); ap2 += __shfl_xor(ap2, 32);
    ap3 += __shfl_xor(ap3, 16); ap3 += __shfl_xor(ap3, 32);
    float val = (hi == 0) ? ap0 : (hi == 1) ? ap1 : (hi == 2) ? ap2 : ap3;
    out[(size_t)(b0 + mt)*512 + cb + lane] = val;
  }
}

extern "C" void kernel_launch(void* const* d_in, const int* in_sizes, int n_in,
                              void* d_out, int out_size, void* d_ws, size_t ws_size,
                              hipStream_t stream) {
  const float* state = (const float*)d_in[0];
  const int*   agp   = (const int*)d_in[1];
  const float* Ws    = (const float*)d_in[2];
  const float* bs    = (const float*)d_in[3];
  const float* Wc    = (const float*)d_in[4];
  const float* bc    = (const float*)d_in[5];
  const float* Wk    = (const float*)d_in[6];
  const float* Wq    = (const float*)d_in[7];
  const float* Wv    = (const float*)d_in[8];
  float* out = (float*)d_out;
  int B = in_sizes[0] / 4096;   // state is (B,16,256)

  char* wsb = (char*)d_ws;
  float* part  = (float*)wsb;                                   // 1 MB
  float* stats = (float*)(wsb + (1 << 20));                     // 4 KB
  float* bsp   = (float*)(wsb + (1 << 20) + 4096);              // 2 KB
  float* bcp   = (float*)(wsb + (1 << 20) + 6144);              // 2 KB
  unsigned short* WsT  = (unsigned short*)(wsb + (1 << 20) + 8192);
  unsigned short* WcT  = WsT  + 512*256;
  unsigned short* WkT  = WcT  + 512*256;
  unsigned short* WvT  = WkT  + 512*512;
  unsigned short* WqT  = WvT  + 512*512;
  unsigned short* WkF2 = WqT  + 512*512;         // fragment-major Wk (qk GEMM)
  unsigned short* Qws  = WkF2 + 512*512;         // B*512  (fallback only)
  unsigned short* QKws = Qws  + (size_t)B*512;   // B*8*512
  unsigned short* WsF  = Qws;                    // F-layouts overlay Qws (qk path)
  unsigned short* WcF  = WsF + 512*256;
  unsigned short* WqF  = WcF + 512*256;
  unsigned short* WvF  = WqF + 512*512;

  size_t need = ((size_t)(1 << 20) + 8192)
              + 2ull*(512*256 + 512*256 + 512*512 + 512*512 + 512*512 + 512*512)
              + 2ull*B*512 + 2ull*B*8*512;
  bool qkp = (ws_size >= need);

  hipLaunchKernelGGL(ca_stats_partial, dim3(256), dim3(1024), 0, stream, state, agp, part, B);
  hipLaunchKernelGGL(ca_stats_final,   dim3(1),   dim3(1024), 0, stream, part, stats, 256, B);
  hipLaunchKernelGGL(ca_prep_sc,       dim3(512), dim3(256), 0, stream, Ws, bs, Wc, bc, stats, WsT, WcT, WsF, WcF, bsp, bcp);
  hipLaunchKernelGGL(ca_prep_kvq,      dim3(2048),dim3(512), 0, stream, Wk, Wv, Wq, WkT, WvT, WqT, WkF2, WvF, WqF);
  if (qkp){
    hipLaunchKernelGGL(ca_q_kernel_qk,   dim3(B/16),dim3(512), 0, stream, state, agp, WsF, bsp, WqF, WkF2, QKws);
    hipLaunchKernelGGL(ca_main_kernel_qk,dim3(B/8), dim3(512), 0, stream, state, agp, WcF, bcp, WvF, QKws, out);
  } else {
    hipLaunchKernelGGL(ca_q_kernel,      dim3(B/32),dim3(512), 0, stream, state, agp, WsT, bsp, WqT, Qws);
    hipLaunchKernelGGL(ca_main_kernel,   dim3(B/8), dim3(512), 0, stream, state, agp, WcT, bcp, WkT, WvT, Qws, out);
  }
}

// Round 14
// 234.194 us; speedup vs baseline: 1.8960x; 1.0018x over previous
//
#include <hip/hip_runtime.h>

typedef __attribute__((ext_vector_type(8))) short short8;
typedef __attribute__((ext_vector_type(8))) unsigned short ushort8;
typedef __attribute__((ext_vector_type(4))) unsigned short bfu4;
typedef __attribute__((ext_vector_type(4))) float f32x4;

__device__ __forceinline__ unsigned short f2bf(float f){
  unsigned int u = __builtin_bit_cast(unsigned int, f);
  u += 0x7fffu + ((u >> 16) & 1u);           // round-to-nearest-even
  return (unsigned short)(u >> 16);
}
__device__ __forceinline__ float bf2f(unsigned short h){
  unsigned int u = ((unsigned int)h) << 16;
  return __builtin_bit_cast(float, u);
}
__device__ __forceinline__ float leaky(float x){ return x > 0.f ? x : 0.3f * x; }

// ---------------- BN statistics: stage 1 (1024 thr: 4 batch-slices + LDS reduce) ----------------
__global__ __launch_bounds__(1024) void ca_stats_partial(const float* __restrict__ state,
    const int* __restrict__ agp, float* __restrict__ part, int B){
  int d = threadIdx.x & 255, sl = threadIdx.x >> 8;
  int ag = agp[0];
  int bPer = (B + 255) >> 8;
  int b0 = blockIdx.x * bPer;
  float sC = 0.f, ssC = 0.f, sO = 0.f, ssO = 0.f;
  for (int b = sl; b < bPer; b += 4){
    int bb = b0 + b;
    if (bb >= B) continue;
    const float* row = state + ((size_t)bb << 12);   // *16*256
    #pragma unroll
    for (int a = 0; a < 16; a++){
      float v = row[a*256 + d];
      bool isC = (a == ag);
      sC  += isC ? v   : 0.f;
      ssC += isC ? v*v : 0.f;
      sO  += isC ? 0.f : v;
      ssO += isC ? 0.f : v*v;
    }
  }
  __shared__ float red[4][4][256];
  red[sl][0][d] = sC; red[sl][1][d] = ssC; red[sl][2][d] = sO; red[sl][3][d] = ssO;
  __syncthreads();
  if (sl == 0){
    float* p = part + (size_t)blockIdx.x * 1024;
    p[d]     = red[0][0][d] + red[1][0][d] + red[2][0][d] + red[3][0][d];
    p[d+256] = red[0][1][d] + red[1][1][d] + red[2][1][d] + red[3][1][d];
    p[d+512] = red[0][2][d] + red[1][2][d] + red[2][2][d] + red[3][2][d];
    p[d+768] = red[0][3][d] + red[1][3][d] + red[2][3][d] + red[3][3][d];
  }
}

// ---------------- BN statistics: stage 2 (finalize rs, mean*rs), 1024 threads ----------------
__global__ __launch_bounds__(1024) void ca_stats_final(const float* __restrict__ part,
    float* __restrict__ stats, int nblk, int B){
  int d = threadIdx.x & 255, sl = threadIdx.x >> 8;
  float sC = 0.f, ssC = 0.f, sO = 0.f, ssO = 0.f;
  for (int g = sl; g < nblk; g += 4){
    const float* p = part + (size_t)g * 1024;
    sC += p[d]; ssC += p[d+256]; sO += p[d+512]; ssO += p[d+768];
  }
  __shared__ float red[4][4][256];
  red[sl][0][d] = sC; red[sl][1][d] = ssC; red[sl][2][d] = sO; red[sl][3][d] = ssO;
  __syncthreads();
  if (sl == 0){
    sC  = red[0][0][d] + red[1][0][d] + red[2][0][d] + red[3][0][d];
    ssC = red[0][1][d] + red[1][1][d] + red[2][1][d] + red[3][1][d];
    sO  = red[0][2][d] + red[1][2][d] + red[2][2][d] + red[3][2][d];
    ssO = red[0][3][d] + red[1][3][d] + red[2][3][d] + red[3][3][d];
    float nC = (float)B, nO = (float)B * 15.f;
    float mC = sC / nC, vC = ssC / nC - mC * mC;
    float mO = sO / nO, vO = ssO / nO - mO * mO;
    float rC = rsqrtf(vC + 1e-3f), rO = rsqrtf(vO + 1e-3f);
    stats[d] = rC; stats[d+256] = mC * rC; stats[d+512] = rO; stats[d+768] = mO * rO;
  }
}

// ---------------- weight prep: WsF/WcF (+WsT/WcT if writeT) + biases ----------------
__global__ __launch_bounds__(256) void ca_prep_sc(const float* __restrict__ Ws,
    const float* __restrict__ bs, const float* __restrict__ Wc, const float* __restrict__ bc,
    const float* __restrict__ stats, unsigned short* __restrict__ WsT,
    unsigned short* __restrict__ WcT, unsigned short* __restrict__ WsF,
    unsigned short* __restrict__ WcF, float* __restrict__ bsp, float* __restrict__ bcp,
    int writeT){
  int n = blockIdx.x, d = threadIdx.x;
  float rC = stats[d], mrC = stats[d+256], rO = stats[d+512], mrO = stats[d+768];
  float ws = Ws[(size_t)d*512 + n], wc = Wc[(size_t)d*512 + n];
  unsigned short wsb = f2bf(ws * rC), wcb = f2bf(wc * rO);
  if (writeT){
    WsT[(size_t)n*256 + d] = wsb;
    WcT[(size_t)n*256 + d] = wcb;
  }
  {
    int h = n >> 6, nt = (n >> 4) & 3, j = n & 15;
    int kk = d >> 5, hi = (d >> 3) & 3, e = d & 7;
    size_t fi = (size_t)((h*8 + kk)*4 + nt)*512 + (hi*16 + j)*8 + e;
    WsF[fi] = wsb;
    WcF[fi] = wcb;
  }
  __shared__ float red[256];
  red[d] = mrC * ws;
  __syncthreads();
  for (int s = 128; s > 0; s >>= 1){ if (d < s) red[d] += red[d+s]; __syncthreads(); }
  if (d == 0) bsp[n] = bs[n] - red[0];
  __syncthreads();
  red[d] = mrO * wc;
  __syncthreads();
  for (int s = 128; s > 0; s >>= 1){ if (d < s) red[d] += red[d+s]; __syncthreads(); }
  if (d == 0) bcp[n] = bc[n] - red[0];
}

// ---------------- weight prep: WvF/WqF/WkF2 (+WkT/WvT/WqT if writeT) ----------------
__global__ __launch_bounds__(512) void ca_prep_kvq(const float* __restrict__ Wk,
    const float* __restrict__ Wv, const float* __restrict__ Wq,
    unsigned short* __restrict__ WkT, unsigned short* __restrict__ WvT,
    unsigned short* __restrict__ WqT, unsigned short* __restrict__ WkF2,
    unsigned short* __restrict__ WvF, unsigned short* __restrict__ WqF, int writeT){
  int c = blockIdx.x & 511, m = blockIdx.x >> 9;
  int n = threadIdx.x;
  if (m == 3){   // WkF2: fragment-major Wk for the qk GEMM (A-operand, K=64)
    size_t idx = (size_t)c*512 + n;
    int h = (int)(idx >> 15), nn = (int)((idx >> 6) & 511), dd = (int)(idx & 63);
    int nt = nn >> 4, j = nn & 15, kq = dd >> 5, hi = (dd >> 3) & 3, e = dd & 7;
    WkF2[(size_t)((h*32 + nt)*2 + kq)*512 + (hi*16 + j)*8 + e] = f2bf(Wk[idx]);
    return;
  }
  if (m == 0 && !writeT) return;            // WkT only needed by fallback
  int h = c >> 6, dd = c & 63;
  const float* W = (m == 0) ? Wk : (m == 1) ? Wv : Wq;
  unsigned short* O = (m == 0) ? WkT : (m == 1) ? WvT : WqT;
  float scale = (m == 2) ? 0.125f : 1.f;
  unsigned short v = f2bf(W[((size_t)h*512 + n)*64 + dd] * scale);
  if (m == 0 || writeT) O[(size_t)c*512 + n] = v;
  if (m != 0){
    int nt = (c >> 4) & 3, j = c & 15;
    int kk = n >> 5, hi = (n >> 3) & 3, e = n & 7;
    size_t fi = (size_t)((h*16 + kk)*4 + nt)*512 + (hi*16 + j)*8 + e;
    if (m == 1) WvF[fi] = v; else WqF[fi] = v;
  }
}

// ---------------- Q kernel (fallback path, unchanged R9 structure) ----------------
__global__ __launch_bounds__(512) void ca_q_kernel(const float* __restrict__ state,
    const int* __restrict__ agp,
    const unsigned short* __restrict__ WsT, const float* __restrict__ bsp,
    const unsigned short* __restrict__ WqT, unsigned short* __restrict__ Qws){
  __shared__ unsigned short U[32*512];
  __shared__ float bias_s[512];
  unsigned short* Alds = U;
  unsigned short* SE = U;
  int tid = threadIdx.x, lane = tid & 63, w = tid >> 6;
  int j = lane & 15, hi = lane >> 4;
  int b0 = blockIdx.x * 32;
  int ag = agp[0];

  for (int s = tid; s < 32*32; s += 512){
    int row = s >> 5, kg = s & 31;
    const float* p = state + (((size_t)(b0 + row) * 16 + ag) << 8) + kg * 8;
    f32x4 v0 = *(const f32x4*)p, v1 = *(const f32x4*)(p + 4);
    ushort8 hv;
    hv[0]=f2bf(v0[0]); hv[1]=f2bf(v0[1]); hv[2]=f2bf(v0[2]); hv[3]=f2bf(v0[3]);
    hv[4]=f2bf(v1[0]); hv[5]=f2bf(v1[1]); hv[6]=f2bf(v1[2]); hv[7]=f2bf(v1[3]);
    *(ushort8*)&Alds[row*256 + ((kg ^ (row & 7)) << 3)] = hv;
  }
  bias_s[tid & 511] = bsp[tid & 511];
  __syncthreads();

  int cb = w * 64;
  f32x4 zero4 = {0.f, 0.f, 0.f, 0.f};
  f32x4 acc[2][4];
  #pragma unroll
  for (int a1 = 0; a1 < 2; a1++)
    #pragma unroll
    for (int a2 = 0; a2 < 4; a2++) acc[a1][a2] = zero4;

  #pragma unroll
  for (int kk = 0; kk < 8; kk++){
    short8 bfr[4];
    #pragma unroll
    for (int nt = 0; nt < 4; nt++)
      bfr[nt] = *(const short8*)&WsT[(size_t)(cb + nt*16 + j)*256 + kk*32 + hi*8];
    #pragma unroll
    for (int mt = 0; mt < 2; mt++){
      int row = mt*16 + j;
      short8 afr = *(const short8*)&Alds[row*256 + ((((kk << 2) | hi) ^ (row & 7)) << 3)];
      #pragma unroll
      for (int nt = 0; nt < 4; nt++)
        acc[mt][nt] = __builtin_amdgcn_mfma_f32_16x16x32_bf16(afr, bfr[nt], acc[mt][nt], 0, 0, 0);
    }
  }
  __syncthreads();
  #pragma unroll
  for (int mt = 0; mt < 2; mt++)
    #pragma unroll
    for (int nt = 0; nt < 4; nt++)
      #pragma unroll
      for (int i = 0; i < 4; i++){
        int row = mt*16 + hi*4 + i, col = cb + nt*16 + j;
        float x = leaky(acc[mt][nt][i] + bias_s[col]);
        SE[row*512 + ((((col >> 3) ^ (row & 7)) << 3) | (col & 7))] = f2bf(x);
      }
  __syncthreads();

  f32x4 qa[2][4];
  #pragma unroll
  for (int a1 = 0; a1 < 2; a1++)
    #pragma unroll
    for (int a2 = 0; a2 < 4; a2++) qa[a1][a2] = zero4;
  #pragma unroll
  for (int kk = 0; kk < 16; kk++){
    short8 bfr[4];
    #pragma unroll
    for (int nt = 0; nt < 4; nt++)
      bfr[nt] = *(const short8*)&WqT[(size_t)(cb + nt*16 + j)*512 + kk*32 + hi*8];
    #pragma unroll
    for (int mt = 0; mt < 2; mt++){
      int row = mt*16 + j;
      short8 afr = *(const short8*)&SE[row*512 + ((((kk << 2) | hi) ^ (row & 7)) << 3)];
      #pragma unroll
      for (int nt = 0; nt < 4; nt++)
        qa[mt][nt] = __builtin_amdgcn_mfma_f32_16x16x32_bf16(afr, bfr[nt], qa[mt][nt], 0, 0, 0);
    }
  }
  #pragma unroll
  for (int mt = 0; mt < 2; mt++)
    #pragma unroll
    for (int nt = 0; nt < 4; nt++)
      #pragma unroll
      for (int i = 0; i < 4; i++)
        Qws[(size_t)(b0 + mt*16 + hi*4 + i)*512 + cb + nt*16 + j] = f2bf(qa[mt][nt][i]);
}

// ---------------- Q kernel (qk path): 16 batches/block, XOR-swizzled, packed writes ----------------
__global__ __launch_bounds__(512) void ca_q_kernel_qk(const float* __restrict__ state,
    const int* __restrict__ agp,
    const unsigned short* __restrict__ WsF, const float* __restrict__ bsp,
    const unsigned short* __restrict__ WqF, const unsigned short* __restrict__ WkF2,
    unsigned short* __restrict__ QKws){
  __shared__ unsigned short U[16*512];      // 16KB union: Alds (stride 256) / SE / Qlds
  __shared__ float bias_s[512];
  unsigned short* Alds = U;
  unsigned short* SE = U;
  unsigned short* Qlds = U;
  int tid = threadIdx.x, lane = tid & 63, w = tid >> 6;
  int j = lane & 15, hi = lane >> 4;
  int b0 = blockIdx.x * 16;
  int ag = agp[0];
  f32x4 zero4 = {0.f, 0.f, 0.f, 0.f};

  {
    int row = tid >> 5, kg = tid & 31;
    const float* p = state + (((size_t)(b0 + row) * 16 + ag) << 8) + kg * 8;
    f32x4 v0 = *(const f32x4*)p, v1 = *(const f32x4*)(p + 4);
    ushort8 hv;
    hv[0]=f2bf(v0[0]); hv[1]=f2bf(v0[1]); hv[2]=f2bf(v0[2]); hv[3]=f2bf(v0[3]);
    hv[4]=f2bf(v1[0]); hv[5]=f2bf(v1[1]); hv[6]=f2bf(v1[2]); hv[7]=f2bf(v1[3]);
    *(ushort8*)&Alds[row*256 + ((kg ^ (row & 7)) << 3)] = hv;
  }
  bias_s[tid] = bsp[tid];
  __syncthreads();

  int cb = w * 64;

  // GEMM1 (swapped): acc[nt] rows = s_enc cols, cols = batch rows
  f32x4 acc[4];
  #pragma unroll
  for (int a2 = 0; a2 < 4; a2++) acc[a2] = zero4;
  #pragma unroll
  for (int kk = 0; kk < 8; kk++){
    short8 bfr[4];
    #pragma unroll
    for (int nt = 0; nt < 4; nt++)
      bfr[nt] = *(const short8*)&WsF[(size_t)((w*8 + kk)*4 + nt)*512 + lane*8];
    short8 afr = *(const short8*)&Alds[j*256 + ((((kk << 2) | hi) ^ (j & 7)) << 3)];
    #pragma unroll
    for (int nt = 0; nt < 4; nt++)
      acc[nt] = __builtin_amdgcn_mfma_f32_16x16x32_bf16(bfr[nt], afr, acc[nt], 0, 0, 0);
  }
  __syncthreads();   // Alds dead; SE overlays it
  #pragma unroll
  for (int nt = 0; nt < 4; nt++){
    int nb = cb + nt*16 + hi*4;
    int g = nb >> 3;
    bfu4 pk;
    #pragma unroll
    for (int i = 0; i < 4; i++) pk[i] = f2bf(leaky(acc[nt][i] + bias_s[nb + i]));
    *(bfu4*)&SE[j*512 + ((g ^ (j & 7)) << 3) + (hi & 1)*4] = pk;
  }
  __syncthreads();

  // q-GEMM (swapped)
  f32x4 qa[4];
  #pragma unroll
  for (int a2 = 0; a2 < 4; a2++) qa[a2] = zero4;
  #pragma unroll
  for (int kk = 0; kk < 16; kk++){
    short8 bfr[4];
    #pragma unroll
    for (int nt = 0; nt < 4; nt++)
      bfr[nt] = *(const short8*)&WqF[(size_t)((w*16 + kk)*4 + nt)*512 + lane*8];
    short8 afr = *(const short8*)&SE[j*512 + ((((kk << 2) | hi) ^ (j & 7)) << 3)];
    #pragma unroll
    for (int nt = 0; nt < 4; nt++)
      qa[nt] = __builtin_amdgcn_mfma_f32_16x16x32_bf16(bfr[nt], afr, qa[nt], 0, 0, 0);
  }
  __syncthreads();   // SE dead; Qlds overlays it
  #pragma unroll
  for (int nt = 0; nt < 4; nt++){
    int nb = cb + nt*16 + hi*4;
    int g = nb >> 3;
    bfu4 pk;
    #pragma unroll
    for (int i = 0; i < 4; i++) pk[i] = f2bf(qa[nt][i]);
    *(bfu4*)&Qlds[j*512 + ((g ^ (j & 7)) << 3) + (hi & 1)*4] = pk;
  }
  __syncthreads();

  // qk GEMM (swapped): C rows = n, cols = batch j; packed 8B stores
  short8 aq[2];
  #pragma unroll
  for (int kq = 0; kq < 2; kq++){
    int gq = w*8 + kq*4 + hi;
    aq[kq] = *(const short8*)&Qlds[j*512 + ((gq ^ (j & 7)) << 3)];
  }
  for (int nt = 0; nt < 32; nt++){
    short8 bf0 = *(const short8*)&WkF2[(size_t)((w*32 + nt)*2 + 0)*512 + lane*8];
    short8 bf1 = *(const short8*)&WkF2[(size_t)((w*32 + nt)*2 + 1)*512 + lane*8];
    f32x4 qt = zero4;
    qt = __builtin_amdgcn_mfma_f32_16x16x32_bf16(bf0, aq[0], qt, 0, 0, 0);
    qt = __builtin_amdgcn_mfma_f32_16x16x32_bf16(bf1, aq[1], qt, 0, 0, 0);
    bfu4 pk;
    pk[0] = f2bf(qt[0]); pk[1] = f2bf(qt[1]); pk[2] = f2bf(qt[2]); pk[3] = f2bf(qt[3]);
    *(bfu4*)&QKws[((size_t)(b0 + j)*8 + w)*512 + nt*16 + hi*4] = pk;
  }
}

// ---------------- main kernel (qk path): XOR-swizzled SA, packed swizzled writes ----------------
__global__ __launch_bounds__(512) void ca_main_kernel_qk(const float* __restrict__ state,
    const int* __restrict__ agp,
    const unsigned short* __restrict__ WcF, const float* __restrict__ bcp,
    const unsigned short* __restrict__ WvF, const unsigned short* __restrict__ QKws,
    float* __restrict__ out){
  __shared__ unsigned short U[128*512];     // 128KB union: Alds (first 64KB, stride 256), SA (stride 512 swz)
  __shared__ float bias_s[512];
  __shared__ float Wl[8*16*8];              // wgt[b][a][h], 4KB
  unsigned short* Alds = U;
  unsigned short* SA = U;
  int tid = threadIdx.x, lane = tid & 63, w = tid >> 6;
  int j = lane & 15, hi = lane >> 4;
  int b0 = blockIdx.x * 8;
  int ag = agp[0];
  f32x4 zero4 = {0.f, 0.f, 0.f, 0.f};
  short8 zero8 = {0,0,0,0,0,0,0,0};

  #pragma unroll
  for (int g = 0; g < 2; g++){
    f32x4 st0[4], st1[4];
    #pragma unroll
    for (int it = 0; it < 4; it++){
      int s = tid + 512*(g*4 + it);
      int row = s >> 5, kg = s & 31;
      int bl = row >> 4, ai = row & 15;
      if (ai < 15){
        int a = ai + (ai >= ag ? 1 : 0);
        const float* p = state + (((size_t)(b0 + bl) * 16 + a) << 8) + kg * 8;
        st0[it] = *(const f32x4*)p;
        st1[it] = *(const f32x4*)(p + 4);
      } else { st0[it] = zero4; st1[it] = zero4; }
    }
    #pragma unroll
    for (int it = 0; it < 4; it++){
      int s = tid + 512*(g*4 + it);
      int row = s >> 5, kg = s & 31;
      ushort8 hv;
      hv[0]=f2bf(st0[it][0]); hv[1]=f2bf(st0[it][1]); hv[2]=f2bf(st0[it][2]); hv[3]=f2bf(st0[it][3]);
      hv[4]=f2bf(st1[it][0]); hv[5]=f2bf(st1[it][1]); hv[6]=f2bf(st1[it][2]); hv[7]=f2bf(st1[it][3]);
      *(ushort8*)&Alds[row*256 + ((kg ^ (row & 7)) << 3)] = hv;
    }
  }
  bias_s[tid] = bcp[tid];
  __syncthreads();

  int cb = w * 64;

  // ---- GEMM1 (swapped): acc rows = sa cols (hi*4+i), cols = sa rows (j)
  f32x4 acc[8][4];
  #pragma unroll
  for (int a1 = 0; a1 < 8; a1++)
    #pragma unroll
    for (int a2 = 0; a2 < 4; a2++) acc[a1][a2] = zero4;
  {
    short8 bcur[4], bnxt[4];
    #pragma unroll
    for (int nt = 0; nt < 4; nt++)
      bcur[nt] = *(const short8*)&WcF[(size_t)((w*8 + 0)*4 + nt)*512 + lane*8];
    #pragma unroll 1
    for (int kk = 0; kk < 8; kk++){
      if (kk < 7){
        #pragma unroll
        for (int nt = 0; nt < 4; nt++)
          bnxt[nt] = *(const short8*)&WcF[(size_t)((w*8 + kk + 1)*4 + nt)*512 + lane*8];
      }
      #pragma unroll
      for (int mt = 0; mt < 8; mt++){
        int row = mt*16 + j;
        short8 afr = *(const short8*)&Alds[row*256 + ((((kk << 2) | hi) ^ (row & 7)) << 3)];
        #pragma unroll
        for (int nt = 0; nt < 4; nt++)
          acc[mt][nt] = __builtin_amdgcn_mfma_f32_16x16x32_bf16(bcur[nt], afr, acc[mt][nt], 0, 0, 0);
      }
      #pragma unroll
      for (int nt = 0; nt < 4; nt++) bcur[nt] = bnxt[nt];
    }
  }
  __syncthreads();   // Alds dead; SA overlays
  #pragma unroll
  for (int mt = 0; mt < 8; mt++)
    #pragma unroll
    for (int nt = 0; nt < 4; nt++){
      int m = mt*16 + j;
      int nb = cb + nt*16 + hi*4;
      int g = nb >> 3;
      bfu4 pk;
      #pragma unroll
      for (int i = 0; i < 4; i++) pk[i] = f2bf(leaky(acc[mt][nt][i] + bias_s[nb + i]));
      *(bfu4*)&SA[m*512 + ((g ^ (m & 7)) << 3) + (hi & 1)*4] = pk;
    }
  __syncthreads();

  // ---- scores for batch b0+w: M=16 agents x N=16 heads(8 valid), K=512
  f32x4 qs = zero4;
  {
    size_t qbase = ((size_t)(b0 + w)*8 + (j & 7))*512;
    #pragma unroll
    for (int kk = 0; kk < 16; kk++){
      short8 bq = *(const short8*)&QKws[qbase + kk*32 + hi*8];
      if (j >= 8) bq = zero8;
      int row = w*16 + j;
      short8 afr = *(const short8*)&SA[row*512 + ((((kk << 2) | hi) ^ (row & 7)) << 3)];
      qs = __builtin_amdgcn_mfma_f32_16x16x32_bf16(afr, bq, qs, 0, 0, 0);
    }
  }
  // softmax over agents (rows) per head col j
  {
    float sv0 = qs[0], sv1 = qs[1], sv2 = qs[2], sv3 = qs[3];
    sv3 = (hi == 3) ? -1e30f : sv3;         // mask pad agent a=15
    float m = fmaxf(fmaxf(sv0, sv1), fmaxf(sv2, sv3));
    m = fmaxf(m, __shfl_xor(m, 16)); m = fmaxf(m, __shfl_xor(m, 32));
    float e0 = __expf(sv0-m), e1 = __expf(sv1-m), e2 = __expf(sv2-m), e3 = __expf(sv3-m);
    float sum = e0 + e1 + e2 + e3;
    sum += __shfl_xor(sum, 16); sum += __shfl_xor(sum, 32);
    float inv = 1.f / sum;
    if (j < 8){
      Wl[w*128 + (hi*4+0)*8 + j] = e0*inv;
      Wl[w*128 + (hi*4+1)*8 + j] = e1*inv;
      Wl[w*128 + (hi*4+2)*8 + j] = e2*inv;
      Wl[w*128 + (hi*4+3)*8 + j] = e3*inv;
    }
  }

  // ---- GEMM2-V (unswapped: lane reduction over agents stays hi/i-local)
  f32x4 va[8][4];
  #pragma unroll
  for (int a1 = 0; a1 < 8; a1++)
    #pragma unroll
    for (int a2 = 0; a2 < 4; a2++) va[a1][a2] = zero4;
  {
    short8 bcur[4], bnxt[4];
    #pragma unroll
    for (int nt = 0; nt < 4; nt++)
      bcur[nt] = *(const short8*)&WvF[(size_t)((w*16 + 0)*4 + nt)*512 + lane*8];
    #pragma unroll 1
    for (int kk = 0; kk < 16; kk++){
      if (kk < 15){
        #pragma unroll
        for (int nt = 0; nt < 4; nt++)
          bnxt[nt] = *(const short8*)&WvF[(size_t)((w*16 + kk + 1)*4 + nt)*512 + lane*8];
      }
      #pragma unroll
      for (int mt = 0; mt < 8; mt++){
        int row = mt*16 + j;
        short8 afr = *(const short8*)&SA[row*512 + ((((kk << 2) | hi) ^ (row & 7)) << 3)];
        #pragma unroll
        for (int nt = 0; nt < 4; nt++)
          va[mt][nt] = __builtin_amdgcn_mfma_f32_16x16x32_bf16(afr, bcur[nt], va[mt][nt], 0, 0, 0);
      }
      #pragma unroll
      for (int nt = 0; nt < 4; nt++) bcur[nt] = bnxt[nt];
    }
  }
  __syncthreads();   // Wl writes (pre-V) now visible to all waves

  // ---- att = sum_a wgt * leaky(V); wave w = head w reads wgt[mt][a][w]
  #pragma unroll
  for (int mt = 0; mt < 8; mt++){
    float w0 = Wl[mt*128 + (hi*4+0)*8 + w];
    float w1 = Wl[mt*128 + (hi*4+1)*8 + w];
    float w2 = Wl[mt*128 + (hi*4+2)*8 + w];
    float w3 = Wl[mt*128 + (hi*4+3)*8 + w];
    float ap0 = w0*leaky(va[mt][0][0]) + w1*leaky(va[mt][0][1]) + w2*leaky(va[mt][0][2]) + w3*leaky(va[mt][0][3]);
    float ap1 = w0*leaky(va[mt][1][0]) + w1*leaky(va[mt][1][1]) + w2*leaky(va[mt][1][2]) + w3*leaky(va[mt][1][3]);
    float ap2 = w0*leaky(va[mt][2][0]) + w1*leaky(va[mt][2][1]) + w2*leaky(va[mt][2][2]) + w3*leaky(va[mt][2][3]);
    float ap3 = w0*leaky(va[mt][3][0]) + w1*leaky(va[mt][3][1]) + w2*leaky(va[mt][3][2]) + w3*leaky(va[mt][3][3]);
    ap0 += __shfl_xor(ap0, 16); ap0 += __shfl_xor(ap0, 32);
    ap1 += __shfl_xor(ap1, 16); ap1 += __shfl_xor(ap1, 32);
    ap2 += __shfl_xor(ap2, 16); ap2 += __shfl_xor(ap2, 32);
    ap3 += __shfl_xor(ap3, 16); ap3 += __shfl_xor(ap3, 32);
    float val = (hi == 0) ? ap0 : (hi == 1) ? ap1 : (hi == 2) ? ap2 : ap3;
    out[(size_t)(b0 + mt)*512 + cb + lane] = val;
  }
}

// ---------------- main kernel (fallback = R9, unchanged) ----------------
__global__ __launch_bounds__(512) void ca_main_kernel(const float* __restrict__ state,
    const int* __restrict__ agp,
    const unsigned short* __restrict__ WcT, const float* __restrict__ bcp,
    const unsigned short* __restrict__ WkT, const unsigned short* __restrict__ WvT,
    const unsigned short* __restrict__ Qws, float* __restrict__ out){
  __shared__ unsigned short U[128*512];
  __shared__ unsigned short Qs[8*512];
  __shared__ float bias_s[512];
  unsigned short* Alds = U;
  unsigned short* SA = U;
  int tid = threadIdx.x, lane = tid & 63, w = tid >> 6;
  int j = lane & 15, hi = lane >> 4;
  int b0 = blockIdx.x * 8;
  int ag = agp[0];
  f32x4 zero4 = {0.f, 0.f, 0.f, 0.f};

  #pragma unroll
  for (int g = 0; g < 2; g++){
    f32x4 st0[4], st1[4];
    #pragma unroll
    for (int it = 0; it < 4; it++){
      int s = tid + 512*(g*4 + it);
      int row = s >> 5, kg = s & 31;
      int bl = row >> 4, ai = row & 15;
      if (ai < 15){
        int a = ai + (ai >= ag ? 1 : 0);
        const float* p = state + (((size_t)(b0 + bl) * 16 + a) << 8) + kg * 8;
        st0[it] = *(const f32x4*)p;
        st1[it] = *(const f32x4*)(p + 4);
      } else { st0[it] = zero4; st1[it] = zero4; }
    }
    #pragma unroll
    for (int it = 0; it < 4; it++){
      int s = tid + 512*(g*4 + it);
      int row = s >> 5, kg = s & 31;
      ushort8 hv;
      hv[0]=f2bf(st0[it][0]); hv[1]=f2bf(st0[it][1]); hv[2]=f2bf(st0[it][2]); hv[3]=f2bf(st0[it][3]);
      hv[4]=f2bf(st1[it][0]); hv[5]=f2bf(st1[it][1]); hv[6]=f2bf(st1[it][2]); hv[7]=f2bf(st1[it][3]);
      *(ushort8*)&Alds[row*256 + ((kg ^ (row & 7)) << 3)] = hv;
    }
  }
  *(ushort8*)&Qs[tid*8] = *(const ushort8*)&Qws[(size_t)b0*512 + tid*8];
  bias_s[tid] = bcp[tid];
  __syncthreads();

  int cb = w * 64;

  f32x4 acc[8][4];
  #pragma unroll
  for (int a1 = 0; a1 < 8; a1++)
    #pragma unroll
    for (int a2 = 0; a2 < 4; a2++) acc[a1][a2] = zero4;
  {
    short8 bcur[4], bnxt[4];
    #pragma unroll
    for (int nt = 0; nt < 4; nt++)
      bcur[nt] = *(const short8*)&WcT[(size_t)(cb + nt*16 + j)*256 + hi*8];
    #pragma unroll 1
    for (int kk = 0; kk < 8; kk++){
      if (kk < 7){
        #pragma unroll
        for (int nt = 0; nt < 4; nt++)
          bnxt[nt] = *(const short8*)&WcT[(size_t)(cb + nt*16 + j)*256 + (kk+1)*32 + hi*8];
      }
      #pragma unroll
      for (int mt = 0; mt < 8; mt++){
        int row = mt*16 + j;
        short8 afr = *(const short8*)&Alds[row*256 + ((((kk << 2) | hi) ^ (row & 7)) << 3)];
        #pragma unroll
        for (int nt = 0; nt < 4; nt++)
          acc[mt][nt] = __builtin_amdgcn_mfma_f32_16x16x32_bf16(afr, bcur[nt], acc[mt][nt], 0, 0, 0);
      }
      #pragma unroll
      for (int nt = 0; nt < 4; nt++) bcur[nt] = bnxt[nt];
    }
  }
  __syncthreads();
  #pragma unroll
  for (int mt = 0; mt < 8; mt++)
    #pragma unroll
    for (int nt = 0; nt < 4; nt++)
      #pragma unroll
      for (int i = 0; i < 4; i++){
        int row = mt*16 + hi*4 + i, col = cb + nt*16 + j;
        float x = leaky(acc[mt][nt][i] + bias_s[col]);
        SA[row*512 + ((((col >> 3) ^ (row & 7)) << 3) | (col & 7))] = f2bf(x);
      }
  __syncthreads();

  f32x4 ka[8][4];
  #pragma unroll
  for (int a1 = 0; a1 < 8; a1++)
    #pragma unroll
    for (int a2 = 0; a2 < 4; a2++) ka[a1][a2] = zero4;
  {
    short8 bcur[4], bnxt[4];
    #pragma unroll
    for (int nt = 0; nt < 4; nt++)
      bcur[nt] = *(const short8*)&WkT[(size_t)(cb + nt*16 + j)*512 + hi*8];
    #pragma unroll 1
    for (int kk = 0; kk < 16; kk++){
      if (kk < 15){
        #pragma unroll
        for (int nt = 0; nt < 4; nt++)
          bnxt[nt] = *(const short8*)&WkT[(size_t)(cb + nt*16 + j)*512 + (kk+1)*32 + hi*8];
      }
      #pragma unroll
      for (int mt = 0; mt < 8; mt++){
        int row = mt*16 + j;
        short8 afr = *(const short8*)&SA[row*512 + ((((kk << 2) | hi) ^ (row & 7)) << 3)];
        #pragma unroll
        for (int nt = 0; nt < 4; nt++)
          ka[mt][nt] = __builtin_amdgcn_mfma_f32_16x16x32_bf16(afr, bcur[nt], ka[mt][nt], 0, 0, 0);
      }
      #pragma unroll
      for (int nt = 0; nt < 4; nt++) bcur[nt] = bnxt[nt];
    }
  }

  float wgt[8][4];
  #pragma unroll
  for (int mt = 0; mt < 8; mt++){
    float sv[4];
    #pragma unroll
    for (int i = 0; i < 4; i++){
      float t = 0.f;
      #pragma unroll
      for (int nt = 0; nt < 4; nt++)
        t += bf2f(Qs[mt*512 + cb + nt*16 + j]) * ka[mt][nt][i];
      t += __shfl_xor(t, 1); t += __shfl_xor(t, 2);
      t += __shfl_xor(t, 4); t += __shfl_xor(t, 8);
      sv[i] = t;
    }
    sv[3] = (hi == 3) ? -1e30f : sv[3];
    float m = fmaxf(fmaxf(sv[0], sv[1]), fmaxf(sv[2], sv[3]));
    m = fmaxf(m, __shfl_xor(m, 16)); m = fmaxf(m, __shfl_xor(m, 32));
    float e0 = __expf(sv[0]-m), e1 = __expf(sv[1]-m), e2 = __expf(sv[2]-m), e3 = __expf(sv[3]-m);
    float sum = e0 + e1 + e2 + e3;
    sum += __shfl_xor(sum, 16); sum += __shfl_xor(sum, 32);
    float inv = 1.f / sum;
    wgt[mt][0] = e0*inv; wgt[mt][1] = e1*inv; wgt[mt][2] = e2*inv; wgt[mt][3] = e3*inv;
  }

  f32x4 va[8][4];
  #pragma unroll
  for (int a1 = 0; a1 < 8; a1++)
    #pragma unroll
    for (int a2 = 0; a2 < 4; a2++) va[a1][a2] = zero4;
  {
    short8 bcur[4], bnxt[4];
    #pragma unroll
    for (int nt = 0; nt < 4; nt++)
      bcur[nt] = *(const short8*)&WvT[(size_t)(cb + nt*16 + j)*512 + hi*8];
    #pragma unroll 1
    for (int kk = 0; kk < 16; kk++){
      if (kk < 15){
        #pragma unroll
        for (int nt = 0; nt < 4; nt++)
          bnxt[nt] = *(const short8*)&WvT[(size_t)(cb + nt*16 + j)*512 + (kk+1)*32 + hi*8];
      }
      #pragma unroll
      for (int mt = 0; mt < 8; mt++){
        int row = mt*16 + j;
        short8 afr = *(const short8*)&SA[row*512 + ((((kk << 2) | hi) ^ (row & 7)) << 3)];
        #pragma unroll
        for (int nt = 0; nt < 4; nt++)
          va[mt][nt] = __builtin_amdgcn_mfma_f32_16x16x32_bf16(afr, bcur[nt], va[mt][nt], 0, 0, 0);
      }
      #pragma unroll
      for (int nt = 0; nt < 4; nt++) bcur[nt] = bnxt[nt];
    }
  }

  #pragma unroll
  for (int mt = 0; mt < 8; mt++){
    float ap0 = 0.f, ap1 = 0.f, ap2 = 0.f, ap3 = 0.f;
    #pragma unroll
    for (int i = 0; i < 4; i++){
      float wv = wgt[mt][i];
      ap0 += wv * leaky(va[mt][0][i]);
      ap1 += wv * leaky(va[mt][1][i]);
      ap2 += wv * leaky(va[mt][2][i]);
      ap3 += wv * leaky(va[mt][3][i]);
    }
    ap0 += __shfl_xor(ap0, 16); ap0 += __shfl_xor(ap0, 32);
    ap1 += __shfl_xor(ap1, 16); ap1 += __shfl_xor(ap1, 32);
    ap2 += __shfl_xor(ap2, 16); ap2 += __shfl_xor(ap2, 32);
    ap3 += __shfl_xor(ap3, 16); ap3 += __shfl_xor(ap3, 32);
    float val = (hi == 0) ? ap0 : (hi == 1) ? ap1 : (hi == 2) ? ap2 : ap3;
    out[(size_t)(b0 + mt)*512 + cb + lane] = val;
  }
}

extern "C" void kernel_launch(void* const* d_in, const int* in_sizes, int n_in,
                              void* d_out, int out_size, void* d_ws, size_t ws_size,
                              hipStream_t stream) {
  const float* state = (const float*)d_in[0];
  const int*   agp   = (const int*)d_in[1];
  const float* Ws    = (const float*)d_in[2];
  const float* bs    = (const float*)d_in[3];
  const float* Wc    = (const float*)d_in[4];
  const float* bc    = (const float*)d_in[5];
  const float* Wk    = (const float*)d_in[6];
  const float* Wq    = (const float*)d_in[7];
  const float* Wv    = (const float*)d_in[8];
  float* out = (float*)d_out;
  int B = in_sizes[0] / 4096;   // state is (B,16,256)

  char* wsb = (char*)d_ws;
  float* part  = (float*)wsb;                                   // 1 MB
  float* stats = (float*)(wsb + (1 << 20));                     // 4 KB
  float* bsp   = (float*)(wsb + (1 << 20) + 4096);              // 2 KB
  float* bcp   = (float*)(wsb + (1 << 20) + 6144);              // 2 KB
  unsigned short* WsT  = (unsigned short*)(wsb + (1 << 20) + 8192);
  unsigned short* WcT  = WsT  + 512*256;
  unsigned short* WkT  = WcT  + 512*256;
  unsigned short* WvT  = WkT  + 512*512;
  unsigned short* WqT  = WvT  + 512*512;
  unsigned short* WkF2 = WqT  + 512*512;         // fragment-major Wk (qk GEMM)
  unsigned short* Qws  = WkF2 + 512*512;         // B*512  (fallback only)
  unsigned short* QKws = Qws  + (size_t)B*512;   // B*8*512
  unsigned short* WsF  = Qws;                    // F-layouts overlay Qws (qk path)
  unsigned short* WcF  = WsF + 512*256;
  unsigned short* WqF  = WcF + 512*256;
  unsigned short* WvF  = WqF + 512*512;

  size_t need = ((size_t)(1 << 20) + 8192)
              + 2ull*(512*256 + 512*256 + 512*512 + 512*512 + 512*512 + 512*512)
              + 2ull*B*512 + 2ull*B*8*512;
  bool qkp = (ws_size >= need);
  int writeT = qkp ? 0 : 1;

  hipLaunchKernelGGL(ca_stats_partial, dim3(256), dim3(1024), 0, stream, state, agp, part, B);
  hipLaunchKernelGGL(ca_stats_final,   dim3(1),   dim3(1024), 0, stream, part, stats, 256, B);
  hipLaunchKernelGGL(ca_prep_sc,       dim3(512), dim3(256), 0, stream, Ws, bs, Wc, bc, stats, WsT, WcT, WsF, WcF, bsp, bcp, writeT);
  hipLaunchKernelGGL(ca_prep_kvq,      dim3(2048),dim3(512), 0, stream, Wk, Wv, Wq, WkT, WvT, WqT, WkF2, WvF, WqF, writeT);
  if (qkp){
    hipLaunchKernelGGL(ca_q_kernel_qk,   dim3(B/16),dim3(512), 0, stream, state, agp, WsF, bsp, WqF, WkF2, QKws);
    hipLaunchKernelGGL(ca_main_kernel_qk,dim3(B/8), dim3(512), 0, stream, state, agp, WcF, bcp, WvF, QKws, out);
  } else {
    hipLaunchKernelGGL(ca_q_kernel,      dim3(B/32),dim3(512), 0, stream, state, agp, WsT, bsp, WqT, Qws);
    hipLaunchKernelGGL(ca_main_kernel,   dim3(B/8), dim3(512), 0, stream, state, agp, WcT, bcp, WkT, WvT, Qws, out);
  }
}